// Round 1
// baseline (789.375 us; speedup 1.0000x reference)
//
#include <hip/hip_runtime.h>
#include <cstddef>

#define P_ 4096   // H*W
#define HW_ 64

// ---------------- mean over H*W (per b,c) ----------------
__global__ __launch_bounds__(256) void mean_kernel(const float* __restrict__ x,
                                                   float* __restrict__ mean) {
  int bc = blockIdx.x;
  int tid = threadIdx.x;
  const float* xp = x + (size_t)bc * P_;
  float s = 0.f;
  for (int i = tid; i < P_; i += 256) s += xp[i];
  __shared__ float red[256];
  red[tid] = s;
  __syncthreads();
  for (int off = 128; off > 0; off >>= 1) {
    if (tid < off) red[tid] += red[tid + off];
    __syncthreads();
  }
  if (tid == 0) mean[bc] = red[0] * (1.f / P_);
}

// ---------------- sca = conv1x1(mean) + bias ----------------
__global__ __launch_bounds__(256) void sca_kernel(const float* __restrict__ mean,
                                                  const float* __restrict__ w,
                                                  const float* __restrict__ bias,
                                                  float* __restrict__ sca) {
  int b = blockIdx.x, c = threadIdx.x;  // grid=B, block=256
  const float* mb = mean + b * 256;
  const float* wr = w + c * 256;
  float s = bias[c];
  for (int k = 0; k < 256; ++k) s += wr[k] * mb[k];
  sca[b * 256 + c] = s;
}

// ---------------- generic 1x1 conv as GEMM ----------------
// out[b,m,p] = sum_k W[m,k] (wt=0) or W[k,m] (wt=1) * in[b,k,p] + bias[m]
// grid: (P/64, M/64, B), block 256. K % 16 == 0, M % 64 == 0.
__global__ __launch_bounds__(256) void conv1x1_kernel(
    const float* __restrict__ in, const float* __restrict__ W,
    const float* __restrict__ bias, float* __restrict__ out,
    int M, int K, int wt) {
  int p0 = blockIdx.x * 64;
  int m0 = blockIdx.y * 64;
  int b  = blockIdx.z;
  __shared__ float Ws[16][68];
  __shared__ float Xs[16][68];
  int tid = threadIdx.x;
  int tm = tid >> 4, tp = tid & 15;
  float acc[4][4] = {};
  const float* inb = in + (size_t)b * K * P_;
  for (int k0 = 0; k0 < K; k0 += 16) {
    {
      int kk = tid >> 4, pq = (tid & 15) << 2;
      float4 v = *(const float4*)(inb + (size_t)(k0 + kk) * P_ + p0 + pq);
      *(float4*)&Xs[kk][pq] = v;
    }
    if (!wt) {
      int mm = tid >> 2, kq = (tid & 3) << 2;
      float4 v = *(const float4*)(W + (size_t)(m0 + mm) * K + k0 + kq);
      Ws[kq + 0][mm] = v.x; Ws[kq + 1][mm] = v.y;
      Ws[kq + 2][mm] = v.z; Ws[kq + 3][mm] = v.w;
    } else {
      int kk = tid >> 4, mq = (tid & 15) << 2;
      float4 v = *(const float4*)(W + (size_t)(k0 + kk) * M + m0 + mq);
      *(float4*)&Ws[kk][mq] = v;
    }
    __syncthreads();
#pragma unroll
    for (int kk = 0; kk < 16; ++kk) {
      const float4 wv = *(const float4*)&Ws[kk][tm << 2];
      const float4 xv = *(const float4*)&Xs[kk][tp << 2];
      const float wa[4] = {wv.x, wv.y, wv.z, wv.w};
      const float xa[4] = {xv.x, xv.y, xv.z, xv.w};
#pragma unroll
      for (int i = 0; i < 4; ++i)
#pragma unroll
        for (int j = 0; j < 4; ++j) acc[i][j] += wa[i] * xa[j];
    }
    __syncthreads();
  }
#pragma unroll
  for (int i = 0; i < 4; ++i) {
    int m = m0 + (tm << 2) + i;
    float bv = bias ? bias[m] : 0.f;
    float4 r;
    r.x = acc[i][0] + bv; r.y = acc[i][1] + bv;
    r.z = acc[i][2] + bv; r.w = acc[i][3] + bv;
    *(float4*)(out + ((size_t)b * M + m) * P_ + p0 + (tp << 2)) = r;
  }
}

// ---------------- generic depthwise conv ----------------
__global__ __launch_bounds__(256) void dwconv_kernel(
    const float* __restrict__ in, const float* __restrict__ w,
    float* __restrict__ out, int ks, int dil, int pad) {
  int idx = blockIdx.x * 256 + threadIdx.x;  // B*C*P, exact multiple
  int x = idx & 63;
  int y = (idx >> 6) & 63;
  int c = (idx >> 12) & 255;
  const float* wr = w + c * ks * ks;
  const float* ib = in + (size_t)(idx >> 12) * P_;  // (b*C+c)*P
  float s = 0.f;
  for (int dy = 0; dy < ks; ++dy) {
    int yy = y + dy * dil - pad;
    if (yy < 0 || yy >= 64) continue;
    for (int dx = 0; dx < ks; ++dx) {
      int xx = x + dx * dil - pad;
      if (xx < 0 || xx >= 64) continue;
      s += wr[dy * ks + dx] * ib[yy * 64 + xx];
    }
  }
  out[idx] = s;
}

// ---------------- grouped conv c2a: [2,256,HW] -> [2,32,HW], groups=32 ----------------
__global__ __launch_bounds__(256) void c2a_kernel(const float* __restrict__ x,
                                                  const float* __restrict__ w,
                                                  const float* __restrict__ bias,
                                                  float* __restrict__ out) {
  int idx = blockIdx.x * 256 + threadIdx.x;  // 2*32*4096
  int xq = idx & 63, y = (idx >> 6) & 63, go = (idx >> 12) & 31, b = idx >> 17;
  const float* wr = w + go * 72;  // [8][3][3]
  float s = bias[go];
  const float* xb = x + ((size_t)b * 256 + go * 8) * P_;
  for (int ci = 0; ci < 8; ++ci)
    for (int dy = 0; dy < 3; ++dy) {
      int yy = y + dy - 1;
      if (yy < 0 || yy >= 64) continue;
      for (int dx = 0; dx < 3; ++dx) {
        int xx = xq + dx - 1;
        if (xx < 0 || xx >= 64) continue;
        s += wr[ci * 9 + dy * 3 + dx] * xb[(size_t)ci * P_ + yy * 64 + xx];
      }
    }
  out[idx] = s;
}

// ---------------- SimpleGate: s = t[:, :16] * t[:, 16:] ----------------
__global__ __launch_bounds__(256) void gate_kernel(const float* __restrict__ t,
                                                   float* __restrict__ s) {
  int idx = blockIdx.x * 256 + threadIdx.x;  // 2*16*4096
  int b = idx >> 16;
  int r = idx & 65535;
  const float* tb = t + (size_t)b * 32 * P_;
  s[idx] = tb[r] * tb[65536 + r];
}

// ---------------- att = att1 * gamma[n] + att0 (in-place into att0) ----------------
__global__ __launch_bounds__(256) void combine_kernel(const float* __restrict__ att1,
                                                      const float* __restrict__ gamma,
                                                      float* __restrict__ att0) {
  int idx = blockIdx.x * 256 + threadIdx.x;  // 2*128*4096
  int n = (idx >> 12) & 127;
  att0[idx] = att1[idx] * gamma[n] + att0[idx];
}

// ---------------- prod = x1 * x2 * sca[b,c] * lka (in-place into x1 buffer) ----------------
__global__ __launch_bounds__(256) void finalmul_kernel(const float* __restrict__ x1,
                                                       const float* __restrict__ x2,
                                                       const float* __restrict__ sca,
                                                       const float* __restrict__ lka,
                                                       float* __restrict__ prod) {
  int idx = blockIdx.x * 256 + threadIdx.x;  // 2*256*4096
  int bc = idx >> 12;
  prod[idx] = x1[idx] * x2[idx] * sca[bc] * lka[idx];
}

// ---------------- IKBA pass (fused attk GEMM + unfold apply) ----------------
// grid: (P/64 row-tiles, 32 group-pairs, B), block 256.
// thread: ps = tid&31 (pixel slot; pixels ps and ps+32 of the row),
//         cq = (tid>>5)&3 (output channel within group, = i),
//         gsel = tid>>7 (which group of the pair).
// Computes m[2][12] = attk slice for its (pixels, group, i, all j), then applies
// the k=3 unfold along y (dirH=0) or x (dirH=1).
__global__ __launch_bounds__(256) void ikba_kernel(
    const float* __restrict__ in,      // uf (V) or xh (H), [B,256,P]
    const float* __restrict__ att,     // [B,128,P]
    const float* __restrict__ wcb,     // [128,6144]
    const float* __restrict__ bias_t,  // [B,256,P] (H only)
    const float* __restrict__ uf_ep,   // [B,256,P] (H only)
    const float* __restrict__ ga1,     // [256] (H only)
    float* __restrict__ out,           // xh (V) or x2 (H)
    int dirH, int wofs) {
  int tid = threadIdx.x;
  int ps = tid & 31;
  int cq = (tid >> 5) & 3;
  int gsel = tid >> 7;
  int b = blockIdx.z;
  int p0 = blockIdx.x * 64;
  int gi = blockIdx.y * 2 + gsel;

  const float* attb = att + (size_t)b * 128 * P_;
  const float* inb = in + (size_t)b * 256 * P_;

  float m0[12] = {};
  float m1[12] = {};
  const float* ap = attb + p0 + ps;
  const float* wp = wcb + wofs + gi * 48 + cq * 12;
#pragma unroll 4
  for (int n = 0; n < 128; ++n) {
    float a0 = ap[(size_t)n * P_];
    float a1 = ap[(size_t)n * P_ + 32];
    const float* wr = wp + (size_t)n * 6144;
    const float4 w0 = *(const float4*)(wr);
    const float4 w1 = *(const float4*)(wr + 4);
    const float4 w2 = *(const float4*)(wr + 8);
    const float wv[12] = {w0.x, w0.y, w0.z, w0.w, w1.x, w1.y, w1.z, w1.w,
                          w2.x, w2.y, w2.z, w2.w};
#pragma unroll
    for (int u = 0; u < 12; ++u) {
      m0[u] += a0 * wv[u];
      m1[u] += a1 * wv[u];
    }
  }

  int ch = gi * 4 + cq;
#pragma unroll
  for (int pp = 0; pp < 2; ++pp) {
    const float* mrow = pp ? m1 : m0;
    int p = p0 + ps + pp * 32;
    int xq = p & 63;
    int y = p >> 6;
    float s = 0.f;
#pragma unroll
    for (int ci = 0; ci < 4; ++ci) {
      const float* src = inb + (size_t)(gi * 4 + ci) * P_;
#pragma unroll
      for (int tap = 0; tap < 3; ++tap) {
        float v = 0.f;
        if (dirH) {
          int xx = xq + tap - 1;
          if (xx >= 0 && xx < 64) v = src[p + tap - 1];
        } else {
          int yy = y + tap - 1;
          if (yy >= 0 && yy < 64) v = src[p + (tap - 1) * 64];
        }
        s += mrow[ci * 3 + tap] * v;
      }
    }
    size_t oidx = ((size_t)b * 256 + ch) * P_ + p;
    if (dirH) {
      out[oidx] = (s + bias_t[oidx]) * ga1[ch] + uf_ep[oidx];
    } else {
      out[oidx] = s;
    }
  }
}

extern "C" void kernel_launch(void* const* d_in, const int* in_sizes, int n_in,
                              void* d_out, int out_size, void* d_ws, size_t ws_size,
                              hipStream_t stream) {
  const float* x      = (const float*)d_in[0];
  const float* dw1_w  = (const float*)d_in[1];
  const float* dw2_w  = (const float*)d_in[2];
  const float* proj_w = (const float*)d_in[3];
  const float* lka0_w = (const float*)d_in[4];
  const float* lkas_w = (const float*)d_in[5];
  const float* lka1_w = (const float*)d_in[6];
  const float* lka1_b = (const float*)d_in[7];
  const float* sca_w  = (const float*)d_in[8];
  const float* sca_b  = (const float*)d_in[9];
  const float* c1a_w  = (const float*)d_in[10];
  const float* c1b_w  = (const float*)d_in[11];
  const float* c2a_w  = (const float*)d_in[12];
  const float* c2a_b  = (const float*)d_in[13];
  const float* c2b_w  = (const float*)d_in[14];
  const float* c2b_b  = (const float*)d_in[15];
  const float* c211_w = (const float*)d_in[16];
  const float* c211_b = (const float*)d_in[17];
  const float* w_cb   = (const float*)d_in[18];
  const float* b_cb   = (const float*)d_in[19];
  const float* attg   = (const float*)d_in[20];
  const float* ga1    = (const float*)d_in[21];
  float* out = (float*)d_out;

  const size_t NCHW = 2u * 256u * P_;  // 2,097,152
  float* ws = (float*)d_ws;
  size_t off = 0;
  float* meanb = ws + off; off += 512;
  float* scab  = ws + off; off += 512;
  float* B1 = ws + off; off += NCHW;   // ta -> l0 -> lka
  float* B2 = ws + off; off += NCHW;   // x1 -> prod
  float* B3 = ws + off; off += NCHW;   // l1 -> ua -> bias_t
  float* B4 = ws + off; off += NCHW;   // xh
  float* B5 = ws + off; off += NCHW;   // uf
  float* B6 = ws + off; off += NCHW;   // x2
  float* tb   = ws + off; off += 2u * 32u * P_;   // t
  float* sb   = ws + off; off += 2u * 16u * P_;   // gate
  float* att0 = ws + off; off += 2u * 128u * P_;  // c211 path -> att
  float* att1 = ws + off; off += 2u * 128u * P_;  // c2b path

  dim3 blk(256);
  dim3 g1x1_256(64, 4, 2);  // M=256
  dim3 g1x1_128(64, 2, 2);  // M=128

  // sca branch
  mean_kernel<<<512, blk, 0, stream>>>(x, meanb);
  sca_kernel<<<2, blk, 0, stream>>>(meanb, sca_w, sca_b, scab);

  // x1 = dw2(dw1(x))
  conv1x1_kernel<<<g1x1_256, blk, 0, stream>>>(x, dw1_w, nullptr, B1, 256, 256, 0);
  dwconv_kernel<<<8192, blk, 0, stream>>>(B1, dw2_w, B2, 3, 1, 1);

  // lka = lka1(lkas(lka0(x)))
  dwconv_kernel<<<8192, blk, 0, stream>>>(x, lka0_w, B1, 5, 1, 2);
  dwconv_kernel<<<8192, blk, 0, stream>>>(B1, lkas_w, B3, 7, 3, 9);
  conv1x1_kernel<<<g1x1_256, blk, 0, stream>>>(B3, lka1_w, lka1_b, B1, 256, 256, 0);

  // uf = c1b(c1a(x))
  conv1x1_kernel<<<g1x1_256, blk, 0, stream>>>(x, c1a_w, nullptr, B3, 256, 256, 0);
  dwconv_kernel<<<8192, blk, 0, stream>>>(B3, c1b_w, B5, 3, 1, 1);

  // att = c2b(gate(c2a(x))) * gamma + c211(x)
  c2a_kernel<<<1024, blk, 0, stream>>>(x, c2a_w, c2a_b, tb);
  gate_kernel<<<512, blk, 0, stream>>>(tb, sb);
  conv1x1_kernel<<<g1x1_128, blk, 0, stream>>>(sb, c2b_w, c2b_b, att1, 128, 16, 0);
  conv1x1_kernel<<<g1x1_128, blk, 0, stream>>>(x, c211_w, c211_b, att0, 128, 256, 0);
  combine_kernel<<<4096, blk, 0, stream>>>(att1, attg, att0);  // att in att0

  // bias_t[b,c,p] = sum_n b_cb[n,c] * att[b,n,p]
  conv1x1_kernel<<<g1x1_256, blk, 0, stream>>>(att0, b_cb, nullptr, B3, 256, 128, 1);

  // IKBA vertical then horizontal (+bias, *ga1, +uf)
  dim3 gik(64, 32, 2);
  ikba_kernel<<<gik, blk, 0, stream>>>(B5, att0, w_cb, nullptr, nullptr, nullptr,
                                       B4, 0, 0);
  ikba_kernel<<<gik, blk, 0, stream>>>(B4, att0, w_cb, B3, B5, ga1,
                                       B6, 1, 3072);

  // out = proj(x1 * x2 * sca * lka)
  finalmul_kernel<<<8192, blk, 0, stream>>>(B2, B6, scab, B1, B2);
  conv1x1_kernel<<<g1x1_256, blk, 0, stream>>>(B2, proj_w, nullptr, out, 256, 256, 0);
}

// Round 2
// 456.754 us; speedup vs baseline: 1.7282x; 1.7282x over previous
//
#include <hip/hip_runtime.h>
#include <cstddef>

#define P_ 4096   // H*W
#define HW_ 64

typedef __bf16 bf16x8 __attribute__((ext_vector_type(8)));
typedef float f32x4 __attribute__((ext_vector_type(4)));

__device__ inline ushort f2bf(float f) {
  unsigned u = __float_as_uint(f);
  unsigned r = (u + 0x7FFFu + ((u >> 16) & 1u)) >> 16;
  return (ushort)r;
}

// ---------------- mean over H*W (per b,c) ----------------
__global__ __launch_bounds__(256) void mean_kernel(const float* __restrict__ x,
                                                   float* __restrict__ mean) {
  int bc = blockIdx.x;
  int tid = threadIdx.x;
  const float* xp = x + (size_t)bc * P_;
  float s = 0.f;
  for (int i = tid; i < P_; i += 256) s += xp[i];
  __shared__ float red[256];
  red[tid] = s;
  __syncthreads();
  for (int off = 128; off > 0; off >>= 1) {
    if (tid < off) red[tid] += red[tid + off];
    __syncthreads();
  }
  if (tid == 0) mean[bc] = red[0] * (1.f / P_);
}

// ---------------- sca = conv1x1(mean) + bias ----------------
__global__ __launch_bounds__(256) void sca_kernel(const float* __restrict__ mean,
                                                  const float* __restrict__ w,
                                                  const float* __restrict__ bias,
                                                  float* __restrict__ sca) {
  int b = blockIdx.x, c = threadIdx.x;
  const float* mb = mean + b * 256;
  const float* wr = w + c * 256;
  float s = bias[c];
  for (int k = 0; k < 256; ++k) s += wr[k] * mb[k];
  sca[b * 256 + c] = s;
}

// ---------------- generic 1x1 conv as GEMM ----------------
__global__ __launch_bounds__(256) void conv1x1_kernel(
    const float* __restrict__ in, const float* __restrict__ W,
    const float* __restrict__ bias, float* __restrict__ out,
    int M, int K, int wt) {
  int p0 = blockIdx.x * 64;
  int m0 = blockIdx.y * 64;
  int b  = blockIdx.z;
  __shared__ float Ws[16][68];
  __shared__ float Xs[16][68];
  int tid = threadIdx.x;
  int tm = tid >> 4, tp = tid & 15;
  float acc[4][4] = {};
  const float* inb = in + (size_t)b * K * P_;
  for (int k0 = 0; k0 < K; k0 += 16) {
    {
      int kk = tid >> 4, pq = (tid & 15) << 2;
      float4 v = *(const float4*)(inb + (size_t)(k0 + kk) * P_ + p0 + pq);
      *(float4*)&Xs[kk][pq] = v;
    }
    if (!wt) {
      int mm = tid >> 2, kq = (tid & 3) << 2;
      float4 v = *(const float4*)(W + (size_t)(m0 + mm) * K + k0 + kq);
      Ws[kq + 0][mm] = v.x; Ws[kq + 1][mm] = v.y;
      Ws[kq + 2][mm] = v.z; Ws[kq + 3][mm] = v.w;
    } else {
      int kk = tid >> 4, mq = (tid & 15) << 2;
      float4 v = *(const float4*)(W + (size_t)(k0 + kk) * M + m0 + mq);
      *(float4*)&Ws[kk][mq] = v;
    }
    __syncthreads();
#pragma unroll
    for (int kk = 0; kk < 16; ++kk) {
      const float4 wv = *(const float4*)&Ws[kk][tm << 2];
      const float4 xv = *(const float4*)&Xs[kk][tp << 2];
      const float wa[4] = {wv.x, wv.y, wv.z, wv.w};
      const float xa[4] = {xv.x, xv.y, xv.z, xv.w};
#pragma unroll
      for (int i = 0; i < 4; ++i)
#pragma unroll
        for (int j = 0; j < 4; ++j) acc[i][j] += wa[i] * xa[j];
    }
    __syncthreads();
  }
#pragma unroll
  for (int i = 0; i < 4; ++i) {
    int m = m0 + (tm << 2) + i;
    float bv = bias ? bias[m] : 0.f;
    float4 r;
    r.x = acc[i][0] + bv; r.y = acc[i][1] + bv;
    r.z = acc[i][2] + bv; r.w = acc[i][3] + bv;
    *(float4*)(out + ((size_t)b * M + m) * P_ + p0 + (tp << 2)) = r;
  }
}

// ---------------- generic depthwise conv ----------------
__global__ __launch_bounds__(256) void dwconv_kernel(
    const float* __restrict__ in, const float* __restrict__ w,
    float* __restrict__ out, int ks, int dil, int pad) {
  int idx = blockIdx.x * 256 + threadIdx.x;
  int x = idx & 63;
  int y = (idx >> 6) & 63;
  int c = (idx >> 12) & 255;
  const float* wr = w + c * ks * ks;
  const float* ib = in + (size_t)(idx >> 12) * P_;
  float s = 0.f;
  for (int dy = 0; dy < ks; ++dy) {
    int yy = y + dy * dil - pad;
    if (yy < 0 || yy >= 64) continue;
    for (int dx = 0; dx < ks; ++dx) {
      int xx = x + dx * dil - pad;
      if (xx < 0 || xx >= 64) continue;
      s += wr[dy * ks + dx] * ib[yy * 64 + xx];
    }
  }
  out[idx] = s;
}

// ---------------- grouped conv c2a ----------------
__global__ __launch_bounds__(256) void c2a_kernel(const float* __restrict__ x,
                                                  const float* __restrict__ w,
                                                  const float* __restrict__ bias,
                                                  float* __restrict__ out) {
  int idx = blockIdx.x * 256 + threadIdx.x;
  int xq = idx & 63, y = (idx >> 6) & 63, go = (idx >> 12) & 31, b = idx >> 17;
  const float* wr = w + go * 72;
  float s = bias[go];
  const float* xb = x + ((size_t)b * 256 + go * 8) * P_;
  for (int ci = 0; ci < 8; ++ci)
    for (int dy = 0; dy < 3; ++dy) {
      int yy = y + dy - 1;
      if (yy < 0 || yy >= 64) continue;
      for (int dx = 0; dx < 3; ++dx) {
        int xx = xq + dx - 1;
        if (xx < 0 || xx >= 64) continue;
        s += wr[ci * 9 + dy * 3 + dx] * xb[(size_t)ci * P_ + yy * 64 + xx];
      }
    }
  out[idx] = s;
}

// ---------------- SimpleGate ----------------
__global__ __launch_bounds__(256) void gate_kernel(const float* __restrict__ t,
                                                   float* __restrict__ s) {
  int idx = blockIdx.x * 256 + threadIdx.x;
  int b = idx >> 16;
  int r = idx & 65535;
  const float* tb = t + (size_t)b * 32 * P_;
  s[idx] = tb[r] * tb[65536 + r];
}

// ---------------- att combine ----------------
__global__ __launch_bounds__(256) void combine_kernel(const float* __restrict__ att1,
                                                      const float* __restrict__ gamma,
                                                      float* __restrict__ att0) {
  int idx = blockIdx.x * 256 + threadIdx.x;
  int n = (idx >> 12) & 127;
  att0[idx] = att1[idx] * gamma[n] + att0[idx];
}

// ---------------- final elementwise product ----------------
__global__ __launch_bounds__(256) void finalmul_kernel(const float* __restrict__ x1,
                                                       const float* __restrict__ x2,
                                                       const float* __restrict__ sca,
                                                       const float* __restrict__ lka,
                                                       float* __restrict__ prod) {
  int idx = blockIdx.x * 256 + threadIdx.x;
  int bc = idx >> 12;
  prod[idx] = x1[idx] * x2[idx] * sca[bc] * lka[idx];
}

// ---------------- transpose [128][N] fp32 -> [N][128] bf16 ----------------
// grid: (N/64, nbatch). One block: 128 x 64 tile.
__global__ __launch_bounds__(256) void t128_bf16_kernel(
    const float* __restrict__ src, ushort* __restrict__ dst,
    size_t sbs, size_t dbs, int ld) {
  src += (size_t)blockIdx.y * sbs;
  dst += (size_t)blockIdx.y * dbs;
  int c0 = blockIdx.x * 64;
  __shared__ float T[128][65];
  int t = threadIdx.x;
#pragma unroll
  for (int i = 0; i < 32; ++i) {
    int l = i * 256 + t;
    int n = l >> 6, c = l & 63;
    T[n][c] = src[(size_t)n * ld + c0 + c];
  }
  __syncthreads();
#pragma unroll
  for (int i = 0; i < 4; ++i) {
    int l = i * 256 + t;
    int c = l >> 4, n8 = (l & 15) << 3;
    ushort v[8];
#pragma unroll
    for (int u = 0; u < 8; ++u) v[u] = f2bf(T[n8 + u][c]);
    *(uint4*)&dst[(size_t)(c0 + c) * 128 + n8] = *(uint4*)v;
  }
}

// ---------------- IKBA: fused MFMA attk-GEMM + unfold apply ----------------
// grid: (64 pixel-rows, 16 group-quads, B), block 256 = 4 waves.
// Wave gg handles group (quad*4+gg): T[48 cols][64 p] = W^T @ att, then
// xh[i,p] = sum_j T[i*12+j][p] * uftap[j][p]  (+ epilogue on H pass).
__global__ __launch_bounds__(256) void ikba_mfma_kernel(
    const float* __restrict__ in,      // [B,256,P] fp32 (uf for V, xh for H)
    const ushort* __restrict__ attT,   // [B][P][128] bf16
    const ushort* __restrict__ Wt,     // [6144 col][128 n] bf16
    const float* __restrict__ bias_t,  // [B,256,P] (H only)
    const float* __restrict__ uf_ep,   // [B,256,P] (H only)
    const float* __restrict__ ga1,     // [256] (H only)
    float* __restrict__ out,
    int dirH, int wofs) {
  __shared__ __align__(16) char smem[70656];
  ushort* Ws = (ushort*)smem;            // [192][136] bf16, phase 1-2
  ushort* As = (ushort*)(smem + 53248);  // [64][136]  bf16, phase 1-2
  float*  Ts = (float*)smem;             // [4][64][52] fp32, phase 3-4 (alias Ws)
  float*  ufs = (float*)(smem + 53248);  // [4][4][3][64] fp32, phase 3-4 (alias As)

  int t = threadIdx.x;
  int b = blockIdx.z;
  int quad = blockIdx.y;
  int y = blockIdx.x;      // pixel row
  int p0 = y * 64;

  // ---- phase 1: stage W slice + att tile ----
  const ushort* Wg = Wt + ((size_t)wofs + (size_t)quad * 192) * 128;
  const ushort* Ab = attT + ((size_t)b * P_ + p0) * 128;
#pragma unroll
  for (int i = 0; i < 12; ++i) {
    int l = i * 256 + t;
    int c = l >> 4, n8 = (l & 15) << 3;
    *(uint4*)&Ws[c * 136 + n8] = *(const uint4*)&Wg[c * 128 + n8];
  }
#pragma unroll
  for (int i = 0; i < 4; ++i) {
    int l = i * 256 + t;
    int pp = l >> 4, n8 = (l & 15) << 3;
    *(uint4*)&As[pp * 136 + n8] = *(const uint4*)&Ab[pp * 128 + n8];
  }
  __syncthreads();

  // ---- phase 2: MFMA. wave gg -> group quad*4+gg ----
  int gg = t >> 6;
  int lane = t & 63;
  int lm = lane & 15, lq = lane >> 4;

  bf16x8 Af[3][4];
#pragma unroll
  for (int ct = 0; ct < 3; ++ct)
#pragma unroll
    for (int K = 0; K < 4; ++K)
      Af[ct][K] = *reinterpret_cast<const bf16x8*>(
          &Ws[(gg * 48 + ct * 16 + lm) * 136 + K * 32 + lq * 8]);

  f32x4 Cf[3][4];
#pragma unroll
  for (int ct = 0; ct < 3; ++ct)
#pragma unroll
    for (int pt = 0; pt < 4; ++pt) Cf[ct][pt] = (f32x4)(0.f);

#pragma unroll
  for (int pt = 0; pt < 4; ++pt) {
    bf16x8 Bf[4];
#pragma unroll
    for (int K = 0; K < 4; ++K)
      Bf[K] = *reinterpret_cast<const bf16x8*>(
          &As[(pt * 16 + lm) * 136 + K * 32 + lq * 8]);
#pragma unroll
    for (int ct = 0; ct < 3; ++ct)
#pragma unroll
      for (int K = 0; K < 4; ++K)
        Cf[ct][pt] = __builtin_amdgcn_mfma_f32_16x16x32_bf16(
            Af[ct][K], Bf[K], Cf[ct][pt], 0, 0, 0);
  }
  __syncthreads();  // all waves done reading Ws/As

  // ---- phase 3: T -> LDS; stage uf taps ----
#pragma unroll
  for (int ct = 0; ct < 3; ++ct)
#pragma unroll
    for (int pt = 0; pt < 4; ++pt) {
      float* dst = &Ts[(gg * 64 + pt * 16 + lm) * 52 + ct * 16 + lq * 4];
      *(float4*)dst = *(float4*)&Cf[ct][pt];
    }
#pragma unroll
  for (int i = 0; i < 12; ++i) {
    int l = i * 256 + t;
    int chl = l >> 6, x = l & 63;
    int g2 = chl / 12, rem = chl % 12;
    int cj = rem / 3, tap = rem % 3;
    int ch = (quad * 4 + g2) * 4 + cj;
    float v = 0.f;
    if (dirH) {
      int xx = x + tap - 1;
      if (xx >= 0 && xx < 64) v = in[((size_t)b * 256 + ch) * P_ + p0 + xx];
    } else {
      int yy = y + tap - 1;
      if (yy >= 0 && yy < 64) v = in[((size_t)b * 256 + ch) * P_ + yy * 64 + x];
    }
    ufs[l] = v;
  }
  __syncthreads();

  // ---- phase 4: apply + epilogue ----
  int x = t & 63;
  int g2 = t >> 6;
  float u[12];
#pragma unroll
  for (int j = 0; j < 12; ++j) u[j] = ufs[(g2 * 12 + j) * 64 + x];
  const float* Tp = &Ts[(g2 * 64 + x) * 52];
#pragma unroll
  for (int i = 0; i < 4; ++i) {
    float4 a0 = *(const float4*)&Tp[i * 12 + 0];
    float4 a1 = *(const float4*)&Tp[i * 12 + 4];
    float4 a2 = *(const float4*)&Tp[i * 12 + 8];
    float s = a0.x * u[0] + a0.y * u[1] + a0.z * u[2] + a0.w * u[3]
            + a1.x * u[4] + a1.y * u[5] + a1.z * u[6] + a1.w * u[7]
            + a2.x * u[8] + a2.y * u[9] + a2.z * u[10] + a2.w * u[11];
    int ch = (quad * 4 + g2) * 4 + i;
    size_t oidx = ((size_t)b * 256 + ch) * P_ + p0 + x;
    if (dirH) {
      out[oidx] = (s + bias_t[oidx]) * ga1[ch] + uf_ep[oidx];
    } else {
      out[oidx] = s;
    }
  }
}

extern "C" void kernel_launch(void* const* d_in, const int* in_sizes, int n_in,
                              void* d_out, int out_size, void* d_ws, size_t ws_size,
                              hipStream_t stream) {
  const float* x      = (const float*)d_in[0];
  const float* dw1_w  = (const float*)d_in[1];
  const float* dw2_w  = (const float*)d_in[2];
  const float* proj_w = (const float*)d_in[3];
  const float* lka0_w = (const float*)d_in[4];
  const float* lkas_w = (const float*)d_in[5];
  const float* lka1_w = (const float*)d_in[6];
  const float* lka1_b = (const float*)d_in[7];
  const float* sca_w  = (const float*)d_in[8];
  const float* sca_b  = (const float*)d_in[9];
  const float* c1a_w  = (const float*)d_in[10];
  const float* c1b_w  = (const float*)d_in[11];
  const float* c2a_w  = (const float*)d_in[12];
  const float* c2a_b  = (const float*)d_in[13];
  const float* c2b_w  = (const float*)d_in[14];
  const float* c2b_b  = (const float*)d_in[15];
  const float* c211_w = (const float*)d_in[16];
  const float* c211_b = (const float*)d_in[17];
  const float* w_cb   = (const float*)d_in[18];
  const float* b_cb   = (const float*)d_in[19];
  const float* attg   = (const float*)d_in[20];
  const float* ga1    = (const float*)d_in[21];
  float* out = (float*)d_out;

  const size_t NCHW = 2u * 256u * P_;
  float* ws = (float*)d_ws;
  size_t off = 0;
  float* meanb = ws + off; off += 512;
  float* scab  = ws + off; off += 512;
  float* B1 = ws + off; off += NCHW;   // ta -> l0 -> lka
  float* B2 = ws + off; off += NCHW;   // x1 -> prod
  float* B3 = ws + off; off += NCHW;   // l1 -> ua -> bias_t
  float* B4 = ws + off; off += NCHW;   // xh
  float* B5 = ws + off; off += NCHW;   // uf
  float* B6 = ws + off; off += NCHW;   // x2
  float* tb   = ws + off; off += 2u * 32u * P_;
  float* sb   = ws + off; off += 2u * 16u * P_;
  float* att0 = ws + off; off += 2u * 128u * P_;
  float* att1 = ws + off; off += 2u * 128u * P_;  // c2b out; reused as attT after combine
  float* wTf  = ws + off; off += 6144u * 128u / 2u;  // bf16 W^T
  ushort* attT = (ushort*)att1;
  ushort* wT   = (ushort*)wTf;

  dim3 blk(256);
  dim3 g1x1_256(64, 4, 2);
  dim3 g1x1_128(64, 2, 2);

  // W^T bf16 (data-independent; run first)
  t128_bf16_kernel<<<dim3(96, 1), blk, 0, stream>>>(w_cb, wT, 0, 0, 6144);

  // sca branch
  mean_kernel<<<512, blk, 0, stream>>>(x, meanb);
  sca_kernel<<<2, blk, 0, stream>>>(meanb, sca_w, sca_b, scab);

  // x1 = dw2(dw1(x))
  conv1x1_kernel<<<g1x1_256, blk, 0, stream>>>(x, dw1_w, nullptr, B1, 256, 256, 0);
  dwconv_kernel<<<8192, blk, 0, stream>>>(B1, dw2_w, B2, 3, 1, 1);

  // lka = lka1(lkas(lka0(x)))
  dwconv_kernel<<<8192, blk, 0, stream>>>(x, lka0_w, B1, 5, 1, 2);
  dwconv_kernel<<<8192, blk, 0, stream>>>(B1, lkas_w, B3, 7, 3, 9);
  conv1x1_kernel<<<g1x1_256, blk, 0, stream>>>(B3, lka1_w, lka1_b, B1, 256, 256, 0);

  // uf = c1b(c1a(x))
  conv1x1_kernel<<<g1x1_256, blk, 0, stream>>>(x, c1a_w, nullptr, B3, 256, 256, 0);
  dwconv_kernel<<<8192, blk, 0, stream>>>(B3, c1b_w, B5, 3, 1, 1);

  // att = c2b(gate(c2a(x))) * gamma + c211(x)
  c2a_kernel<<<1024, blk, 0, stream>>>(x, c2a_w, c2a_b, tb);
  gate_kernel<<<512, blk, 0, stream>>>(tb, sb);
  conv1x1_kernel<<<g1x1_128, blk, 0, stream>>>(sb, c2b_w, c2b_b, att1, 128, 16, 0);
  conv1x1_kernel<<<g1x1_128, blk, 0, stream>>>(x, c211_w, c211_b, att0, 128, 256, 0);
  combine_kernel<<<4096, blk, 0, stream>>>(att1, attg, att0);

  // bias_t[b,c,p] = sum_n b_cb[n,c] * att[b,n,p]  (fp32)
  conv1x1_kernel<<<g1x1_256, blk, 0, stream>>>(att0, b_cb, nullptr, B3, 256, 128, 1);

  // att -> bf16 transposed [b][p][n]  (att1 region is dead now)
  t128_bf16_kernel<<<dim3(64, 2), blk, 0, stream>>>(
      att0, attT, (size_t)128 * P_, (size_t)P_ * 128, P_);

  // IKBA vertical then horizontal
  dim3 gik(64, 16, 2);
  ikba_mfma_kernel<<<gik, blk, 0, stream>>>(B5, attT, wT, nullptr, nullptr,
                                            nullptr, B4, 0, 0);
  ikba_mfma_kernel<<<gik, blk, 0, stream>>>(B4, attT, wT, B3, B5, ga1,
                                            B6, 1, 3072);

  // out = proj(x1 * x2 * sca * lka)
  finalmul_kernel<<<8192, blk, 0, stream>>>(B2, B6, scab, B1, B2);
  conv1x1_kernel<<<g1x1_256, blk, 0, stream>>>(B2, proj_w, nullptr, out, 256, 256, 0);
}

// Round 3
// 363.079 us; speedup vs baseline: 2.1741x; 1.2580x over previous
//
#include <hip/hip_runtime.h>
#include <cstddef>

#define P_ 4096   // H*W
#define HW_ 64

typedef __bf16 bf16x8 __attribute__((ext_vector_type(8)));
typedef float f32x4 __attribute__((ext_vector_type(4)));

__device__ inline ushort f2bf(float f) {
  unsigned u = __float_as_uint(f);
  unsigned r = (u + 0x7FFFu + ((u >> 16) & 1u)) >> 16;
  return (ushort)r;
}

// ---------------- mean over H*W (per b,c) ----------------
__global__ __launch_bounds__(256) void mean_kernel(const float* __restrict__ x,
                                                   float* __restrict__ mean) {
  int bc = blockIdx.x;
  int tid = threadIdx.x;
  const float* xp = x + (size_t)bc * P_;
  float s = 0.f;
  for (int i = tid; i < P_; i += 256) s += xp[i];
  __shared__ float red[256];
  red[tid] = s;
  __syncthreads();
  for (int off = 128; off > 0; off >>= 1) {
    if (tid < off) red[tid] += red[tid + off];
    __syncthreads();
  }
  if (tid == 0) mean[bc] = red[0] * (1.f / P_);
}

// ---------------- sca = conv1x1(mean) + bias ----------------
__global__ __launch_bounds__(256) void sca_kernel(const float* __restrict__ mean,
                                                  const float* __restrict__ w,
                                                  const float* __restrict__ bias,
                                                  float* __restrict__ sca) {
  int b = blockIdx.x, c = threadIdx.x;
  const float* mb = mean + b * 256;
  const float* wr = w + c * 256;
  float s = bias[c];
  for (int k = 0; k < 256; ++k) s += wr[k] * mb[k];
  sca[b * 256 + c] = s;
}

// ---------------- generic 1x1 conv as GEMM ----------------
// out[b,m,p] = (sum_k W[.]in[b,k,p] + bias[m]) * gamma[m] + res[b,m,p]
__global__ __launch_bounds__(256) void conv1x1_kernel(
    const float* __restrict__ in, const float* __restrict__ W,
    const float* __restrict__ bias, float* __restrict__ out,
    int M, int K, int wt, const float* __restrict__ gamma,
    const float* __restrict__ res) {
  int p0 = blockIdx.x * 64;
  int m0 = blockIdx.y * 64;
  int b  = blockIdx.z;
  __shared__ float Ws[16][68];
  __shared__ float Xs[16][68];
  int tid = threadIdx.x;
  int tm = tid >> 4, tp = tid & 15;
  float acc[4][4] = {};
  const float* inb = in + (size_t)b * K * P_;
  for (int k0 = 0; k0 < K; k0 += 16) {
    {
      int kk = tid >> 4, pq = (tid & 15) << 2;
      float4 v = *(const float4*)(inb + (size_t)(k0 + kk) * P_ + p0 + pq);
      *(float4*)&Xs[kk][pq] = v;
    }
    if (!wt) {
      int mm = tid >> 2, kq = (tid & 3) << 2;
      float4 v = *(const float4*)(W + (size_t)(m0 + mm) * K + k0 + kq);
      Ws[kq + 0][mm] = v.x; Ws[kq + 1][mm] = v.y;
      Ws[kq + 2][mm] = v.z; Ws[kq + 3][mm] = v.w;
    } else {
      int kk = tid >> 4, mq = (tid & 15) << 2;
      float4 v = *(const float4*)(W + (size_t)(k0 + kk) * M + m0 + mq);
      *(float4*)&Ws[kk][mq] = v;
    }
    __syncthreads();
#pragma unroll
    for (int kk = 0; kk < 16; ++kk) {
      const float4 wv = *(const float4*)&Ws[kk][tm << 2];
      const float4 xv = *(const float4*)&Xs[kk][tp << 2];
      const float wa[4] = {wv.x, wv.y, wv.z, wv.w};
      const float xa[4] = {xv.x, xv.y, xv.z, xv.w};
#pragma unroll
      for (int i = 0; i < 4; ++i)
#pragma unroll
        for (int j = 0; j < 4; ++j) acc[i][j] += wa[i] * xa[j];
    }
    __syncthreads();
  }
#pragma unroll
  for (int i = 0; i < 4; ++i) {
    int m = m0 + (tm << 2) + i;
    float bv = bias ? bias[m] : 0.f;
    float gm = gamma ? gamma[m] : 1.f;
    size_t obase = ((size_t)b * M + m) * P_ + p0 + (tp << 2);
    float4 r;
    r.x = (acc[i][0] + bv) * gm; r.y = (acc[i][1] + bv) * gm;
    r.z = (acc[i][2] + bv) * gm; r.w = (acc[i][3] + bv) * gm;
    if (res) {
      float4 rv = *(const float4*)(res + obase);
      r.x += rv.x; r.y += rv.y; r.z += rv.z; r.w += rv.w;
    }
    *(float4*)(out + obase) = r;
  }
}

// ---------------- depthwise conv, whole-plane LDS ----------------
// one block per (b*C+c) plane; padded plane in LDS, fully unrolled taps.
template <int KS, int DIL, int PAD>
__global__ __launch_bounds__(256) void dwplane_kernel(
    const float* __restrict__ in, const float* __restrict__ w,
    float* __restrict__ out) {
  constexpr int PN = 64 + 2 * PAD;
  __shared__ float pl[PN * PN];
  int bc = blockIdx.x;
  int t = threadIdx.x;
  const float* ib = in + (size_t)bc * P_;
  for (int i = t; i < PN * PN; i += 256) pl[i] = 0.f;
  __syncthreads();
#pragma unroll
  for (int i = 0; i < 4; ++i) {
    int l = i * 1024 + t * 4;
    int y = l >> 6, xx = l & 63;
    float4 v = *(const float4*)(ib + l);
    float* d = &pl[(y + PAD) * PN + PAD + xx];
    d[0] = v.x; d[1] = v.y; d[2] = v.z; d[3] = v.w;
  }
  float wr[KS * KS];
  const float* wp = w + (size_t)(bc & 255) * KS * KS;
#pragma unroll
  for (int i = 0; i < KS * KS; ++i) wr[i] = wp[i];
  __syncthreads();
  float* ob = out + (size_t)bc * P_;
#pragma unroll
  for (int r = 0; r < 16; ++r) {
    int l = r * 256 + t;
    int y = l >> 6, xx = l & 63;
    float s = 0.f;
#pragma unroll
    for (int dy = 0; dy < KS; ++dy)
#pragma unroll
      for (int dx = 0; dx < KS; ++dx)
        s += wr[dy * KS + dx] * pl[(y + dy * DIL) * PN + xx + dx * DIL];
    ob[l] = s;
  }
}

// ---------------- fused lka0 (5x5 p2) -> lkas (7x7 d3 p9), depthwise ----------------
__global__ __launch_bounds__(256) void lka_fused_kernel(
    const float* __restrict__ in, const float* __restrict__ w0,
    const float* __restrict__ w1, float* __restrict__ out) {
  constexpr int PN0 = 68;  // pad 2
  constexpr int PN1 = 82;  // pad 9
  __shared__ float p0[PN0 * PN0];
  __shared__ float p1[PN1 * PN1];
  int bc = blockIdx.x;
  int t = threadIdx.x;
  const float* ib = in + (size_t)bc * P_;
  for (int i = t; i < PN0 * PN0; i += 256) p0[i] = 0.f;
  for (int i = t; i < PN1 * PN1; i += 256) p1[i] = 0.f;
  __syncthreads();
#pragma unroll
  for (int i = 0; i < 4; ++i) {
    int l = i * 1024 + t * 4;
    int y = l >> 6, xx = l & 63;
    float4 v = *(const float4*)(ib + l);
    float* d = &p0[(y + 2) * PN0 + 2 + xx];
    d[0] = v.x; d[1] = v.y; d[2] = v.z; d[3] = v.w;
  }
  float wr0[25];
  {
    const float* wp = w0 + (size_t)(bc & 255) * 25;
#pragma unroll
    for (int i = 0; i < 25; ++i) wr0[i] = wp[i];
  }
  __syncthreads();
#pragma unroll
  for (int r = 0; r < 16; ++r) {
    int l = r * 256 + t;
    int y = l >> 6, xx = l & 63;
    float s = 0.f;
#pragma unroll
    for (int dy = 0; dy < 5; ++dy)
#pragma unroll
      for (int dx = 0; dx < 5; ++dx)
        s += wr0[dy * 5 + dx] * p0[(y + dy) * PN0 + xx + dx];
    p1[(y + 9) * PN1 + 9 + xx] = s;
  }
  float wr1[49];
  {
    const float* wp = w1 + (size_t)(bc & 255) * 49;
#pragma unroll
    for (int i = 0; i < 49; ++i) wr1[i] = wp[i];
  }
  __syncthreads();
  float* ob = out + (size_t)bc * P_;
#pragma unroll
  for (int r = 0; r < 16; ++r) {
    int l = r * 256 + t;
    int y = l >> 6, xx = l & 63;
    float s = 0.f;
#pragma unroll
    for (int dy = 0; dy < 7; ++dy)
#pragma unroll
      for (int dx = 0; dx < 7; ++dx)
        s += wr1[dy * 7 + dx] * p1[(y + dy * 3) * PN1 + xx + dx * 3];
    ob[l] = s;
  }
}

// ---------------- grouped conv c2a fused with SimpleGate ----------------
// s[b,go,p] = c2a(go) * c2a(go+16)
__global__ __launch_bounds__(256) void c2a_gate_kernel(
    const float* __restrict__ x, const float* __restrict__ w,
    const float* __restrict__ bias, float* __restrict__ s) {
  int idx = blockIdx.x * 256 + threadIdx.x;  // 2*16*4096
  int xq = idx & 63, y = (idx >> 6) & 63, go = (idx >> 12) & 15, b = idx >> 16;
  float acc[2];
#pragma unroll
  for (int h = 0; h < 2; ++h) {
    int gc = go + h * 16;
    const float* wr = w + gc * 72;
    const float* xb = x + ((size_t)b * 256 + gc * 8) * P_;
    float ss = bias[gc];
    for (int ci = 0; ci < 8; ++ci)
      for (int dy = 0; dy < 3; ++dy) {
        int yy = y + dy - 1;
        if (yy < 0 || yy >= 64) continue;
        for (int dx = 0; dx < 3; ++dx) {
          int xx = xq + dx - 1;
          if (xx < 0 || xx >= 64) continue;
          ss += wr[ci * 9 + dy * 3 + dx] * xb[(size_t)ci * P_ + yy * 64 + xx];
        }
      }
    acc[h] = ss;
  }
  s[idx] = acc[0] * acc[1];
}

// ---------------- final elementwise product ----------------
__global__ __launch_bounds__(256) void finalmul_kernel(const float* __restrict__ x1,
                                                       const float* __restrict__ x2,
                                                       const float* __restrict__ sca,
                                                       const float* __restrict__ lka,
                                                       float* __restrict__ prod) {
  int idx = blockIdx.x * 256 + threadIdx.x;
  int bc = idx >> 12;
  prod[idx] = x1[idx] * x2[idx] * sca[bc] * lka[idx];
}

// ---------------- transpose [128][N] fp32 -> [N][128] bf16 ----------------
__global__ __launch_bounds__(256) void t128_bf16_kernel(
    const float* __restrict__ src, ushort* __restrict__ dst,
    size_t sbs, size_t dbs, int ld) {
  src += (size_t)blockIdx.y * sbs;
  dst += (size_t)blockIdx.y * dbs;
  int c0 = blockIdx.x * 64;
  __shared__ float T[128][65];
  int t = threadIdx.x;
#pragma unroll
  for (int i = 0; i < 32; ++i) {
    int l = i * 256 + t;
    int n = l >> 6, c = l & 63;
    T[n][c] = src[(size_t)n * ld + c0 + c];
  }
  __syncthreads();
#pragma unroll
  for (int i = 0; i < 4; ++i) {
    int l = i * 256 + t;
    int c = l >> 4, n8 = (l & 15) << 3;
    ushort v[8];
#pragma unroll
    for (int u = 0; u < 8; ++u) v[u] = f2bf(T[n8 + u][c]);
    *(uint4*)&dst[(size_t)(c0 + c) * 128 + n8] = *(uint4*)v;
  }
}

// ---------------- IKBA: fused MFMA attk-GEMM + unfold apply ----------------
__global__ __launch_bounds__(256) void ikba_mfma_kernel(
    const float* __restrict__ in,      // [B,256,P] fp32 (uf for V, xh for H)
    const ushort* __restrict__ attT,   // [B][P][128] bf16
    const ushort* __restrict__ Wt,     // [6144 col][128 n] bf16
    const float* __restrict__ bias_t,  // [B,256,P] (H only)
    const float* __restrict__ uf_ep,   // [B,256,P] (H only)
    const float* __restrict__ ga1,     // [256] (H only)
    float* __restrict__ out,
    int dirH, int wofs) {
  __shared__ __align__(16) char smem[70656];
  ushort* Ws = (ushort*)smem;            // [192][136] bf16, phase 1-2
  ushort* As = (ushort*)(smem + 53248);  // [64][136]  bf16, phase 1-2
  float*  Ts = (float*)smem;             // [4][64][52] fp32, phase 3-4
  float*  ufs = (float*)(smem + 53248);  // [4][4][3][64] fp32, phase 3-4

  int t = threadIdx.x;
  int b = blockIdx.z;
  int quad = blockIdx.y;
  int y = blockIdx.x;
  int p0 = y * 64;

  const ushort* Wg = Wt + ((size_t)wofs + (size_t)quad * 192) * 128;
  const ushort* Ab = attT + ((size_t)b * P_ + p0) * 128;
#pragma unroll
  for (int i = 0; i < 12; ++i) {
    int l = i * 256 + t;
    int c = l >> 4, n8 = (l & 15) << 3;
    *(uint4*)&Ws[c * 136 + n8] = *(const uint4*)&Wg[c * 128 + n8];
  }
#pragma unroll
  for (int i = 0; i < 4; ++i) {
    int l = i * 256 + t;
    int pp = l >> 4, n8 = (l & 15) << 3;
    *(uint4*)&As[pp * 136 + n8] = *(const uint4*)&Ab[pp * 128 + n8];
  }
  __syncthreads();

  int gg = t >> 6;
  int lane = t & 63;
  int lm = lane & 15, lq = lane >> 4;

  bf16x8 Af[3][4];
#pragma unroll
  for (int ct = 0; ct < 3; ++ct)
#pragma unroll
    for (int K = 0; K < 4; ++K)
      Af[ct][K] = *reinterpret_cast<const bf16x8*>(
          &Ws[(gg * 48 + ct * 16 + lm) * 136 + K * 32 + lq * 8]);

  f32x4 Cf[3][4];
#pragma unroll
  for (int ct = 0; ct < 3; ++ct)
#pragma unroll
    for (int pt = 0; pt < 4; ++pt) Cf[ct][pt] = (f32x4)(0.f);

#pragma unroll
  for (int pt = 0; pt < 4; ++pt) {
    bf16x8 Bf[4];
#pragma unroll
    for (int K = 0; K < 4; ++K)
      Bf[K] = *reinterpret_cast<const bf16x8*>(
          &As[(pt * 16 + lm) * 136 + K * 32 + lq * 8]);
#pragma unroll
    for (int ct = 0; ct < 3; ++ct)
#pragma unroll
      for (int K = 0; K < 4; ++K)
        Cf[ct][pt] = __builtin_amdgcn_mfma_f32_16x16x32_bf16(
            Af[ct][K], Bf[K], Cf[ct][pt], 0, 0, 0);
  }
  __syncthreads();

#pragma unroll
  for (int ct = 0; ct < 3; ++ct)
#pragma unroll
    for (int pt = 0; pt < 4; ++pt) {
      float* dst = &Ts[(gg * 64 + pt * 16 + lm) * 52 + ct * 16 + lq * 4];
      *(float4*)dst = *(float4*)&Cf[ct][pt];
    }
#pragma unroll
  for (int i = 0; i < 12; ++i) {
    int l = i * 256 + t;
    int chl = l >> 6, x = l & 63;
    int g2 = chl / 12, rem = chl % 12;
    int cj = rem / 3, tap = rem % 3;
    int ch = (quad * 4 + g2) * 4 + cj;
    float v = 0.f;
    if (dirH) {
      int xx = x + tap - 1;
      if (xx >= 0 && xx < 64) v = in[((size_t)b * 256 + ch) * P_ + p0 + xx];
    } else {
      int yy = y + tap - 1;
      if (yy >= 0 && yy < 64) v = in[((size_t)b * 256 + ch) * P_ + yy * 64 + x];
    }
    ufs[l] = v;
  }
  __syncthreads();

  int x = t & 63;
  int g2 = t >> 6;
  float u[12];
#pragma unroll
  for (int j = 0; j < 12; ++j) u[j] = ufs[(g2 * 12 + j) * 64 + x];
  const float* Tp = &Ts[(g2 * 64 + x) * 52];
#pragma unroll
  for (int i = 0; i < 4; ++i) {
    float4 a0 = *(const float4*)&Tp[i * 12 + 0];
    float4 a1 = *(const float4*)&Tp[i * 12 + 4];
    float4 a2 = *(const float4*)&Tp[i * 12 + 8];
    float s = a0.x * u[0] + a0.y * u[1] + a0.z * u[2] + a0.w * u[3]
            + a1.x * u[4] + a1.y * u[5] + a1.z * u[6] + a1.w * u[7]
            + a2.x * u[8] + a2.y * u[9] + a2.z * u[10] + a2.w * u[11];
    int ch = (quad * 4 + g2) * 4 + i;
    size_t oidx = ((size_t)b * 256 + ch) * P_ + p0 + x;
    if (dirH) {
      out[oidx] = (s + bias_t[oidx]) * ga1[ch] + uf_ep[oidx];
    } else {
      out[oidx] = s;
    }
  }
}

extern "C" void kernel_launch(void* const* d_in, const int* in_sizes, int n_in,
                              void* d_out, int out_size, void* d_ws, size_t ws_size,
                              hipStream_t stream) {
  const float* x      = (const float*)d_in[0];
  const float* dw1_w  = (const float*)d_in[1];
  const float* dw2_w  = (const float*)d_in[2];
  const float* proj_w = (const float*)d_in[3];
  const float* lka0_w = (const float*)d_in[4];
  const float* lkas_w = (const float*)d_in[5];
  const float* lka1_w = (const float*)d_in[6];
  const float* lka1_b = (const float*)d_in[7];
  const float* sca_w  = (const float*)d_in[8];
  const float* sca_b  = (const float*)d_in[9];
  const float* c1a_w  = (const float*)d_in[10];
  const float* c1b_w  = (const float*)d_in[11];
  const float* c2a_w  = (const float*)d_in[12];
  const float* c2a_b  = (const float*)d_in[13];
  const float* c2b_w  = (const float*)d_in[14];
  const float* c2b_b  = (const float*)d_in[15];
  const float* c211_w = (const float*)d_in[16];
  const float* c211_b = (const float*)d_in[17];
  const float* w_cb   = (const float*)d_in[18];
  const float* b_cb   = (const float*)d_in[19];
  const float* attg   = (const float*)d_in[20];
  const float* ga1    = (const float*)d_in[21];
  float* out = (float*)d_out;

  const size_t NCHW = 2u * 256u * P_;
  float* ws = (float*)d_ws;
  size_t off = 0;
  float* meanb = ws + off; off += 512;
  float* scab  = ws + off; off += 512;
  float* B1 = ws + off; off += NCHW;   // ta -> lka
  float* B2 = ws + off; off += NCHW;   // x1 -> prod
  float* B3 = ws + off; off += NCHW;   // lkas -> ua -> bias_t
  float* B4 = ws + off; off += NCHW;   // xh
  float* B5 = ws + off; off += NCHW;   // uf
  float* B6 = ws + off; off += NCHW;   // x2
  float* sb   = ws + off; off += 2u * 16u * P_;   // gated
  float* att0 = ws + off; off += 2u * 128u * P_;  // att
  float* att1 = ws + off; off += 2u * 128u * P_;  // attT (bf16)
  float* wTf  = ws + off; off += 6144u * 128u / 2u;  // bf16 W^T
  ushort* attT = (ushort*)att1;
  ushort* wT   = (ushort*)wTf;

  dim3 blk(256);
  dim3 g1x1_256(64, 4, 2);
  dim3 g1x1_128(64, 2, 2);

  // W^T bf16 (data-independent; run first)
  t128_bf16_kernel<<<dim3(96, 1), blk, 0, stream>>>(w_cb, wT, 0, 0, 6144);

  // sca branch
  mean_kernel<<<512, blk, 0, stream>>>(x, meanb);
  sca_kernel<<<2, blk, 0, stream>>>(meanb, sca_w, sca_b, scab);

  // x1 = dw2(dw1(x))
  conv1x1_kernel<<<g1x1_256, blk, 0, stream>>>(x, dw1_w, nullptr, B1, 256, 256, 0,
                                               nullptr, nullptr);
  dwplane_kernel<3, 1, 1><<<512, blk, 0, stream>>>(B1, dw2_w, B2);

  // lka = lka1(lkas(lka0(x)))  -- depthwise part fused
  lka_fused_kernel<<<512, blk, 0, stream>>>(x, lka0_w, lkas_w, B3);
  conv1x1_kernel<<<g1x1_256, blk, 0, stream>>>(B3, lka1_w, lka1_b, B1, 256, 256, 0,
                                               nullptr, nullptr);

  // uf = c1b(c1a(x))
  conv1x1_kernel<<<g1x1_256, blk, 0, stream>>>(x, c1a_w, nullptr, B3, 256, 256, 0,
                                               nullptr, nullptr);
  dwplane_kernel<3, 1, 1><<<512, blk, 0, stream>>>(B3, c1b_w, B5);

  // att = c2b(gate(c2a(x))) * gamma + c211(x)
  c2a_gate_kernel<<<512, blk, 0, stream>>>(x, c2a_w, c2a_b, sb);
  conv1x1_kernel<<<g1x1_128, blk, 0, stream>>>(x, c211_w, c211_b, att0, 128, 256, 0,
                                               nullptr, nullptr);
  conv1x1_kernel<<<g1x1_128, blk, 0, stream>>>(sb, c2b_w, c2b_b, att0, 128, 16, 0,
                                               attg, att0);

  // bias_t[b,c,p] = sum_n b_cb[n,c] * att[b,n,p]  (fp32)
  conv1x1_kernel<<<g1x1_256, blk, 0, stream>>>(att0, b_cb, nullptr, B3, 256, 128, 1,
                                               nullptr, nullptr);

  // att -> bf16 transposed [b][p][n]
  t128_bf16_kernel<<<dim3(64, 2), blk, 0, stream>>>(
      att0, attT, (size_t)128 * P_, (size_t)P_ * 128, P_);

  // IKBA vertical then horizontal
  dim3 gik(64, 16, 2);
  ikba_mfma_kernel<<<gik, blk, 0, stream>>>(B5, attT, wT, nullptr, nullptr,
                                            nullptr, B4, 0, 0);
  ikba_mfma_kernel<<<gik, blk, 0, stream>>>(B4, attT, wT, B3, B5, ga1,
                                            B6, 1, 3072);

  // out = proj(x1 * x2 * sca * lka)
  finalmul_kernel<<<8192, blk, 0, stream>>>(B2, B6, scab, B1, B2);
  conv1x1_kernel<<<g1x1_256, blk, 0, stream>>>(B2, proj_w, nullptr, out, 256, 256, 0,
                                               nullptr, nullptr);
}

// Round 4
// 302.813 us; speedup vs baseline: 2.6068x; 1.1990x over previous
//
#include <hip/hip_runtime.h>
#include <cstddef>

#define P_ 4096   // H*W
#define HW_ 64

typedef __bf16 bf16x8 __attribute__((ext_vector_type(8)));
typedef float f32x4 __attribute__((ext_vector_type(4)));

__device__ inline ushort f2bf(float f) {
  unsigned u = __float_as_uint(f);
  unsigned r = (u + 0x7FFFu + ((u >> 16) & 1u)) >> 16;
  return (ushort)r;
}
__device__ inline float bf2f(ushort h) {
  return __uint_as_float(((unsigned)h) << 16);
}

// ---------------- mean over H*W (per b,c) ----------------
__global__ __launch_bounds__(256) void mean_kernel(const float* __restrict__ x,
                                                   float* __restrict__ mean) {
  int bc = blockIdx.x;
  int tid = threadIdx.x;
  const float* xp = x + (size_t)bc * P_;
  float s = 0.f;
  for (int i = tid; i < P_; i += 256) s += xp[i];
  __shared__ float red[256];
  red[tid] = s;
  __syncthreads();
  for (int off = 128; off > 0; off >>= 1) {
    if (tid < off) red[tid] += red[tid + off];
    __syncthreads();
  }
  if (tid == 0) mean[bc] = red[0] * (1.f / P_);
}

// ---------------- sca = conv1x1(mean) + bias ----------------
__global__ __launch_bounds__(256) void sca_kernel(const float* __restrict__ mean,
                                                  const float* __restrict__ w,
                                                  const float* __restrict__ bias,
                                                  float* __restrict__ sca) {
  int b = blockIdx.x, c = threadIdx.x;
  const float* mb = mean + b * 256;
  const float* wr = w + c * 256;
  float s = bias[c];
  for (int k = 0; k < 256; ++k) s += wr[k] * mb[k];
  sca[b * 256 + c] = s;
}

// ---------------- legacy fp32 1x1 conv (only c2b, K=16) ----------------
__global__ __launch_bounds__(256) void conv1x1_kernel(
    const float* __restrict__ in, const float* __restrict__ W,
    const float* __restrict__ bias, float* __restrict__ out,
    int M, int K, const float* __restrict__ gamma,
    const float* __restrict__ res) {
  int p0 = blockIdx.x * 64;
  int m0 = blockIdx.y * 64;
  int b  = blockIdx.z;
  __shared__ float Ws[16][68];
  __shared__ float Xs[16][68];
  int tid = threadIdx.x;
  int tm = tid >> 4, tp = tid & 15;
  float acc[4][4] = {};
  const float* inb = in + (size_t)b * K * P_;
  for (int k0 = 0; k0 < K; k0 += 16) {
    {
      int kk = tid >> 4, pq = (tid & 15) << 2;
      float4 v = *(const float4*)(inb + (size_t)(k0 + kk) * P_ + p0 + pq);
      *(float4*)&Xs[kk][pq] = v;
    }
    {
      int mm = tid >> 2, kq = (tid & 3) << 2;
      float4 v = *(const float4*)(W + (size_t)(m0 + mm) * K + k0 + kq);
      Ws[kq + 0][mm] = v.x; Ws[kq + 1][mm] = v.y;
      Ws[kq + 2][mm] = v.z; Ws[kq + 3][mm] = v.w;
    }
    __syncthreads();
#pragma unroll
    for (int kk = 0; kk < 16; ++kk) {
      const float4 wv = *(const float4*)&Ws[kk][tm << 2];
      const float4 xv = *(const float4*)&Xs[kk][tp << 2];
      const float wa[4] = {wv.x, wv.y, wv.z, wv.w};
      const float xa[4] = {xv.x, xv.y, xv.z, xv.w};
#pragma unroll
      for (int i = 0; i < 4; ++i)
#pragma unroll
        for (int j = 0; j < 4; ++j) acc[i][j] += wa[i] * xa[j];
    }
    __syncthreads();
  }
#pragma unroll
  for (int i = 0; i < 4; ++i) {
    int m = m0 + (tm << 2) + i;
    float bv = bias ? bias[m] : 0.f;
    float gm = gamma ? gamma[m] : 1.f;
    size_t obase = ((size_t)b * M + m) * P_ + p0 + (tp << 2);
    float4 r;
    r.x = (acc[i][0] + bv) * gm; r.y = (acc[i][1] + bv) * gm;
    r.z = (acc[i][2] + bv) * gm; r.w = (acc[i][3] + bv) * gm;
    if (res) {
      float4 rv = *(const float4*)(res + obase);
      r.x += rv.x; r.y += rv.y; r.z += rv.z; r.w += rv.w;
    }
    *(float4*)(out + obase) = r;
  }
}

// ---------------- split-bf16 MFMA GEMM ----------------
// out[b,m,p] = sum_k W[m,k]*X[b,p,k] (+bias[m]); W,X pre-split hi/lo bf16.
// grid (P/64, M/64, B), block 256 = 4 waves, wave w -> 16 m-rows.
__global__ __launch_bounds__(256) void gemm_bf16s_kernel(
    const ushort* __restrict__ Wh, const ushort* __restrict__ Wl,
    const ushort* __restrict__ Xh, const ushort* __restrict__ Xl,
    const float* __restrict__ bias, float* __restrict__ out, int M, int K) {
  int p0 = blockIdx.x * 64, m0 = blockIdx.y * 64, b = blockIdx.z;
  __shared__ __align__(16) ushort Wsh[64 * 72];
  __shared__ __align__(16) ushort Wsl[64 * 72];
  __shared__ __align__(16) ushort Xsh[64 * 72];
  __shared__ __align__(16) ushort Xsl[64 * 72];
  int t = threadIdx.x;
  int w = t >> 6, lane = t & 63, lm = lane & 15, lq = lane >> 4;
  f32x4 C[4];
#pragma unroll
  for (int pt = 0; pt < 4; ++pt) C[pt] = (f32x4)(0.f);
  const ushort* Whb = Wh + (size_t)m0 * K;
  const ushort* Wlb = Wl + (size_t)m0 * K;
  const ushort* Xhb = Xh + ((size_t)b * P_ + p0) * K;
  const ushort* Xlb = Xl + ((size_t)b * P_ + p0) * K;
  for (int k0 = 0; k0 < K; k0 += 64) {
#pragma unroll
    for (int i = 0; i < 2; ++i) {
      int u = i * 256 + t;
      int row = u >> 3, k8 = (u & 7) * 8;
      *(uint4*)&Wsh[row * 72 + k8] = *(const uint4*)&Whb[(size_t)row * K + k0 + k8];
      *(uint4*)&Wsl[row * 72 + k8] = *(const uint4*)&Wlb[(size_t)row * K + k0 + k8];
      *(uint4*)&Xsh[row * 72 + k8] = *(const uint4*)&Xhb[(size_t)row * K + k0 + k8];
      *(uint4*)&Xsl[row * 72 + k8] = *(const uint4*)&Xlb[(size_t)row * K + k0 + k8];
    }
    __syncthreads();
#pragma unroll
    for (int kt = 0; kt < 2; ++kt) {
      bf16x8 Ah = *(const bf16x8*)&Wsh[(w * 16 + lm) * 72 + kt * 32 + lq * 8];
      bf16x8 Al = *(const bf16x8*)&Wsl[(w * 16 + lm) * 72 + kt * 32 + lq * 8];
#pragma unroll
      for (int pt = 0; pt < 4; ++pt) {
        bf16x8 Bh = *(const bf16x8*)&Xsh[(pt * 16 + lm) * 72 + kt * 32 + lq * 8];
        bf16x8 Bl = *(const bf16x8*)&Xsl[(pt * 16 + lm) * 72 + kt * 32 + lq * 8];
        C[pt] = __builtin_amdgcn_mfma_f32_16x16x32_bf16(Ah, Bh, C[pt], 0, 0, 0);
        C[pt] = __builtin_amdgcn_mfma_f32_16x16x32_bf16(Al, Bh, C[pt], 0, 0, 0);
        C[pt] = __builtin_amdgcn_mfma_f32_16x16x32_bf16(Ah, Bl, C[pt], 0, 0, 0);
      }
    }
    __syncthreads();
  }
#pragma unroll
  for (int pt = 0; pt < 4; ++pt) {
    int p = p0 + pt * 16 + lm;
#pragma unroll
    for (int r = 0; r < 4; ++r) {
      int m = m0 + w * 16 + lq * 4 + r;
      float v = C[pt][r];
      if (bias) v += bias[m];
      out[((size_t)b * M + m) * P_ + p] = v;
    }
  }
}

// ---------------- transpose+split: [K][P] fp32 -> [P][K] bf16 hi/lo ----------
// grid (P/64, K/128, B)
__global__ __launch_bounds__(256) void xsplit_kernel(
    const float* __restrict__ src, ushort* __restrict__ dh,
    ushort* __restrict__ dl, int K) {
  int p0 = blockIdx.x * 64;
  int kb = blockIdx.y;
  int b = blockIdx.z;
  const float* sb = src + ((size_t)b * K + kb * 128) * P_;
  ushort* dhb = dh + (size_t)b * P_ * K + (size_t)kb * 128;
  ushort* dlb = dl + (size_t)b * P_ * K + (size_t)kb * 128;
  __shared__ float T[128][65];
  int t = threadIdx.x;
#pragma unroll
  for (int i = 0; i < 32; ++i) {
    int l = i * 256 + t;
    int n = l >> 6, c = l & 63;
    T[n][c] = sb[(size_t)n * P_ + p0 + c];
  }
  __syncthreads();
#pragma unroll
  for (int i = 0; i < 4; ++i) {
    int l = i * 256 + t;
    int c = l >> 4, n8 = (l & 15) << 3;
    ushort vh[8], vl[8];
#pragma unroll
    for (int u = 0; u < 8; ++u) {
      float f = T[n8 + u][c];
      ushort h = f2bf(f);
      vh[u] = h;
      vl[u] = f2bf(f - bf2f(h));
    }
    *(uint4*)&dhb[(size_t)(p0 + c) * K + n8] = *(uint4*)vh;
    *(uint4*)&dlb[(size_t)(p0 + c) * K + n8] = *(uint4*)vl;
  }
}

// ---------------- product transpose+split: (x1*x2*sca*lka) -> [P][256] hi/lo --
// grid (P/64, 2, B)
__global__ __launch_bounds__(256) void prodsplit_kernel(
    const float* __restrict__ x1, const float* __restrict__ x2,
    const float* __restrict__ sca, const float* __restrict__ lka,
    ushort* __restrict__ dh, ushort* __restrict__ dl) {
  const int K = 256;
  int p0 = blockIdx.x * 64;
  int kb = blockIdx.y;
  int b = blockIdx.z;
  size_t base = ((size_t)b * K + kb * 128) * P_;
  ushort* dhb = dh + (size_t)b * P_ * K + (size_t)kb * 128;
  ushort* dlb = dl + (size_t)b * P_ * K + (size_t)kb * 128;
  __shared__ float T[128][65];
  int t = threadIdx.x;
#pragma unroll
  for (int i = 0; i < 32; ++i) {
    int l = i * 256 + t;
    int n = l >> 6, c = l & 63;
    size_t a = base + (size_t)n * P_ + p0 + c;
    float sc = sca[b * 256 + kb * 128 + n];
    T[n][c] = x1[a] * x2[a] * sc * lka[a];
  }
  __syncthreads();
#pragma unroll
  for (int i = 0; i < 4; ++i) {
    int l = i * 256 + t;
    int c = l >> 4, n8 = (l & 15) << 3;
    ushort vh[8], vl[8];
#pragma unroll
    for (int u = 0; u < 8; ++u) {
      float f = T[n8 + u][c];
      ushort h = f2bf(f);
      vh[u] = h;
      vl[u] = f2bf(f - bf2f(h));
    }
    *(uint4*)&dhb[(size_t)(p0 + c) * K + n8] = *(uint4*)vh;
    *(uint4*)&dlb[(size_t)(p0 + c) * K + n8] = *(uint4*)vl;
  }
}

// ---------------- prep: w_cb^T (hi), 5 weight splits, b_cb^T split ----------
// grid 244: [0,96) wT; [96,240) flat; [240,244) b_cb^T
__global__ __launch_bounds__(256) void prep_kernel(
    const float* __restrict__ w_cb, const float* __restrict__ dw1_w,
    const float* __restrict__ lka1_w, const float* __restrict__ c1a_w,
    const float* __restrict__ proj_w, const float* __restrict__ c211_w,
    const float* __restrict__ b_cb, ushort* __restrict__ wT,
    ushort* __restrict__ W5h, ushort* __restrict__ W5l,
    ushort* __restrict__ bth, ushort* __restrict__ btl) {
  __shared__ float T[128][65];
  int blk = blockIdx.x;
  int t = threadIdx.x;
  if (blk < 96) {
    int c0 = blk * 64;
#pragma unroll
    for (int i = 0; i < 32; ++i) {
      int l = i * 256 + t;
      int n = l >> 6, c = l & 63;
      T[n][c] = w_cb[(size_t)n * 6144 + c0 + c];
    }
    __syncthreads();
#pragma unroll
    for (int i = 0; i < 4; ++i) {
      int l = i * 256 + t;
      int c = l >> 4, n8 = (l & 15) << 3;
      ushort v[8];
#pragma unroll
      for (int u = 0; u < 8; ++u) v[u] = f2bf(T[n8 + u][c]);
      *(uint4*)&wT[(size_t)(c0 + c) * 128 + n8] = *(uint4*)v;
    }
  } else if (blk < 240) {
    int f = (blk - 96) * 2048 + t * 8;
    const float* srcs[5] = {dw1_w, lka1_w, c1a_w, proj_w, c211_w};
    const int base[6] = {0, 65536, 131072, 196608, 262144, 294912};
    int r = 0;
    while (f >= base[r + 1]) ++r;
    const float* s = srcs[r] + (f - base[r]);
    float4 a = *(const float4*)s;
    float4 b4 = *(const float4*)(s + 4);
    float vv[8] = {a.x, a.y, a.z, a.w, b4.x, b4.y, b4.z, b4.w};
    ushort vh[8], vl[8];
#pragma unroll
    for (int u = 0; u < 8; ++u) {
      ushort h = f2bf(vv[u]);
      vh[u] = h;
      vl[u] = f2bf(vv[u] - bf2f(h));
    }
    *(uint4*)&W5h[f] = *(uint4*)vh;
    *(uint4*)&W5l[f] = *(uint4*)vl;
  } else {
    int c0 = (blk - 240) * 64;
#pragma unroll
    for (int i = 0; i < 32; ++i) {
      int l = i * 256 + t;
      int n = l >> 6, c = l & 63;
      T[n][c] = b_cb[(size_t)n * 256 + c0 + c];
    }
    __syncthreads();
#pragma unroll
    for (int i = 0; i < 4; ++i) {
      int l = i * 256 + t;
      int c = l >> 4, n8 = (l & 15) << 3;
      ushort vh[8], vl[8];
#pragma unroll
      for (int u = 0; u < 8; ++u) {
        float fv = T[n8 + u][c];
        ushort h = f2bf(fv);
        vh[u] = h;
        vl[u] = f2bf(fv - bf2f(h));
      }
      *(uint4*)&bth[(size_t)(c0 + c) * 128 + n8] = *(uint4*)vh;
      *(uint4*)&btl[(size_t)(c0 + c) * 128 + n8] = *(uint4*)vl;
    }
  }
}

// ---------------- depthwise conv, whole-plane LDS ----------------
template <int KS, int DIL, int PAD>
__global__ __launch_bounds__(256) void dwplane_kernel(
    const float* __restrict__ in, const float* __restrict__ w,
    float* __restrict__ out) {
  constexpr int PN = 64 + 2 * PAD;
  __shared__ float pl[PN * PN];
  int bc = blockIdx.x;
  int t = threadIdx.x;
  const float* ib = in + (size_t)bc * P_;
  for (int i = t; i < PN * PN; i += 256) pl[i] = 0.f;
  __syncthreads();
#pragma unroll
  for (int i = 0; i < 4; ++i) {
    int l = i * 1024 + t * 4;
    int y = l >> 6, xx = l & 63;
    float4 v = *(const float4*)(ib + l);
    float* d = &pl[(y + PAD) * PN + PAD + xx];
    d[0] = v.x; d[1] = v.y; d[2] = v.z; d[3] = v.w;
  }
  float wr[KS * KS];
  const float* wp = w + (size_t)(bc & 255) * KS * KS;
#pragma unroll
  for (int i = 0; i < KS * KS; ++i) wr[i] = wp[i];
  __syncthreads();
  float* ob = out + (size_t)bc * P_;
#pragma unroll
  for (int r = 0; r < 16; ++r) {
    int l = r * 256 + t;
    int y = l >> 6, xx = l & 63;
    float s = 0.f;
#pragma unroll
    for (int dy = 0; dy < KS; ++dy)
#pragma unroll
      for (int dx = 0; dx < KS; ++dx)
        s += wr[dy * KS + dx] * pl[(y + dy * DIL) * PN + xx + dx * DIL];
    ob[l] = s;
  }
}

// ---------------- fused lka0 (5x5 p2) -> lkas (7x7 d3 p9) ----------------
__global__ __launch_bounds__(256) void lka_fused_kernel(
    const float* __restrict__ in, const float* __restrict__ w0,
    const float* __restrict__ w1, float* __restrict__ out) {
  constexpr int PN0 = 68;
  constexpr int PN1 = 82;
  __shared__ float p0[PN0 * PN0];
  __shared__ float p1[PN1 * PN1];
  int bc = blockIdx.x;
  int t = threadIdx.x;
  const float* ib = in + (size_t)bc * P_;
  for (int i = t; i < PN0 * PN0; i += 256) p0[i] = 0.f;
  for (int i = t; i < PN1 * PN1; i += 256) p1[i] = 0.f;
  __syncthreads();
#pragma unroll
  for (int i = 0; i < 4; ++i) {
    int l = i * 1024 + t * 4;
    int y = l >> 6, xx = l & 63;
    float4 v = *(const float4*)(ib + l);
    float* d = &p0[(y + 2) * PN0 + 2 + xx];
    d[0] = v.x; d[1] = v.y; d[2] = v.z; d[3] = v.w;
  }
  float wr0[25];
  {
    const float* wp = w0 + (size_t)(bc & 255) * 25;
#pragma unroll
    for (int i = 0; i < 25; ++i) wr0[i] = wp[i];
  }
  __syncthreads();
#pragma unroll
  for (int r = 0; r < 16; ++r) {
    int l = r * 256 + t;
    int y = l >> 6, xx = l & 63;
    float s = 0.f;
#pragma unroll
    for (int dy = 0; dy < 5; ++dy)
#pragma unroll
      for (int dx = 0; dx < 5; ++dx)
        s += wr0[dy * 5 + dx] * p0[(y + dy) * PN0 + xx + dx];
    p1[(y + 9) * PN1 + 9 + xx] = s;
  }
  float wr1[49];
  {
    const float* wp = w1 + (size_t)(bc & 255) * 49;
#pragma unroll
    for (int i = 0; i < 49; ++i) wr1[i] = wp[i];
  }
  __syncthreads();
  float* ob = out + (size_t)bc * P_;
#pragma unroll
  for (int r = 0; r < 16; ++r) {
    int l = r * 256 + t;
    int y = l >> 6, xx = l & 63;
    float s = 0.f;
#pragma unroll
    for (int dy = 0; dy < 7; ++dy)
#pragma unroll
      for (int dx = 0; dx < 7; ++dx)
        s += wr1[dy * 7 + dx] * p1[(y + dy * 3) * PN1 + xx + dx * 3];
    ob[l] = s;
  }
}

// ---------------- grouped conv c2a fused with SimpleGate ----------------
__global__ __launch_bounds__(256) void c2a_gate_kernel(
    const float* __restrict__ x, const float* __restrict__ w,
    const float* __restrict__ bias, float* __restrict__ s) {
  int idx = blockIdx.x * 256 + threadIdx.x;
  int xq = idx & 63, y = (idx >> 6) & 63, go = (idx >> 12) & 15, b = idx >> 16;
  float acc[2];
#pragma unroll
  for (int h = 0; h < 2; ++h) {
    int gc = go + h * 16;
    const float* wr = w + gc * 72;
    const float* xb = x + ((size_t)b * 256 + gc * 8) * P_;
    float ss = bias[gc];
    for (int ci = 0; ci < 8; ++ci)
      for (int dy = 0; dy < 3; ++dy) {
        int yy = y + dy - 1;
        if (yy < 0 || yy >= 64) continue;
        for (int dx = 0; dx < 3; ++dx) {
          int xx = xq + dx - 1;
          if (xx < 0 || xx >= 64) continue;
          ss += wr[ci * 9 + dy * 3 + dx] * xb[(size_t)ci * P_ + yy * 64 + xx];
        }
      }
    acc[h] = ss;
  }
  s[idx] = acc[0] * acc[1];
}

// ---------------- IKBA: fused MFMA attk-GEMM + unfold apply ----------------
__global__ __launch_bounds__(256) void ikba_mfma_kernel(
    const float* __restrict__ in, const ushort* __restrict__ attT,
    const ushort* __restrict__ Wt, const float* __restrict__ bias_t,
    const float* __restrict__ uf_ep, const float* __restrict__ ga1,
    float* __restrict__ out, int dirH, int wofs) {
  __shared__ __align__(16) char smem[70656];
  ushort* Ws = (ushort*)smem;
  ushort* As = (ushort*)(smem + 53248);
  float*  Ts = (float*)smem;
  float*  ufs = (float*)(smem + 53248);

  int t = threadIdx.x;
  int b = blockIdx.z;
  int quad = blockIdx.y;
  int y = blockIdx.x;
  int p0 = y * 64;

  const ushort* Wg = Wt + ((size_t)wofs + (size_t)quad * 192) * 128;
  const ushort* Ab = attT + ((size_t)b * P_ + p0) * 128;
#pragma unroll
  for (int i = 0; i < 12; ++i) {
    int l = i * 256 + t;
    int c = l >> 4, n8 = (l & 15) << 3;
    *(uint4*)&Ws[c * 136 + n8] = *(const uint4*)&Wg[c * 128 + n8];
  }
#pragma unroll
  for (int i = 0; i < 4; ++i) {
    int l = i * 256 + t;
    int pp = l >> 4, n8 = (l & 15) << 3;
    *(uint4*)&As[pp * 136 + n8] = *(const uint4*)&Ab[pp * 128 + n8];
  }
  __syncthreads();

  int gg = t >> 6;
  int lane = t & 63;
  int lm = lane & 15, lq = lane >> 4;

  bf16x8 Af[3][4];
#pragma unroll
  for (int ct = 0; ct < 3; ++ct)
#pragma unroll
    for (int K = 0; K < 4; ++K)
      Af[ct][K] = *reinterpret_cast<const bf16x8*>(
          &Ws[(gg * 48 + ct * 16 + lm) * 136 + K * 32 + lq * 8]);

  f32x4 Cf[3][4];
#pragma unroll
  for (int ct = 0; ct < 3; ++ct)
#pragma unroll
    for (int pt = 0; pt < 4; ++pt) Cf[ct][pt] = (f32x4)(0.f);

#pragma unroll
  for (int pt = 0; pt < 4; ++pt) {
    bf16x8 Bf[4];
#pragma unroll
    for (int K = 0; K < 4; ++K)
      Bf[K] = *reinterpret_cast<const bf16x8*>(
          &As[(pt * 16 + lm) * 136 + K * 32 + lq * 8]);
#pragma unroll
    for (int ct = 0; ct < 3; ++ct)
#pragma unroll
      for (int K = 0; K < 4; ++K)
        Cf[ct][pt] = __builtin_amdgcn_mfma_f32_16x16x32_bf16(
            Af[ct][K], Bf[K], Cf[ct][pt], 0, 0, 0);
  }
  __syncthreads();

#pragma unroll
  for (int ct = 0; ct < 3; ++ct)
#pragma unroll
    for (int pt = 0; pt < 4; ++pt) {
      float* dst = &Ts[(gg * 64 + pt * 16 + lm) * 52 + ct * 16 + lq * 4];
      *(float4*)dst = *(float4*)&Cf[ct][pt];
    }
#pragma unroll
  for (int i = 0; i < 12; ++i) {
    int l = i * 256 + t;
    int chl = l >> 6, x = l & 63;
    int g2 = chl / 12, rem = chl % 12;
    int cj = rem / 3, tap = rem % 3;
    int ch = (quad * 4 + g2) * 4 + cj;
    float v = 0.f;
    if (dirH) {
      int xx = x + tap - 1;
      if (xx >= 0 && xx < 64) v = in[((size_t)b * 256 + ch) * P_ + p0 + xx];
    } else {
      int yy = y + tap - 1;
      if (yy >= 0 && yy < 64) v = in[((size_t)b * 256 + ch) * P_ + yy * 64 + x];
    }
    ufs[l] = v;
  }
  __syncthreads();

  int x = t & 63;
  int g2 = t >> 6;
  float u[12];
#pragma unroll
  for (int j = 0; j < 12; ++j) u[j] = ufs[(g2 * 12 + j) * 64 + x];
  const float* Tp = &Ts[(g2 * 64 + x) * 52];
#pragma unroll
  for (int i = 0; i < 4; ++i) {
    float4 a0 = *(const float4*)&Tp[i * 12 + 0];
    float4 a1 = *(const float4*)&Tp[i * 12 + 4];
    float4 a2 = *(const float4*)&Tp[i * 12 + 8];
    float s = a0.x * u[0] + a0.y * u[1] + a0.z * u[2] + a0.w * u[3]
            + a1.x * u[4] + a1.y * u[5] + a1.z * u[6] + a1.w * u[7]
            + a2.x * u[8] + a2.y * u[9] + a2.z * u[10] + a2.w * u[11];
    int ch = (quad * 4 + g2) * 4 + i;
    size_t oidx = ((size_t)b * 256 + ch) * P_ + p0 + x;
    if (dirH) {
      out[oidx] = (s + bias_t[oidx]) * ga1[ch] + uf_ep[oidx];
    } else {
      out[oidx] = s;
    }
  }
}

extern "C" void kernel_launch(void* const* d_in, const int* in_sizes, int n_in,
                              void* d_out, int out_size, void* d_ws, size_t ws_size,
                              hipStream_t stream) {
  const float* x      = (const float*)d_in[0];
  const float* dw1_w  = (const float*)d_in[1];
  const float* dw2_w  = (const float*)d_in[2];
  const float* proj_w = (const float*)d_in[3];
  const float* lka0_w = (const float*)d_in[4];
  const float* lkas_w = (const float*)d_in[5];
  const float* lka1_w = (const float*)d_in[6];
  const float* lka1_b = (const float*)d_in[7];
  const float* sca_w  = (const float*)d_in[8];
  const float* sca_b  = (const float*)d_in[9];
  const float* c1a_w  = (const float*)d_in[10];
  const float* c1b_w  = (const float*)d_in[11];
  const float* c2a_w  = (const float*)d_in[12];
  const float* c2a_b  = (const float*)d_in[13];
  const float* c2b_w  = (const float*)d_in[14];
  const float* c2b_b  = (const float*)d_in[15];
  const float* c211_w = (const float*)d_in[16];
  const float* c211_b = (const float*)d_in[17];
  const float* w_cb   = (const float*)d_in[18];
  const float* b_cb   = (const float*)d_in[19];
  const float* attg   = (const float*)d_in[20];
  const float* ga1    = (const float*)d_in[21];
  float* out = (float*)d_out;

  const size_t NCHW = 2u * 256u * P_;
  float* ws = (float*)d_ws;
  size_t off = 0;
  float* meanb = ws + off; off += 512;
  float* scab  = ws + off; off += 512;
  float* B1 = ws + off; off += NCHW;   // dw1-out -> lka
  float* B2 = ws + off; off += NCHW;   // x1
  float* B3 = ws + off; off += NCHW;   // lkas -> c1a-out -> bias_t
  float* B4 = ws + off; off += NCHW;   // xh
  float* B5 = ws + off; off += NCHW;   // uf
  float* B6 = ws + off; off += NCHW;   // x2
  float* sb   = ws + off; off += 2u * 16u * P_;   // gated
  float* att0 = ws + off; off += 2u * 128u * P_;  // att
  ushort* wT    = (ushort*)(ws + off); off += 393216;   // [6144][128] bf16
  ushort* W5h   = (ushort*)(ws + off); off += 147456;   // 5 weights hi
  ushort* W5l   = (ushort*)(ws + off); off += 147456;
  ushort* bth   = (ushort*)(ws + off); off += 16384;    // b_cb^T hi [256][128]
  ushort* btl   = (ushort*)(ws + off); off += 16384;
  ushort* XTxh  = (ushort*)(ws + off); off += 1048576;  // x^T  [2][P][256]
  ushort* XTxl  = (ushort*)(ws + off); off += 1048576;
  ushort* XT2h  = (ushort*)(ws + off); off += 1048576;  // lkas^T
  ushort* XT2l  = (ushort*)(ws + off); off += 1048576;
  ushort* XT3h  = (ushort*)(ws + off); off += 1048576;  // product^T
  ushort* XT3l  = (ushort*)(ws + off); off += 1048576;
  ushort* attTh = (ushort*)(ws + off); off += 524288;   // att^T [2][P][128]
  ushort* attTl = (ushort*)(ws + off); off += 524288;

  const ushort* Wdw1h  = W5h,          *Wdw1l  = W5l;
  const ushort* Wlka1h = W5h + 65536,  *Wlka1l = W5l + 65536;
  const ushort* Wc1ah  = W5h + 131072, *Wc1al  = W5l + 131072;
  const ushort* Wprojh = W5h + 196608, *Wprojl = W5l + 196608;
  const ushort* Wc211h = W5h + 262144, *Wc211l = W5l + 262144;

  dim3 blk(256);
  dim3 gg256(64, 4, 2);   // gemm M=256
  dim3 gg128(64, 2, 2);   // gemm M=128
  dim3 gx256(64, 2, 2);   // xsplit K=256
  dim3 gx128(64, 1, 2);   // xsplit K=128

  // weight prep (w_cb^T, 5 weight splits, b_cb^T)
  prep_kernel<<<244, blk, 0, stream>>>(w_cb, dw1_w, lka1_w, c1a_w, proj_w,
                                       c211_w, b_cb, wT, W5h, W5l, bth, btl);

  // sca branch
  mean_kernel<<<512, blk, 0, stream>>>(x, meanb);
  sca_kernel<<<2, blk, 0, stream>>>(meanb, sca_w, sca_b, scab);

  // x^T split (serves dw1, c1a, c211)
  xsplit_kernel<<<gx256, blk, 0, stream>>>(x, XTxh, XTxl, 256);

  // x1 = dw2(dw1(x))
  gemm_bf16s_kernel<<<gg256, blk, 0, stream>>>(Wdw1h, Wdw1l, XTxh, XTxl,
                                               nullptr, B1, 256, 256);
  dwplane_kernel<3, 1, 1><<<512, blk, 0, stream>>>(B1, dw2_w, B2);

  // lka = lka1(lkas(lka0(x)))
  lka_fused_kernel<<<512, blk, 0, stream>>>(x, lka0_w, lkas_w, B3);
  xsplit_kernel<<<gx256, blk, 0, stream>>>(B3, XT2h, XT2l, 256);
  gemm_bf16s_kernel<<<gg256, blk, 0, stream>>>(Wlka1h, Wlka1l, XT2h, XT2l,
                                               lka1_b, B1, 256, 256);

  // uf = c1b(c1a(x))
  gemm_bf16s_kernel<<<gg256, blk, 0, stream>>>(Wc1ah, Wc1al, XTxh, XTxl,
                                               nullptr, B3, 256, 256);
  dwplane_kernel<3, 1, 1><<<512, blk, 0, stream>>>(B3, c1b_w, B5);

  // att = c2b(gate(c2a(x))) * gamma + c211(x)
  c2a_gate_kernel<<<512, blk, 0, stream>>>(x, c2a_w, c2a_b, sb);
  gemm_bf16s_kernel<<<gg128, blk, 0, stream>>>(Wc211h, Wc211l, XTxh, XTxl,
                                               c211_b, att0, 128, 256);
  conv1x1_kernel<<<gg128, blk, 0, stream>>>(sb, c2b_w, c2b_b, att0, 128, 16,
                                            attg, att0);

  // att^T split (hi feeds ikba, hi+lo feed bias_t gemm)
  xsplit_kernel<<<gx128, blk, 0, stream>>>(att0, attTh, attTl, 128);

  // bias_t[b,c,p] = sum_n b_cb[n,c] * att[b,n,p]
  gemm_bf16s_kernel<<<gg256, blk, 0, stream>>>(bth, btl, attTh, attTl,
                                               nullptr, B3, 256, 128);

  // IKBA vertical then horizontal
  dim3 gik(64, 16, 2);
  ikba_mfma_kernel<<<gik, blk, 0, stream>>>(B5, attTh, wT, nullptr, nullptr,
                                            nullptr, B4, 0, 0);
  ikba_mfma_kernel<<<gik, blk, 0, stream>>>(B4, attTh, wT, B3, B5, ga1,
                                            B6, 1, 3072);

  // out = proj(x1 * x2 * sca * lka)
  prodsplit_kernel<<<gx256, blk, 0, stream>>>(B2, B6, scab, B1, XT3h, XT3l);
  gemm_bf16s_kernel<<<gg256, blk, 0, stream>>>(Wprojh, Wprojl, XT3h, XT3l,
                                               nullptr, out, 256, 256);
}

// Round 5
// 273.231 us; speedup vs baseline: 2.8890x; 1.1083x over previous
//
#include <hip/hip_runtime.h>
#include <cstddef>

#define P_ 4096   // H*W
#define HW_ 64

typedef __bf16 bf16x8 __attribute__((ext_vector_type(8)));
typedef float f32x4 __attribute__((ext_vector_type(4)));

__device__ inline ushort f2bf(float f) {
  unsigned u = __float_as_uint(f);
  unsigned r = (u + 0x7FFFu + ((u >> 16) & 1u)) >> 16;
  return (ushort)r;
}
__device__ inline float bf2f(ushort h) {
  return __uint_as_float(((unsigned)h) << 16);
}
__device__ inline unsigned pack2(ushort a, ushort b) {
  return (unsigned)a | ((unsigned)b << 16);
}

// ---------------- prep (w_cb^T, 5 weight splits, b_cb^T) + mean ----------------
// grid 756: [0,96) wT; [96,240) weight splits; [240,244) b_cb^T; [244,756) mean
__global__ __launch_bounds__(256) void prep_mean_kernel(
    const float* __restrict__ w_cb, const float* __restrict__ dw1_w,
    const float* __restrict__ lka1_w, const float* __restrict__ c1a_w,
    const float* __restrict__ proj_w, const float* __restrict__ c211_w,
    const float* __restrict__ b_cb, ushort* __restrict__ wT,
    ushort* __restrict__ W5h, ushort* __restrict__ W5l,
    ushort* __restrict__ bth, ushort* __restrict__ btl,
    const float* __restrict__ x, float* __restrict__ mean) {
  __shared__ float T[128][65];
  int blk = blockIdx.x;
  int t = threadIdx.x;
  if (blk < 96) {
    int c0 = blk * 64;
#pragma unroll
    for (int i = 0; i < 32; ++i) {
      int l = i * 256 + t;
      int n = l >> 6, c = l & 63;
      T[n][c] = w_cb[(size_t)n * 6144 + c0 + c];
    }
    __syncthreads();
#pragma unroll
    for (int i = 0; i < 4; ++i) {
      int l = i * 256 + t;
      int c = l >> 4, n8 = (l & 15) << 3;
      ushort v[8];
#pragma unroll
      for (int u = 0; u < 8; ++u) v[u] = f2bf(T[n8 + u][c]);
      *(uint4*)&wT[(size_t)(c0 + c) * 128 + n8] = *(uint4*)v;
    }
  } else if (blk < 240) {
    int f = (blk - 96) * 2048 + t * 8;
    const float* srcs[5] = {dw1_w, lka1_w, c1a_w, proj_w, c211_w};
    const int base[6] = {0, 65536, 131072, 196608, 262144, 294912};
    int r = 0;
    while (f >= base[r + 1]) ++r;
    const float* s = srcs[r] + (f - base[r]);
    float4 a = *(const float4*)s;
    float4 b4 = *(const float4*)(s + 4);
    float vv[8] = {a.x, a.y, a.z, a.w, b4.x, b4.y, b4.z, b4.w};
    ushort vh[8], vl[8];
#pragma unroll
    for (int u = 0; u < 8; ++u) {
      ushort h = f2bf(vv[u]);
      vh[u] = h;
      vl[u] = f2bf(vv[u] - bf2f(h));
    }
    *(uint4*)&W5h[f] = *(uint4*)vh;
    *(uint4*)&W5l[f] = *(uint4*)vl;
  } else if (blk < 244) {
    int c0 = (blk - 240) * 64;
#pragma unroll
    for (int i = 0; i < 32; ++i) {
      int l = i * 256 + t;
      int n = l >> 6, c = l & 63;
      T[n][c] = b_cb[(size_t)n * 256 + c0 + c];
    }
    __syncthreads();
#pragma unroll
    for (int i = 0; i < 4; ++i) {
      int l = i * 256 + t;
      int c = l >> 4, n8 = (l & 15) << 3;
      ushort vh[8], vl[8];
#pragma unroll
      for (int u = 0; u < 8; ++u) {
        float fv = T[n8 + u][c];
        ushort h = f2bf(fv);
        vh[u] = h;
        vl[u] = f2bf(fv - bf2f(h));
      }
      *(uint4*)&bth[(size_t)(c0 + c) * 128 + n8] = *(uint4*)vh;
      *(uint4*)&btl[(size_t)(c0 + c) * 128 + n8] = *(uint4*)vl;
    }
  } else {
    int bc = blk - 244;
    const float* xp = x + (size_t)bc * P_;
    float s = 0.f;
    for (int i = t; i < P_; i += 256) s += xp[i];
    float* red = (float*)T;
    red[t] = s;
    __syncthreads();
    for (int off2 = 128; off2 > 0; off2 >>= 1) {
      if (t < off2) red[t] += red[t + off2];
      __syncthreads();
    }
    if (t == 0) mean[bc] = red[0] * (1.f / P_);
  }
}

// ---------------- sca + x^T split ----------------
// grid 258: [0,256) xsplit of x (K=256); [256,258) sca
__global__ __launch_bounds__(256) void sca_xsplit_kernel(
    const float* __restrict__ x, ushort* __restrict__ dh,
    ushort* __restrict__ dl, const float* __restrict__ mean,
    const float* __restrict__ w, const float* __restrict__ bias,
    float* __restrict__ sca) {
  __shared__ float T[128][65];
  int blk = blockIdx.x;
  int t = threadIdx.x;
  if (blk < 256) {
    const int K = 256;
    int p0 = (blk & 63) * 64;
    int kb = (blk >> 6) & 1;
    int b = blk >> 7;
    const float* sb = x + ((size_t)b * K + kb * 128) * P_;
    ushort* dhb = dh + (size_t)b * P_ * K + (size_t)kb * 128;
    ushort* dlb = dl + (size_t)b * P_ * K + (size_t)kb * 128;
#pragma unroll
    for (int i = 0; i < 32; ++i) {
      int l = i * 256 + t;
      int n = l >> 6, c = l & 63;
      T[n][c] = sb[(size_t)n * P_ + p0 + c];
    }
    __syncthreads();
#pragma unroll
    for (int i = 0; i < 4; ++i) {
      int l = i * 256 + t;
      int c = l >> 4, n8 = (l & 15) << 3;
      ushort vh[8], vl[8];
#pragma unroll
      for (int u = 0; u < 8; ++u) {
        float f = T[n8 + u][c];
        ushort h = f2bf(f);
        vh[u] = h;
        vl[u] = f2bf(f - bf2f(h));
      }
      *(uint4*)&dhb[(size_t)(p0 + c) * K + n8] = *(uint4*)vh;
      *(uint4*)&dlb[(size_t)(p0 + c) * K + n8] = *(uint4*)vl;
    }
  } else {
    int b = blk - 256, c = t;
    const float* mb = mean + b * 256;
    const float* wr = w + c * 256;
    float s = bias[c];
    for (int k = 0; k < 256; ++k) s += wr[k] * mb[k];
    sca[b * 256 + c] = s;
  }
}

// ---------------- generic xsplit: [K][P] fp32 -> [P][K] bf16 hi/lo ----------
__global__ __launch_bounds__(256) void xsplit_kernel(
    const float* __restrict__ src, ushort* __restrict__ dh,
    ushort* __restrict__ dl, int K) {
  int p0 = blockIdx.x * 64;
  int kb = blockIdx.y;
  int b = blockIdx.z;
  const float* sb = src + ((size_t)b * K + kb * 128) * P_;
  ushort* dhb = dh + (size_t)b * P_ * K + (size_t)kb * 128;
  ushort* dlb = dl + (size_t)b * P_ * K + (size_t)kb * 128;
  __shared__ float T[128][65];
  int t = threadIdx.x;
#pragma unroll
  for (int i = 0; i < 32; ++i) {
    int l = i * 256 + t;
    int n = l >> 6, c = l & 63;
    T[n][c] = sb[(size_t)n * P_ + p0 + c];
  }
  __syncthreads();
#pragma unroll
  for (int i = 0; i < 4; ++i) {
    int l = i * 256 + t;
    int c = l >> 4, n8 = (l & 15) << 3;
    ushort vh[8], vl[8];
#pragma unroll
    for (int u = 0; u < 8; ++u) {
      float f = T[n8 + u][c];
      ushort h = f2bf(f);
      vh[u] = h;
      vl[u] = f2bf(f - bf2f(h));
    }
    *(uint4*)&dhb[(size_t)(p0 + c) * K + n8] = *(uint4*)vh;
    *(uint4*)&dlb[(size_t)(p0 + c) * K + n8] = *(uint4*)vl;
  }
}

// ---------------- split-bf16 MFMA GEMM (generic) ----------------
__global__ __launch_bounds__(256) void gemm_bf16s_kernel(
    const ushort* __restrict__ Wh, const ushort* __restrict__ Wl,
    const ushort* __restrict__ Xh, const ushort* __restrict__ Xl,
    const float* __restrict__ bias, float* __restrict__ out, int M, int K) {
  int p0 = blockIdx.x * 64, m0 = blockIdx.y * 64, b = blockIdx.z;
  __shared__ __align__(16) ushort Wsh[64 * 72];
  __shared__ __align__(16) ushort Wsl[64 * 72];
  __shared__ __align__(16) ushort Xsh[64 * 72];
  __shared__ __align__(16) ushort Xsl[64 * 72];
  int t = threadIdx.x;
  int w = t >> 6, lane = t & 63, lm = lane & 15, lq = lane >> 4;
  f32x4 C[4];
#pragma unroll
  for (int pt = 0; pt < 4; ++pt) C[pt] = (f32x4)(0.f);
  const ushort* Whb = Wh + (size_t)m0 * K;
  const ushort* Wlb = Wl + (size_t)m0 * K;
  const ushort* Xhb = Xh + ((size_t)b * P_ + p0) * K;
  const ushort* Xlb = Xl + ((size_t)b * P_ + p0) * K;
  for (int k0 = 0; k0 < K; k0 += 64) {
#pragma unroll
    for (int i = 0; i < 2; ++i) {
      int u = i * 256 + t;
      int row = u >> 3, k8 = (u & 7) * 8;
      *(uint4*)&Wsh[row * 72 + k8] = *(const uint4*)&Whb[(size_t)row * K + k0 + k8];
      *(uint4*)&Wsl[row * 72 + k8] = *(const uint4*)&Wlb[(size_t)row * K + k0 + k8];
      *(uint4*)&Xsh[row * 72 + k8] = *(const uint4*)&Xhb[(size_t)row * K + k0 + k8];
      *(uint4*)&Xsl[row * 72 + k8] = *(const uint4*)&Xlb[(size_t)row * K + k0 + k8];
    }
    __syncthreads();
#pragma unroll
    for (int kt = 0; kt < 2; ++kt) {
      bf16x8 Ah = *(const bf16x8*)&Wsh[(w * 16 + lm) * 72 + kt * 32 + lq * 8];
      bf16x8 Al = *(const bf16x8*)&Wsl[(w * 16 + lm) * 72 + kt * 32 + lq * 8];
#pragma unroll
      for (int pt = 0; pt < 4; ++pt) {
        bf16x8 Bh = *(const bf16x8*)&Xsh[(pt * 16 + lm) * 72 + kt * 32 + lq * 8];
        bf16x8 Bl = *(const bf16x8*)&Xsl[(pt * 16 + lm) * 72 + kt * 32 + lq * 8];
        C[pt] = __builtin_amdgcn_mfma_f32_16x16x32_bf16(Ah, Bh, C[pt], 0, 0, 0);
        C[pt] = __builtin_amdgcn_mfma_f32_16x16x32_bf16(Al, Bh, C[pt], 0, 0, 0);
        C[pt] = __builtin_amdgcn_mfma_f32_16x16x32_bf16(Ah, Bl, C[pt], 0, 0, 0);
      }
    }
    __syncthreads();
  }
#pragma unroll
  for (int pt = 0; pt < 4; ++pt) {
    int p = p0 + pt * 16 + lm;
#pragma unroll
    for (int r = 0; r < 4; ++r) {
      int m = m0 + w * 16 + lq * 4 + r;
      float v = C[pt][r];
      if (bias) v += bias[m];
      out[((size_t)b * M + m) * P_ + p] = v;
    }
  }
}

// ---------------- triple GEMM on shared X^T(x): dw1 / c1a / c211 ------------
// grid (64, 10, 2): y 0-3 dw1->B1, 4-7 c1a->B3, 8-9 c211(+bias)->att0
__global__ __launch_bounds__(256) void gemm3_kernel(
    const ushort* __restrict__ Xh, const ushort* __restrict__ Xl,
    const ushort* __restrict__ W5h, const ushort* __restrict__ W5l,
    const float* __restrict__ c211_b, float* __restrict__ B1,
    float* __restrict__ B3, float* __restrict__ att0) {
  const int K = 256;
  int my = blockIdx.y;
  const ushort *Wh, *Wl;
  float* out;
  const float* bias = nullptr;
  int M, m0;
  if (my < 4) {
    Wh = W5h; Wl = W5l; out = B1; M = 256; m0 = my * 64;
  } else if (my < 8) {
    Wh = W5h + 131072; Wl = W5l + 131072; out = B3; M = 256; m0 = (my - 4) * 64;
  } else {
    Wh = W5h + 262144; Wl = W5l + 262144; out = att0; M = 128;
    m0 = (my - 8) * 64; bias = c211_b;
  }
  int p0 = blockIdx.x * 64, b = blockIdx.z;
  __shared__ __align__(16) ushort Wsh[64 * 72];
  __shared__ __align__(16) ushort Wsl[64 * 72];
  __shared__ __align__(16) ushort Xsh[64 * 72];
  __shared__ __align__(16) ushort Xsl[64 * 72];
  int t = threadIdx.x;
  int w = t >> 6, lane = t & 63, lm = lane & 15, lq = lane >> 4;
  f32x4 C[4];
#pragma unroll
  for (int pt = 0; pt < 4; ++pt) C[pt] = (f32x4)(0.f);
  const ushort* Whb = Wh + (size_t)m0 * K;
  const ushort* Wlb = Wl + (size_t)m0 * K;
  const ushort* Xhb = Xh + ((size_t)b * P_ + p0) * K;
  const ushort* Xlb = Xl + ((size_t)b * P_ + p0) * K;
  for (int k0 = 0; k0 < K; k0 += 64) {
#pragma unroll
    for (int i = 0; i < 2; ++i) {
      int u = i * 256 + t;
      int row = u >> 3, k8 = (u & 7) * 8;
      *(uint4*)&Wsh[row * 72 + k8] = *(const uint4*)&Whb[(size_t)row * K + k0 + k8];
      *(uint4*)&Wsl[row * 72 + k8] = *(const uint4*)&Wlb[(size_t)row * K + k0 + k8];
      *(uint4*)&Xsh[row * 72 + k8] = *(const uint4*)&Xhb[(size_t)row * K + k0 + k8];
      *(uint4*)&Xsl[row * 72 + k8] = *(const uint4*)&Xlb[(size_t)row * K + k0 + k8];
    }
    __syncthreads();
#pragma unroll
    for (int kt = 0; kt < 2; ++kt) {
      bf16x8 Ah = *(const bf16x8*)&Wsh[(w * 16 + lm) * 72 + kt * 32 + lq * 8];
      bf16x8 Al = *(const bf16x8*)&Wsl[(w * 16 + lm) * 72 + kt * 32 + lq * 8];
#pragma unroll
      for (int pt = 0; pt < 4; ++pt) {
        bf16x8 Bh = *(const bf16x8*)&Xsh[(pt * 16 + lm) * 72 + kt * 32 + lq * 8];
        bf16x8 Bl = *(const bf16x8*)&Xsl[(pt * 16 + lm) * 72 + kt * 32 + lq * 8];
        C[pt] = __builtin_amdgcn_mfma_f32_16x16x32_bf16(Ah, Bh, C[pt], 0, 0, 0);
        C[pt] = __builtin_amdgcn_mfma_f32_16x16x32_bf16(Al, Bh, C[pt], 0, 0, 0);
        C[pt] = __builtin_amdgcn_mfma_f32_16x16x32_bf16(Ah, Bl, C[pt], 0, 0, 0);
      }
    }
    __syncthreads();
  }
#pragma unroll
  for (int pt = 0; pt < 4; ++pt) {
    int p = p0 + pt * 16 + lm;
#pragma unroll
    for (int r = 0; r < 4; ++r) {
      int m = m0 + w * 16 + lq * 4 + r;
      float v = C[pt][r];
      if (bias) v += bias[m];
      out[((size_t)b * M + m) * P_ + p] = v;
    }
  }
}

// ---------------- lka depthwise chain + c2a_gate, one dispatch ----------------
__global__ __launch_bounds__(256) void lka_c2a_kernel(
    const float* __restrict__ in, const float* __restrict__ w0,
    const float* __restrict__ w1, float* __restrict__ outlka,
    const float* __restrict__ c2aw, const float* __restrict__ c2ab,
    float* __restrict__ sgate) {
  constexpr int PN0 = 68;
  constexpr int PN1 = 82;
  __shared__ float p0[PN0 * PN0];
  __shared__ float p1[PN1 * PN1];
  int t = threadIdx.x;
  if (blockIdx.x < 512) {
    int bc = blockIdx.x;
    const float* ib = in + (size_t)bc * P_;
    for (int i = t; i < PN0 * PN0; i += 256) p0[i] = 0.f;
    for (int i = t; i < PN1 * PN1; i += 256) p1[i] = 0.f;
    __syncthreads();
#pragma unroll
    for (int i = 0; i < 4; ++i) {
      int l = i * 1024 + t * 4;
      int y = l >> 6, xx = l & 63;
      float4 v = *(const float4*)(ib + l);
      float* d = &p0[(y + 2) * PN0 + 2 + xx];
      d[0] = v.x; d[1] = v.y; d[2] = v.z; d[3] = v.w;
    }
    float wr0[25];
    {
      const float* wp = w0 + (size_t)(bc & 255) * 25;
#pragma unroll
      for (int i = 0; i < 25; ++i) wr0[i] = wp[i];
    }
    __syncthreads();
#pragma unroll
    for (int r = 0; r < 16; ++r) {
      int l = r * 256 + t;
      int y = l >> 6, xx = l & 63;
      float s = 0.f;
#pragma unroll
      for (int dy = 0; dy < 5; ++dy)
#pragma unroll
        for (int dx = 0; dx < 5; ++dx)
          s += wr0[dy * 5 + dx] * p0[(y + dy) * PN0 + xx + dx];
      p1[(y + 9) * PN1 + 9 + xx] = s;
    }
    float wr1[49];
    {
      const float* wp = w1 + (size_t)(bc & 255) * 49;
#pragma unroll
      for (int i = 0; i < 49; ++i) wr1[i] = wp[i];
    }
    __syncthreads();
    float* ob = outlka + (size_t)bc * P_;
#pragma unroll
    for (int r = 0; r < 16; ++r) {
      int l = r * 256 + t;
      int y = l >> 6, xx = l & 63;
      float s = 0.f;
#pragma unroll
      for (int dy = 0; dy < 7; ++dy)
#pragma unroll
        for (int dx = 0; dx < 7; ++dx)
          s += wr1[dy * 7 + dx] * p1[(y + dy * 3) * PN1 + xx + dx * 3];
      ob[l] = s;
    }
  } else {
    int idx = (blockIdx.x - 512) * 256 + t;
    int xq = idx & 63, y = (idx >> 6) & 63, go = (idx >> 12) & 15, b = idx >> 16;
    float acc[2];
#pragma unroll
    for (int h = 0; h < 2; ++h) {
      int gc = go + h * 16;
      const float* wr = c2aw + gc * 72;
      const float* xb = in + ((size_t)b * 256 + gc * 8) * P_;
      float ss = c2ab[gc];
      for (int ci = 0; ci < 8; ++ci)
        for (int dy = 0; dy < 3; ++dy) {
          int yy = y + dy - 1;
          if (yy < 0 || yy >= 64) continue;
          for (int dx = 0; dx < 3; ++dx) {
            int xx = xq + dx - 1;
            if (xx < 0 || xx >= 64) continue;
            ss += wr[ci * 9 + dy * 3 + dx] * xb[(size_t)ci * P_ + yy * 64 + xx];
          }
        }
      acc[h] = ss;
    }
    sgate[idx] = acc[0] * acc[1];
  }
}

// ---------------- two 3x3 depthwise planes (dw2 + c1b), one dispatch ----------
__global__ __launch_bounds__(256) void dw2x_kernel(
    const float* __restrict__ in1, const float* __restrict__ w1,
    float* __restrict__ out1, const float* __restrict__ in2,
    const float* __restrict__ w2, float* __restrict__ out2) {
  constexpr int PN = 66;
  __shared__ float pl[PN * PN];
  int which = blockIdx.x >> 9;
  int bc = blockIdx.x & 511;
  const float* in = which ? in2 : in1;
  const float* w = which ? w2 : w1;
  float* out = which ? out2 : out1;
  int t = threadIdx.x;
  const float* ib = in + (size_t)bc * P_;
  for (int i = t; i < PN * PN; i += 256) pl[i] = 0.f;
  __syncthreads();
#pragma unroll
  for (int i = 0; i < 4; ++i) {
    int l = i * 1024 + t * 4;
    int y = l >> 6, xx = l & 63;
    float4 v = *(const float4*)(ib + l);
    float* d = &pl[(y + 1) * PN + 1 + xx];
    d[0] = v.x; d[1] = v.y; d[2] = v.z; d[3] = v.w;
  }
  float wr[9];
  const float* wp = w + (size_t)(bc & 255) * 9;
#pragma unroll
  for (int i = 0; i < 9; ++i) wr[i] = wp[i];
  __syncthreads();
  float* ob = out + (size_t)bc * P_;
#pragma unroll
  for (int r = 0; r < 16; ++r) {
    int l = r * 256 + t;
    int y = l >> 6, xx = l & 63;
    float s = 0.f;
#pragma unroll
    for (int dy = 0; dy < 3; ++dy)
#pragma unroll
      for (int dx = 0; dx < 3; ++dx)
        s += wr[dy * 3 + dx] * pl[(y + dy) * PN + xx + dx];
    ob[l] = s;
  }
}

// ---------------- c2b (K=16 fp32) + gamma + res, transposed-split output ------
// grid (64, 2, 2). Writes attT hi/lo [b][P][128] directly.
__global__ __launch_bounds__(256) void c2b_t_kernel(
    const float* __restrict__ in, const float* __restrict__ W,
    const float* __restrict__ bias, const float* __restrict__ gamma,
    const float* __restrict__ res, ushort* __restrict__ outh,
    ushort* __restrict__ outl) {
  const int K = 16, M = 128;
  int p0 = blockIdx.x * 64;
  int m0 = blockIdx.y * 64;
  int b  = blockIdx.z;
  __shared__ float Ws[16][68];
  __shared__ float Xs[16][68];
  int tid = threadIdx.x;
  int tm = tid >> 4, tp = tid & 15;
  float acc[4][4] = {};
  const float* inb = in + (size_t)b * K * P_;
  {
    int kk = tid >> 4, pq = (tid & 15) << 2;
    float4 v = *(const float4*)(inb + (size_t)kk * P_ + p0 + pq);
    *(float4*)&Xs[kk][pq] = v;
  }
  {
    int mm = tid >> 2, kq = (tid & 3) << 2;
    float4 v = *(const float4*)(W + (size_t)(m0 + mm) * K + kq);
    Ws[kq + 0][mm] = v.x; Ws[kq + 1][mm] = v.y;
    Ws[kq + 2][mm] = v.z; Ws[kq + 3][mm] = v.w;
  }
  __syncthreads();
#pragma unroll
  for (int kk = 0; kk < 16; ++kk) {
    const float4 wv = *(const float4*)&Ws[kk][tm << 2];
    const float4 xv = *(const float4*)&Xs[kk][tp << 2];
    const float wa[4] = {wv.x, wv.y, wv.z, wv.w};
    const float xa[4] = {xv.x, xv.y, xv.z, xv.w};
#pragma unroll
    for (int i = 0; i < 4; ++i)
#pragma unroll
      for (int j = 0; j < 4; ++j) acc[i][j] += wa[i] * xa[j];
  }
  float val[4][4];
#pragma unroll
  for (int i = 0; i < 4; ++i) {
    int m = m0 + (tm << 2) + i;
    float bv = bias[m], gm = gamma[m];
    float4 rv = *(const float4*)(res + ((size_t)b * M + m) * P_ + p0 + (tp << 2));
    val[i][0] = (acc[i][0] + bv) * gm + rv.x;
    val[i][1] = (acc[i][1] + bv) * gm + rv.y;
    val[i][2] = (acc[i][2] + bv) * gm + rv.z;
    val[i][3] = (acc[i][3] + bv) * gm + rv.w;
  }
#pragma unroll
  for (int j = 0; j < 4; ++j) {
    int p = p0 + (tp << 2) + j;
    ushort vh[4], vl[4];
#pragma unroll
    for (int i = 0; i < 4; ++i) {
      float f = val[i][j];
      ushort h = f2bf(f);
      vh[i] = h;
      vl[i] = f2bf(f - bf2f(h));
    }
    size_t a = ((size_t)b * P_ + p) * 128 + m0 + (tm << 2);
    uint2 hv, lv;
    hv.x = pack2(vh[0], vh[1]); hv.y = pack2(vh[2], vh[3]);
    lv.x = pack2(vl[0], vl[1]); lv.y = pack2(vl[2], vl[3]);
    *(uint2*)&outh[a] = hv;
    *(uint2*)&outl[a] = lv;
  }
}

// ---------------- IKBA: fused MFMA attk-GEMM + unfold apply ----------------
// V pass (dirH=0): out = xh fp32.
// H pass (dirH=1): + in-kernel bias_t MFMA (b_cb^T x att), epilogue computes
// x2 and the full product x1*x2*sca*lka, written as transposed bf16 hi/lo.
__global__ __launch_bounds__(256) void ikba_mfma_kernel(
    const float* __restrict__ in, const ushort* __restrict__ attT,
    const ushort* __restrict__ Wt, int dirH, int wofs,
    const ushort* __restrict__ bth, const ushort* __restrict__ btl,
    const float* __restrict__ uf_ep, const float* __restrict__ ga1,
    const float* __restrict__ x1, const float* __restrict__ lka,
    const float* __restrict__ sca, ushort* __restrict__ pXh,
    ushort* __restrict__ pXl, float* __restrict__ outV) {
  __shared__ __align__(16) char smem[70656];
  ushort* Ws = (ushort*)smem;            // [192][136] bf16, phase 1-2
  ushort* As = (ushort*)(smem + 53248);  // [64][136]  bf16, phase 1-2
  float*  Ts = (float*)smem;             // [4][64][52] fp32, phase 3-4
  float*  ufs = (float*)(smem + 53248);  // [4][4][3][64] fp32, phase 3-4
  float*  bls = (float*)(smem + 65536);  // [64][16] bias tile, phase 3-4 (H)

  int t = threadIdx.x;
  int b = blockIdx.z;
  int quad = blockIdx.y;
  int y = blockIdx.x;
  int p0 = y * 64;

  const ushort* Wg = Wt + ((size_t)wofs + (size_t)quad * 192) * 128;
  const ushort* Ab = attT + ((size_t)b * P_ + p0) * 128;
#pragma unroll
  for (int i = 0; i < 12; ++i) {
    int l = i * 256 + t;
    int c = l >> 4, n8 = (l & 15) << 3;
    *(uint4*)&Ws[c * 136 + n8] = *(const uint4*)&Wg[c * 128 + n8];
  }
#pragma unroll
  for (int i = 0; i < 4; ++i) {
    int l = i * 256 + t;
    int pp = l >> 4, n8 = (l & 15) << 3;
    *(uint4*)&As[pp * 136 + n8] = *(const uint4*)&Ab[pp * 128 + n8];
  }
  __syncthreads();

  int gg = t >> 6;
  int lane = t & 63;
  int lm = lane & 15, lq = lane >> 4;

  bf16x8 Af[3][4];
#pragma unroll
  for (int ct = 0; ct < 3; ++ct)
#pragma unroll
    for (int K = 0; K < 4; ++K)
      Af[ct][K] = *reinterpret_cast<const bf16x8*>(
          &Ws[(gg * 48 + ct * 16 + lm) * 136 + K * 32 + lq * 8]);

  f32x4 Cf[3][4];
#pragma unroll
  for (int ct = 0; ct < 3; ++ct)
#pragma unroll
    for (int pt = 0; pt < 4; ++pt) Cf[ct][pt] = (f32x4)(0.f);

#pragma unroll
  for (int pt = 0; pt < 4; ++pt) {
    bf16x8 Bf[4];
#pragma unroll
    for (int K = 0; K < 4; ++K)
      Bf[K] = *reinterpret_cast<const bf16x8*>(
          &As[(pt * 16 + lm) * 136 + K * 32 + lq * 8]);
#pragma unroll
    for (int ct = 0; ct < 3; ++ct)
#pragma unroll
      for (int K = 0; K < 4; ++K)
        Cf[ct][pt] = __builtin_amdgcn_mfma_f32_16x16x32_bf16(
            Af[ct][K], Bf[K], Cf[ct][pt], 0, 0, 0);
  }

  // bias_t tile via MFMA (H only): wave gg computes p-tile gg, 16 ch of quad.
  f32x4 Cb = (f32x4)(0.f);
  if (dirH) {
#pragma unroll
    for (int K = 0; K < 4; ++K) {
      bf16x8 Bb = *reinterpret_cast<const bf16x8*>(
          &As[(gg * 16 + lm) * 136 + K * 32 + lq * 8]);
      bf16x8 Abh = *(const bf16x8*)&bth[(size_t)(quad * 16 + lm) * 128 + K * 32 + lq * 8];
      bf16x8 Abl = *(const bf16x8*)&btl[(size_t)(quad * 16 + lm) * 128 + K * 32 + lq * 8];
      Cb = __builtin_amdgcn_mfma_f32_16x16x32_bf16(Abh, Bb, Cb, 0, 0, 0);
      Cb = __builtin_amdgcn_mfma_f32_16x16x32_bf16(Abl, Bb, Cb, 0, 0, 0);
    }
  }
  __syncthreads();

#pragma unroll
  for (int ct = 0; ct < 3; ++ct)
#pragma unroll
    for (int pt = 0; pt < 4; ++pt) {
      float* dst = &Ts[(gg * 64 + pt * 16 + lm) * 52 + ct * 16 + lq * 4];
      *(float4*)dst = *(float4*)&Cf[ct][pt];
    }
  if (dirH) {
    // C layout: p_local = gg*16 + lm (col), ch_local = lq*4 + r (row)
    *(float4*)&bls[(gg * 16 + lm) * 16 + lq * 4] = *(float4*)&Cb;
  }
#pragma unroll
  for (int i = 0; i < 12; ++i) {
    int l = i * 256 + t;
    int chl = l >> 6, x = l & 63;
    int g2 = chl / 12, rem = chl % 12;
    int cj = rem / 3, tap = rem % 3;
    int ch = (quad * 4 + g2) * 4 + cj;
    float v = 0.f;
    if (dirH) {
      int xx = x + tap - 1;
      if (xx >= 0 && xx < 64) v = in[((size_t)b * 256 + ch) * P_ + p0 + xx];
    } else {
      int yy = y + tap - 1;
      if (yy >= 0 && yy < 64) v = in[((size_t)b * 256 + ch) * P_ + yy * 64 + x];
    }
    ufs[l] = v;
  }
  __syncthreads();

  int x = t & 63;
  int g2 = t >> 6;
  float u[12];
#pragma unroll
  for (int j = 0; j < 12; ++j) u[j] = ufs[(g2 * 12 + j) * 64 + x];
  const float* Tp = &Ts[(g2 * 64 + x) * 52];
  ushort vh[4], vl[4];
#pragma unroll
  for (int i = 0; i < 4; ++i) {
    float4 a0 = *(const float4*)&Tp[i * 12 + 0];
    float4 a1 = *(const float4*)&Tp[i * 12 + 4];
    float4 a2 = *(const float4*)&Tp[i * 12 + 8];
    float s = a0.x * u[0] + a0.y * u[1] + a0.z * u[2] + a0.w * u[3]
            + a1.x * u[4] + a1.y * u[5] + a1.z * u[6] + a1.w * u[7]
            + a2.x * u[8] + a2.y * u[9] + a2.z * u[10] + a2.w * u[11];
    int ch = (quad * 4 + g2) * 4 + i;
    size_t oidx = ((size_t)b * 256 + ch) * P_ + p0 + x;
    if (dirH) {
      float biasv = bls[x * 16 + g2 * 4 + i];
      float x2 = (s + biasv) * ga1[ch] + uf_ep[oidx];
      float pr = x1[oidx] * x2 * sca[b * 256 + ch] * lka[oidx];
      ushort h = f2bf(pr);
      vh[i] = h;
      vl[i] = f2bf(pr - bf2f(h));
    } else {
      outV[oidx] = s;
    }
  }
  if (dirH) {
    size_t xa = ((size_t)b * P_ + p0 + x) * 256 + quad * 16 + g2 * 4;
    uint2 hv, lv;
    hv.x = pack2(vh[0], vh[1]); hv.y = pack2(vh[2], vh[3]);
    lv.x = pack2(vl[0], vl[1]); lv.y = pack2(vl[2], vl[3]);
    *(uint2*)&pXh[xa] = hv;
    *(uint2*)&pXl[xa] = lv;
  }
}

extern "C" void kernel_launch(void* const* d_in, const int* in_sizes, int n_in,
                              void* d_out, int out_size, void* d_ws, size_t ws_size,
                              hipStream_t stream) {
  const float* x      = (const float*)d_in[0];
  const float* dw1_w  = (const float*)d_in[1];
  const float* dw2_w  = (const float*)d_in[2];
  const float* proj_w = (const float*)d_in[3];
  const float* lka0_w = (const float*)d_in[4];
  const float* lkas_w = (const float*)d_in[5];
  const float* lka1_w = (const float*)d_in[6];
  const float* lka1_b = (const float*)d_in[7];
  const float* sca_w  = (const float*)d_in[8];
  const float* sca_b  = (const float*)d_in[9];
  const float* c1a_w  = (const float*)d_in[10];
  const float* c1b_w  = (const float*)d_in[11];
  const float* c2a_w  = (const float*)d_in[12];
  const float* c2a_b  = (const float*)d_in[13];
  const float* c2b_w  = (const float*)d_in[14];
  const float* c2b_b  = (const float*)d_in[15];
  const float* c211_w = (const float*)d_in[16];
  const float* c211_b = (const float*)d_in[17];
  const float* w_cb   = (const float*)d_in[18];
  const float* b_cb   = (const float*)d_in[19];
  const float* attg   = (const float*)d_in[20];
  const float* ga1    = (const float*)d_in[21];
  float* out = (float*)d_out;

  const size_t NCHW = 2u * 256u * P_;
  float* ws = (float*)d_ws;
  size_t off = 0;
  float* meanb = ws + off; off += 512;
  float* scab  = ws + off; off += 512;
  float* B1 = ws + off; off += NCHW;   // dw1-out -> lka1-out (lka)
  float* B2 = ws + off; off += NCHW;   // x1
  float* B3 = ws + off; off += NCHW;   // c1a-out
  float* B4 = ws + off; off += NCHW;   // xh
  float* B5 = ws + off; off += NCHW;   // uf
  float* B6 = ws + off; off += NCHW;   // lkas-out
  float* sb   = ws + off; off += 2u * 16u * P_;   // gated
  float* att0 = ws + off; off += 2u * 128u * P_;  // c211 out (fp32)
  ushort* wT    = (ushort*)(ws + off); off += 393216;   // [6144][128] bf16
  ushort* W5h   = (ushort*)(ws + off); off += 147456;
  ushort* W5l   = (ushort*)(ws + off); off += 147456;
  ushort* bth   = (ushort*)(ws + off); off += 16384;    // b_cb^T hi [256][128]
  ushort* btl   = (ushort*)(ws + off); off += 16384;
  ushort* XTxh  = (ushort*)(ws + off); off += 1048576;  // x^T [2][P][256]
  ushort* XTxl  = (ushort*)(ws + off); off += 1048576;
  ushort* XT2h  = (ushort*)(ws + off); off += 1048576;  // lkas^T
  ushort* XT2l  = (ushort*)(ws + off); off += 1048576;
  ushort* XT3h  = (ushort*)(ws + off); off += 1048576;  // product^T
  ushort* XT3l  = (ushort*)(ws + off); off += 1048576;
  ushort* attTh = (ushort*)(ws + off); off += 524288;   // att^T [2][P][128]
  ushort* attTl = (ushort*)(ws + off); off += 524288;

  const ushort* Wlka1h = W5h + 65536,  *Wlka1l = W5l + 65536;
  const ushort* Wprojh = W5h + 196608, *Wprojl = W5l + 196608;

  dim3 blk(256);

  // K1: weight prep + mean
  prep_mean_kernel<<<756, blk, 0, stream>>>(w_cb, dw1_w, lka1_w, c1a_w, proj_w,
                                            c211_w, b_cb, wT, W5h, W5l, bth, btl,
                                            x, meanb);
  // K2: sca + x^T split
  sca_xsplit_kernel<<<258, blk, 0, stream>>>(x, XTxh, XTxl, meanb, sca_w, sca_b,
                                             scab);
  // K3: dw1 / c1a / c211 GEMMs, one dispatch
  gemm3_kernel<<<dim3(64, 10, 2), blk, 0, stream>>>(XTxh, XTxl, W5h, W5l, c211_b,
                                                    B1, B3, att0);
  // K4: lka depthwise chain + c2a_gate
  lka_c2a_kernel<<<1024, blk, 0, stream>>>(x, lka0_w, lkas_w, B6, c2a_w, c2a_b, sb);
  // K5: dw2 (B1->B2) + c1b (B3->B5)
  dw2x_kernel<<<1024, blk, 0, stream>>>(B1, dw2_w, B2, B3, c1b_w, B5);
  // K6: lkas^T split
  xsplit_kernel<<<dim3(64, 2, 2), blk, 0, stream>>>(B6, XT2h, XT2l, 256);
  // K7: lka1 GEMM -> B1 (lka)
  gemm_bf16s_kernel<<<dim3(64, 4, 2), blk, 0, stream>>>(Wlka1h, Wlka1l, XT2h,
                                                        XT2l, lka1_b, B1, 256, 256);
  // K8: c2b + gamma + res(c211) -> attT hi/lo (transposed)
  c2b_t_kernel<<<dim3(64, 2, 2), blk, 0, stream>>>(sb, c2b_w, c2b_b, attg, att0,
                                                   attTh, attTl);
  // K9: IKBA vertical
  dim3 gik(64, 16, 2);
  ikba_mfma_kernel<<<gik, blk, 0, stream>>>(B5, attTh, wT, 0, 0, nullptr, nullptr,
                                            nullptr, nullptr, nullptr, nullptr,
                                            nullptr, nullptr, nullptr, B4);
  // K10: IKBA horizontal + bias_t MFMA + product + transposed split
  ikba_mfma_kernel<<<gik, blk, 0, stream>>>(B4, attTh, wT, 1, 3072, bth, btl,
                                            B5, ga1, B2, B1, scab, XT3h, XT3l,
                                            nullptr);
  // K11: proj GEMM -> out
  gemm_bf16s_kernel<<<dim3(64, 4, 2), blk, 0, stream>>>(Wprojh, Wprojl, XT3h,
                                                        XT3l, nullptr, out, 256, 256);
}

// Round 6
// 272.428 us; speedup vs baseline: 2.8976x; 1.0029x over previous
//
#include <hip/hip_runtime.h>
#include <cstddef>

#define P_ 4096   // H*W
#define HW_ 64

typedef __bf16 bf16x8 __attribute__((ext_vector_type(8)));
typedef float f32x4 __attribute__((ext_vector_type(4)));

__device__ inline ushort f2bf(float f) {
  unsigned u = __float_as_uint(f);
  unsigned r = (u + 0x7FFFu + ((u >> 16) & 1u)) >> 16;
  return (ushort)r;
}
__device__ inline float bf2f(ushort h) {
  return __uint_as_float(((unsigned)h) << 16);
}
__device__ inline unsigned pack2(ushort a, ushort b) {
  return (unsigned)a | ((unsigned)b << 16);
}

// ---------------- prep (w_cb^T, 5 weight splits, b_cb^T) + mean ----------------
// grid 756: [0,96) wT; [96,240) weight splits; [240,244) b_cb^T; [244,756) mean
__global__ __launch_bounds__(256) void prep_mean_kernel(
    const float* __restrict__ w_cb, const float* __restrict__ dw1_w,
    const float* __restrict__ lka1_w, const float* __restrict__ c1a_w,
    const float* __restrict__ proj_w, const float* __restrict__ c211_w,
    const float* __restrict__ b_cb, ushort* __restrict__ wT,
    ushort* __restrict__ W5h, ushort* __restrict__ W5l,
    ushort* __restrict__ bth, ushort* __restrict__ btl,
    const float* __restrict__ x, float* __restrict__ mean) {
  __shared__ float T[128][65];
  int blk = blockIdx.x;
  int t = threadIdx.x;
  if (blk < 96) {
    int c0 = blk * 64;
#pragma unroll
    for (int i = 0; i < 32; ++i) {
      int l = i * 256 + t;
      int n = l >> 6, c = l & 63;
      T[n][c] = w_cb[(size_t)n * 6144 + c0 + c];
    }
    __syncthreads();
#pragma unroll
    for (int i = 0; i < 4; ++i) {
      int l = i * 256 + t;
      int c = l >> 4, n8 = (l & 15) << 3;
      ushort v[8];
#pragma unroll
      for (int u = 0; u < 8; ++u) v[u] = f2bf(T[n8 + u][c]);
      *(uint4*)&wT[(size_t)(c0 + c) * 128 + n8] = *(uint4*)v;
    }
  } else if (blk < 240) {
    int f = (blk - 96) * 2048 + t * 8;
    const float* srcs[5] = {dw1_w, lka1_w, c1a_w, proj_w, c211_w};
    const int base[6] = {0, 65536, 131072, 196608, 262144, 294912};
    int r = 0;
    while (f >= base[r + 1]) ++r;
    const float* s = srcs[r] + (f - base[r]);
    float4 a = *(const float4*)s;
    float4 b4 = *(const float4*)(s + 4);
    float vv[8] = {a.x, a.y, a.z, a.w, b4.x, b4.y, b4.z, b4.w};
    ushort vh[8], vl[8];
#pragma unroll
    for (int u = 0; u < 8; ++u) {
      ushort h = f2bf(vv[u]);
      vh[u] = h;
      vl[u] = f2bf(vv[u] - bf2f(h));
    }
    *(uint4*)&W5h[f] = *(uint4*)vh;
    *(uint4*)&W5l[f] = *(uint4*)vl;
  } else if (blk < 244) {
    int c0 = (blk - 240) * 64;
#pragma unroll
    for (int i = 0; i < 32; ++i) {
      int l = i * 256 + t;
      int n = l >> 6, c = l & 63;
      T[n][c] = b_cb[(size_t)n * 256 + c0 + c];
    }
    __syncthreads();
#pragma unroll
    for (int i = 0; i < 4; ++i) {
      int l = i * 256 + t;
      int c = l >> 4, n8 = (l & 15) << 3;
      ushort vh[8], vl[8];
#pragma unroll
      for (int u = 0; u < 8; ++u) {
        float fv = T[n8 + u][c];
        ushort h = f2bf(fv);
        vh[u] = h;
        vl[u] = f2bf(fv - bf2f(h));
      }
      *(uint4*)&bth[(size_t)(c0 + c) * 128 + n8] = *(uint4*)vh;
      *(uint4*)&btl[(size_t)(c0 + c) * 128 + n8] = *(uint4*)vl;
    }
  } else {
    int bc = blk - 244;
    const float* xp = x + (size_t)bc * P_;
    float s = 0.f;
    for (int i = t; i < P_; i += 256) s += xp[i];
    float* red = (float*)T;
    red[t] = s;
    __syncthreads();
    for (int off2 = 128; off2 > 0; off2 >>= 1) {
      if (t < off2) red[t] += red[t + off2];
      __syncthreads();
    }
    if (t == 0) mean[bc] = red[0] * (1.f / P_);
  }
}

// ---------------- device helpers ----------------

// transpose+split one 128k x 64p tile: src [K][P] fp32 -> dst [P][K] bf16 hi/lo
__device__ inline void xsplit_body(const float* sb, ushort* dhb, ushort* dlb,
                                   int p0, int K, char* smem) {
  float (*T)[65] = (float(*)[65])smem;
  int t = threadIdx.x;
#pragma unroll
  for (int i = 0; i < 32; ++i) {
    int l = i * 256 + t;
    int n = l >> 6, c = l & 63;
    T[n][c] = sb[(size_t)n * P_ + p0 + c];
  }
  __syncthreads();
#pragma unroll
  for (int i = 0; i < 4; ++i) {
    int l = i * 256 + t;
    int c = l >> 4, n8 = (l & 15) << 3;
    ushort vh[8], vl[8];
#pragma unroll
    for (int u = 0; u < 8; ++u) {
      float f = T[n8 + u][c];
      ushort h = f2bf(f);
      vh[u] = h;
      vl[u] = f2bf(f - bf2f(h));
    }
    *(uint4*)&dhb[(size_t)(p0 + c) * K + n8] = *(uint4*)vh;
    *(uint4*)&dlb[(size_t)(p0 + c) * K + n8] = *(uint4*)vl;
  }
}

// split-bf16 GEMM 64x64 tile body
__device__ inline void gemm_body(const ushort* Whb, const ushort* Wlb,
                                 const ushort* Xhb, const ushort* Xlb,
                                 const float* bias, float* out, int M, int m0,
                                 int p0, int b, int K, char* smem) {
  ushort* Wsh = (ushort*)smem;
  ushort* Wsl = (ushort*)(smem + 9216);
  ushort* Xsh = (ushort*)(smem + 18432);
  ushort* Xsl = (ushort*)(smem + 27648);
  int t = threadIdx.x;
  int w = t >> 6, lane = t & 63, lm = lane & 15, lq = lane >> 4;
  f32x4 C[4];
#pragma unroll
  for (int pt = 0; pt < 4; ++pt) C[pt] = (f32x4)(0.f);
  for (int k0 = 0; k0 < K; k0 += 64) {
#pragma unroll
    for (int i = 0; i < 2; ++i) {
      int u = i * 256 + t;
      int row = u >> 3, k8 = (u & 7) * 8;
      *(uint4*)&Wsh[row * 72 + k8] = *(const uint4*)&Whb[(size_t)row * K + k0 + k8];
      *(uint4*)&Wsl[row * 72 + k8] = *(const uint4*)&Wlb[(size_t)row * K + k0 + k8];
      *(uint4*)&Xsh[row * 72 + k8] = *(const uint4*)&Xhb[(size_t)row * K + k0 + k8];
      *(uint4*)&Xsl[row * 72 + k8] = *(const uint4*)&Xlb[(size_t)row * K + k0 + k8];
    }
    __syncthreads();
#pragma unroll
    for (int kt = 0; kt < 2; ++kt) {
      bf16x8 Ah = *(const bf16x8*)&Wsh[(w * 16 + lm) * 72 + kt * 32 + lq * 8];
      bf16x8 Al = *(const bf16x8*)&Wsl[(w * 16 + lm) * 72 + kt * 32 + lq * 8];
#pragma unroll
      for (int pt = 0; pt < 4; ++pt) {
        bf16x8 Bh = *(const bf16x8*)&Xsh[(pt * 16 + lm) * 72 + kt * 32 + lq * 8];
        bf16x8 Bl = *(const bf16x8*)&Xsl[(pt * 16 + lm) * 72 + kt * 32 + lq * 8];
        C[pt] = __builtin_amdgcn_mfma_f32_16x16x32_bf16(Ah, Bh, C[pt], 0, 0, 0);
        C[pt] = __builtin_amdgcn_mfma_f32_16x16x32_bf16(Al, Bh, C[pt], 0, 0, 0);
        C[pt] = __builtin_amdgcn_mfma_f32_16x16x32_bf16(Ah, Bl, C[pt], 0, 0, 0);
      }
    }
    __syncthreads();
  }
#pragma unroll
  for (int pt = 0; pt < 4; ++pt) {
    int p = p0 + pt * 16 + lm;
#pragma unroll
    for (int r = 0; r < 4; ++r) {
      int m = m0 + w * 16 + lq * 4 + r;
      float v = C[pt][r];
      if (bias) v += bias[m];
      out[((size_t)b * M + m) * P_ + p] = v;
    }
  }
}

// ---------------- standalone split-bf16 GEMM (proj) ----------------
__global__ __launch_bounds__(256) void gemm_bf16s_kernel(
    const ushort* __restrict__ Wh, const ushort* __restrict__ Wl,
    const ushort* __restrict__ Xh, const ushort* __restrict__ Xl,
    const float* __restrict__ bias, float* __restrict__ out, int M, int K) {
  __shared__ __align__(16) char smem[36864];
  int p0 = blockIdx.x * 64, m0 = blockIdx.y * 64, b = blockIdx.z;
  gemm_body(Wh + (size_t)m0 * K, Wl + (size_t)m0 * K,
            Xh + ((size_t)b * P_ + p0) * K, Xl + ((size_t)b * P_ + p0) * K,
            bias, out, M, m0, p0, b, K, smem);
}

// ---------------- sca + x^T split ----------------
// grid 258: [0,256) xsplit of x (K=256); [256,258) sca
__global__ __launch_bounds__(256) void sca_xsplit_kernel(
    const float* __restrict__ x, ushort* __restrict__ dh,
    ushort* __restrict__ dl, const float* __restrict__ mean,
    const float* __restrict__ w, const float* __restrict__ bias,
    float* __restrict__ sca) {
  __shared__ __align__(16) char smem[33280];
  int blk = blockIdx.x;
  int t = threadIdx.x;
  if (blk < 256) {
    const int K = 256;
    int p0 = (blk & 63) * 64;
    int kb = (blk >> 6) & 1;
    int b = blk >> 7;
    xsplit_body(x + ((size_t)b * K + kb * 128) * P_,
                dh + (size_t)b * P_ * K + (size_t)kb * 128,
                dl + (size_t)b * P_ * K + (size_t)kb * 128, p0, K, smem);
  } else {
    int b = blk - 256, c = t;
    const float* mb = mean + b * 256;
    const float* wr = w + c * 256;
    float s = bias[c];
    for (int k = 0; k < 256; ++k) s += wr[k] * mb[k];
    sca[b * 256 + c] = s;
  }
}

// ---------------- mega kernel 1: gemm3 (dw1/c1a/c211) + lka chain + c2a_gate --
// grid 2304: [0,1280) gemm tiles; [1280,1792) lka chain; [1792,2304) c2a gate
__global__ __launch_bounds__(256) void main1_kernel(
    const ushort* __restrict__ Xh, const ushort* __restrict__ Xl,
    const ushort* __restrict__ W5h, const ushort* __restrict__ W5l,
    const float* __restrict__ c211_b, float* __restrict__ B1,
    float* __restrict__ B3, float* __restrict__ att0,
    const float* __restrict__ x, const float* __restrict__ w0,
    const float* __restrict__ w1, float* __restrict__ outlka,
    const float* __restrict__ c2aw, const float* __restrict__ c2ab,
    float* __restrict__ sgate) {
  __shared__ __align__(16) char smem[45392];
  int blk = blockIdx.x;
  int t = threadIdx.x;
  if (blk < 1280) {
    const int K = 256;
    int p = blk & 63;
    int my = (blk >> 6) % 10;
    int b = blk / 640;
    const ushort *Wh, *Wl;
    float* out;
    const float* bias = nullptr;
    int M, m0;
    if (my < 4) {
      Wh = W5h; Wl = W5l; out = B1; M = 256; m0 = my * 64;
    } else if (my < 8) {
      Wh = W5h + 131072; Wl = W5l + 131072; out = B3; M = 256; m0 = (my - 4) * 64;
    } else {
      Wh = W5h + 262144; Wl = W5l + 262144; out = att0; M = 128;
      m0 = (my - 8) * 64; bias = c211_b;
    }
    int p0 = p * 64;
    gemm_body(Wh + (size_t)m0 * K, Wl + (size_t)m0 * K,
              Xh + ((size_t)b * P_ + p0) * K, Xl + ((size_t)b * P_ + p0) * K,
              bias, out, M, m0, p0, b, K, smem);
  } else if (blk < 1792) {
    constexpr int PN0 = 68;
    constexpr int PN1 = 82;
    float* p0a = (float*)smem;
    float* p1a = (float*)(smem + PN0 * PN0 * 4);
    int bc = blk - 1280;
    const float* ib = x + (size_t)bc * P_;
    for (int i = t; i < PN0 * PN0; i += 256) p0a[i] = 0.f;
    for (int i = t; i < PN1 * PN1; i += 256) p1a[i] = 0.f;
    __syncthreads();
#pragma unroll
    for (int i = 0; i < 4; ++i) {
      int l = i * 1024 + t * 4;
      int y = l >> 6, xx = l & 63;
      float4 v = *(const float4*)(ib + l);
      float* d = &p0a[(y + 2) * PN0 + 2 + xx];
      d[0] = v.x; d[1] = v.y; d[2] = v.z; d[3] = v.w;
    }
    float wr0[25];
    {
      const float* wp = w0 + (size_t)(bc & 255) * 25;
#pragma unroll
      for (int i = 0; i < 25; ++i) wr0[i] = wp[i];
    }
    __syncthreads();
#pragma unroll
    for (int r = 0; r < 16; ++r) {
      int l = r * 256 + t;
      int y = l >> 6, xx = l & 63;
      float s = 0.f;
#pragma unroll
      for (int dy = 0; dy < 5; ++dy)
#pragma unroll
        for (int dx = 0; dx < 5; ++dx)
          s += wr0[dy * 5 + dx] * p0a[(y + dy) * PN0 + xx + dx];
      p1a[(y + 9) * PN1 + 9 + xx] = s;
    }
    float wr1[49];
    {
      const float* wp = w1 + (size_t)(bc & 255) * 49;
#pragma unroll
      for (int i = 0; i < 49; ++i) wr1[i] = wp[i];
    }
    __syncthreads();
    float* ob = outlka + (size_t)bc * P_;
#pragma unroll
    for (int r = 0; r < 16; ++r) {
      int l = r * 256 + t;
      int y = l >> 6, xx = l & 63;
      float s = 0.f;
#pragma unroll
      for (int dy = 0; dy < 7; ++dy)
#pragma unroll
        for (int dx = 0; dx < 7; ++dx)
          s += wr1[dy * 7 + dx] * p1a[(y + dy * 3) * PN1 + xx + dx * 3];
      ob[l] = s;
    }
  } else {
    int idx = (blk - 1792) * 256 + t;
    int xq = idx & 63, y = (idx >> 6) & 63, go = (idx >> 12) & 15, b = idx >> 16;
    float acc[2];
#pragma unroll
    for (int h = 0; h < 2; ++h) {
      int gc = go + h * 16;
      const float* wr = c2aw + gc * 72;
      const float* xb = x + ((size_t)b * 256 + gc * 8) * P_;
      float ss = c2ab[gc];
      for (int ci = 0; ci < 8; ++ci)
        for (int dy = 0; dy < 3; ++dy) {
          int yy = y + dy - 1;
          if (yy < 0 || yy >= 64) continue;
          for (int dx = 0; dx < 3; ++dx) {
            int xx = xq + dx - 1;
            if (xx < 0 || xx >= 64) continue;
            ss += wr[ci * 9 + dy * 3 + dx] * xb[(size_t)ci * P_ + yy * 64 + xx];
          }
        }
      acc[h] = ss;
    }
    sgate[idx] = acc[0] * acc[1];
  }
}

// ---------------- mega kernel 2: dw2 + c1b 3x3 planes + xsplit(lkas) ---------
// grid 1280: [0,1024) dw planes; [1024,1280) xsplit of B6
__global__ __launch_bounds__(256) void dwsplit_kernel(
    const float* __restrict__ in1, const float* __restrict__ w1,
    float* __restrict__ out1, const float* __restrict__ in2,
    const float* __restrict__ w2, float* __restrict__ out2,
    const float* __restrict__ B6, ushort* __restrict__ XT2h,
    ushort* __restrict__ XT2l) {
  __shared__ __align__(16) char smem[33280];
  int blk = blockIdx.x;
  int t = threadIdx.x;
  if (blk < 1024) {
    constexpr int PN = 66;
    float* pl = (float*)smem;
    int which = blk >> 9;
    int bc = blk & 511;
    const float* in = which ? in2 : in1;
    const float* w = which ? w2 : w1;
    float* out = which ? out2 : out1;
    const float* ib = in + (size_t)bc * P_;
    for (int i = t; i < PN * PN; i += 256) pl[i] = 0.f;
    __syncthreads();
#pragma unroll
    for (int i = 0; i < 4; ++i) {
      int l = i * 1024 + t * 4;
      int y = l >> 6, xx = l & 63;
      float4 v = *(const float4*)(ib + l);
      float* d = &pl[(y + 1) * PN + 1 + xx];
      d[0] = v.x; d[1] = v.y; d[2] = v.z; d[3] = v.w;
    }
    float wr[9];
    const float* wp = w + (size_t)(bc & 255) * 9;
#pragma unroll
    for (int i = 0; i < 9; ++i) wr[i] = wp[i];
    __syncthreads();
    float* ob = out + (size_t)bc * P_;
#pragma unroll
    for (int r = 0; r < 16; ++r) {
      int l = r * 256 + t;
      int y = l >> 6, xx = l & 63;
      float s = 0.f;
#pragma unroll
      for (int dy = 0; dy < 3; ++dy)
#pragma unroll
        for (int dx = 0; dx < 3; ++dx)
          s += wr[dy * 3 + dx] * pl[(y + dy) * PN + xx + dx];
      ob[l] = s;
    }
  } else {
    const int K = 256;
    int l = blk - 1024;
    int p0 = (l & 63) * 64;
    int kb = (l >> 6) & 1;
    int b = l >> 7;
    xsplit_body(B6 + ((size_t)b * K + kb * 128) * P_,
                XT2h + (size_t)b * P_ * K + (size_t)kb * 128,
                XT2l + (size_t)b * P_ * K + (size_t)kb * 128, p0, K, smem);
  }
}

// ---------------- mega kernel 3: lka1 GEMM + c2b_t ----------------
// grid (64, 6, 2): y<4 lka1 gemm -> B1; y in {4,5} c2b_t -> attT
__global__ __launch_bounds__(256) void gemm_c2b_kernel(
    const ushort* __restrict__ Wh, const ushort* __restrict__ Wl,
    const ushort* __restrict__ XT2h, const ushort* __restrict__ XT2l,
    const float* __restrict__ lka1_b, float* __restrict__ B1,
    const float* __restrict__ sb, const float* __restrict__ c2bw,
    const float* __restrict__ c2bb, const float* __restrict__ gamma,
    const float* __restrict__ res, ushort* __restrict__ outh,
    ushort* __restrict__ outl) {
  __shared__ __align__(16) char smem[36864];
  int my = blockIdx.y;
  int b = blockIdx.z;
  int t = threadIdx.x;
  if (my < 4) {
    const int K = 256;
    int p0 = blockIdx.x * 64, m0 = my * 64;
    gemm_body(Wh + (size_t)m0 * K, Wl + (size_t)m0 * K,
              XT2h + ((size_t)b * P_ + p0) * K, XT2l + ((size_t)b * P_ + p0) * K,
              lka1_b, B1, 256, m0, p0, b, K, smem);
  } else {
    const int K = 16, M = 128;
    int p0 = blockIdx.x * 64;
    int m0 = (my - 4) * 64;
    float (*Ws)[68] = (float(*)[68])smem;
    float (*Xs)[68] = (float(*)[68])(smem + 4352 * 4);
    int tm = t >> 4, tp = t & 15;
    float acc[4][4] = {};
    const float* inb = sb + (size_t)b * K * P_;
    {
      int kk = t >> 4, pq = (t & 15) << 2;
      float4 v = *(const float4*)(inb + (size_t)kk * P_ + p0 + pq);
      *(float4*)&Xs[kk][pq] = v;
    }
    {
      int mm = t >> 2, kq = (t & 3) << 2;
      float4 v = *(const float4*)(c2bw + (size_t)(m0 + mm) * K + kq);
      Ws[kq + 0][mm] = v.x; Ws[kq + 1][mm] = v.y;
      Ws[kq + 2][mm] = v.z; Ws[kq + 3][mm] = v.w;
    }
    __syncthreads();
#pragma unroll
    for (int kk = 0; kk < 16; ++kk) {
      const float4 wv = *(const float4*)&Ws[kk][tm << 2];
      const float4 xv = *(const float4*)&Xs[kk][tp << 2];
      const float wa[4] = {wv.x, wv.y, wv.z, wv.w};
      const float xa[4] = {xv.x, xv.y, xv.z, xv.w};
#pragma unroll
      for (int i = 0; i < 4; ++i)
#pragma unroll
        for (int j = 0; j < 4; ++j) acc[i][j] += wa[i] * xa[j];
    }
    float val[4][4];
#pragma unroll
    for (int i = 0; i < 4; ++i) {
      int m = m0 + (tm << 2) + i;
      float bv = c2bb[m], gm = gamma[m];
      float4 rv = *(const float4*)(res + ((size_t)b * M + m) * P_ + p0 + (tp << 2));
      val[i][0] = (acc[i][0] + bv) * gm + rv.x;
      val[i][1] = (acc[i][1] + bv) * gm + rv.y;
      val[i][2] = (acc[i][2] + bv) * gm + rv.z;
      val[i][3] = (acc[i][3] + bv) * gm + rv.w;
    }
#pragma unroll
    for (int j = 0; j < 4; ++j) {
      int p = p0 + (tp << 2) + j;
      ushort vh[4], vl[4];
#pragma unroll
      for (int i = 0; i < 4; ++i) {
        float f = val[i][j];
        ushort h = f2bf(f);
        vh[i] = h;
        vl[i] = f2bf(f - bf2f(h));
      }
      size_t a = ((size_t)b * P_ + p) * 128 + m0 + (tm << 2);
      uint2 hv, lv;
      hv.x = pack2(vh[0], vh[1]); hv.y = pack2(vh[2], vh[3]);
      lv.x = pack2(vl[0], vl[1]); lv.y = pack2(vl[2], vl[3]);
      *(uint2*)&outh[a] = hv;
      *(uint2*)&outl[a] = lv;
    }
  }
}

// ---------------- IKBA v2: all-per-wave, direct global fragments ----------------
// grid (64 rows, 16 quads, B), block 256 = 4 waves; wave gg -> group quad*4+gg.
// No W/att LDS staging: MFMA fragments load straight from global (L2-resident).
// Only the C-layout -> pixel-layout transpose goes through LDS, double-buffered
// per 16-col tile with stride 66 (<=2-way bank aliasing = free).
__global__ __launch_bounds__(256) void ikba_mfma_kernel(
    const float* __restrict__ in, const ushort* __restrict__ attT,
    const ushort* __restrict__ Wt, int dirH, int wofs,
    const ushort* __restrict__ bth, const ushort* __restrict__ btl,
    const float* __restrict__ uf_ep, const float* __restrict__ ga1,
    const float* __restrict__ x1, const float* __restrict__ lka,
    const float* __restrict__ sca, ushort* __restrict__ pXh,
    ushort* __restrict__ pXl, float* __restrict__ outV) {
  __shared__ float Ts[2][4][16][66];  // 33792 B
  __shared__ float bls[64 * 17];      // 4352 B (H only)

  int t = threadIdx.x;
  int b = blockIdx.z;
  int quad = blockIdx.y;
  int y = blockIdx.x;
  int p0 = y * 64;
  int gg = t >> 6;
  int lane = t & 63;
  int lm = lane & 15, lq = lane >> 4;
  int gi = quad * 4 + gg;
  int x = lane;

  // A fragments: W cols gi*48 + ct*16 + lm (16B/lane, 16 full lines/inst)
  const ushort* Wbase = Wt + ((size_t)wofs + (size_t)gi * 48) * 128;
  bf16x8 Af[3][4];
#pragma unroll
  for (int ct = 0; ct < 3; ++ct)
#pragma unroll
    for (int K = 0; K < 4; ++K)
      Af[ct][K] = *(const bf16x8*)&Wbase[(ct * 16 + lm) * 128 + K * 32 + lq * 8];

  const ushort* Ab = attT + ((size_t)b * P_ + p0) * 128;
  f32x4 Cf[3][4];
#pragma unroll
  for (int ct = 0; ct < 3; ++ct)
#pragma unroll
    for (int pt = 0; pt < 4; ++pt) Cf[ct][pt] = (f32x4)(0.f);

#pragma unroll
  for (int pt = 0; pt < 4; ++pt) {
    bf16x8 Bf[4];
#pragma unroll
    for (int K = 0; K < 4; ++K)
      Bf[K] = *(const bf16x8*)&Ab[(pt * 16 + lm) * 128 + K * 32 + lq * 8];
#pragma unroll
    for (int ct = 0; ct < 3; ++ct)
#pragma unroll
      for (int K = 0; K < 4; ++K)
        Cf[ct][pt] = __builtin_amdgcn_mfma_f32_16x16x32_bf16(
            Af[ct][K], Bf[K], Cf[ct][pt], 0, 0, 0);
  }

  // bias_t tile via MFMA (H only); write to bls before first barrier.
  if (dirH) {
    f32x4 Cb = (f32x4)(0.f);
#pragma unroll
    for (int K = 0; K < 4; ++K) {
      bf16x8 Bb = *(const bf16x8*)&Ab[(gg * 16 + lm) * 128 + K * 32 + lq * 8];
      bf16x8 Abh = *(const bf16x8*)&bth[(size_t)(quad * 16 + lm) * 128 + K * 32 + lq * 8];
      bf16x8 Abl = *(const bf16x8*)&btl[(size_t)(quad * 16 + lm) * 128 + K * 32 + lq * 8];
      Cb = __builtin_amdgcn_mfma_f32_16x16x32_bf16(Abh, Bb, Cb, 0, 0, 0);
      Cb = __builtin_amdgcn_mfma_f32_16x16x32_bf16(Abl, Bb, Cb, 0, 0, 0);
    }
#pragma unroll
    for (int r = 0; r < 4; ++r)
      bls[(gg * 16 + lm) * 17 + lq * 4 + r] = Cb[r];
  }

  // u taps: direct per-thread coalesced global loads (no LDS staging).
  float u[12];
  const float* inb = in + ((size_t)b * 256 + gi * 4) * P_;
  if (dirH) {
#pragma unroll
    for (int j = 0; j < 12; ++j) {
      int ci = j / 3, tap = j % 3;
      int xx = x + tap - 1;
      u[j] = (xx >= 0 && xx < 64) ? inb[(size_t)ci * P_ + p0 + xx] : 0.f;
    }
  } else {
#pragma unroll
    for (int j = 0; j < 12; ++j) {
      int ci = j / 3, tap = j % 3;
      int yy = y + tap - 1;
      u[j] = (yy >= 0 && yy < 64) ? inb[(size_t)ci * P_ + yy * 64 + x] : 0.f;
    }
  }

  // transpose C tiles via LDS (double-buffered), accumulate the 12-tap dot.
  float s4[4] = {0.f, 0.f, 0.f, 0.f};
#pragma unroll
  for (int ct = 0; ct < 3; ++ct) {
    int bi = ct & 1;
#pragma unroll
    for (int pt = 0; pt < 4; ++pt)
#pragma unroll
      for (int r = 0; r < 4; ++r)
        Ts[bi][gg][lq * 4 + r][pt * 16 + lm] = Cf[ct][pt][r];
    __syncthreads();
#pragma unroll
    for (int cl = 0; cl < 16; ++cl) {
      int col = ct * 16 + cl;
      int i = col / 12, j = col % 12;
      s4[i] += Ts[bi][gg][cl][x] * u[j];
    }
  }

  // epilogue
#pragma unroll
  for (int i = 0; i < 4; ++i) {
    int ch = gi * 4 + i;
    size_t oidx = ((size_t)b * 256 + ch) * P_ + p0 + x;
    if (dirH) {
      float biasv = bls[x * 17 + gg * 4 + i];
      float x2v = (s4[i] + biasv) * ga1[ch] + uf_ep[oidx];
      float pr = x1[oidx] * x2v * sca[b * 256 + ch] * lka[oidx];
      ushort h = f2bf(pr);
      ushort lo = f2bf(pr - bf2f(h));
      // accumulate packed writes below via registers
      s4[i] = __uint_as_float(pack2(h, lo));  // stash hi,lo packed
    } else {
      outV[oidx] = s4[i];
    }
  }
  if (dirH) {
    size_t xa = ((size_t)b * P_ + p0 + x) * 256 + quad * 16 + gg * 4;
    uint2 hv, lv;
    unsigned w0 = __float_as_uint(s4[0]), w1 = __float_as_uint(s4[1]);
    unsigned w2 = __float_as_uint(s4[2]), w3 = __float_as_uint(s4[3]);
    hv.x = (w0 & 0xFFFFu) | ((w1 & 0xFFFFu) << 16);
    hv.y = (w2 & 0xFFFFu) | ((w3 & 0xFFFFu) << 16);
    lv.x = (w0 >> 16) | (w1 & 0xFFFF0000u);
    lv.y = (w2 >> 16) | (w3 & 0xFFFF0000u);
    *(uint2*)&pXh[xa] = hv;
    *(uint2*)&pXl[xa] = lv;
  }
}

extern "C" void kernel_launch(void* const* d_in, const int* in_sizes, int n_in,
                              void* d_out, int out_size, void* d_ws, size_t ws_size,
                              hipStream_t stream) {
  const float* x      = (const float*)d_in[0];
  const float* dw1_w  = (const float*)d_in[1];
  const float* dw2_w  = (const float*)d_in[2];
  const float* proj_w = (const float*)d_in[3];
  const float* lka0_w = (const float*)d_in[4];
  const float* lkas_w = (const float*)d_in[5];
  const float* lka1_w = (const float*)d_in[6];
  const float* lka1_b = (const float*)d_in[7];
  const float* sca_w  = (const float*)d_in[8];
  const float* sca_b  = (const float*)d_in[9];
  const float* c1a_w  = (const float*)d_in[10];
  const float* c1b_w  = (const float*)d_in[11];
  const float* c2a_w  = (const float*)d_in[12];
  const float* c2a_b  = (const float*)d_in[13];
  const float* c2b_w  = (const float*)d_in[14];
  const float* c2b_b  = (const float*)d_in[15];
  const float* c211_w = (const float*)d_in[16];
  const float* c211_b = (const float*)d_in[17];
  const float* w_cb   = (const float*)d_in[18];
  const float* b_cb   = (const float*)d_in[19];
  const float* attg   = (const float*)d_in[20];
  const float* ga1    = (const float*)d_in[21];
  float* out = (float*)d_out;

  const size_t NCHW = 2u * 256u * P_;
  float* ws = (float*)d_ws;
  size_t off = 0;
  float* meanb = ws + off; off += 512;
  float* scab  = ws + off; off += 512;
  float* B1 = ws + off; off += NCHW;   // dw1-out -> lka1-out (lka)
  float* B2 = ws + off; off += NCHW;   // x1
  float* B3 = ws + off; off += NCHW;   // c1a-out
  float* B4 = ws + off; off += NCHW;   // xh
  float* B5 = ws + off; off += NCHW;   // uf
  float* B6 = ws + off; off += NCHW;   // lkas-out
  float* sb   = ws + off; off += 2u * 16u * P_;   // gated
  float* att0 = ws + off; off += 2u * 128u * P_;  // c211 out (fp32)
  ushort* wT    = (ushort*)(ws + off); off += 393216;   // [6144][128] bf16
  ushort* W5h   = (ushort*)(ws + off); off += 147456;
  ushort* W5l   = (ushort*)(ws + off); off += 147456;
  ushort* bth   = (ushort*)(ws + off); off += 16384;    // b_cb^T hi [256][128]
  ushort* btl   = (ushort*)(ws + off); off += 16384;
  ushort* XTxh  = (ushort*)(ws + off); off += 1048576;  // x^T [2][P][256]
  ushort* XTxl  = (ushort*)(ws + off); off += 1048576;
  ushort* XT2h  = (ushort*)(ws + off); off += 1048576;  // lkas^T
  ushort* XT2l  = (ushort*)(ws + off); off += 1048576;
  ushort* XT3h  = (ushort*)(ws + off); off += 1048576;  // product^T
  ushort* XT3l  = (ushort*)(ws + off); off += 1048576;
  ushort* attTh = (ushort*)(ws + off); off += 524288;   // att^T [2][P][128]
  ushort* attTl = (ushort*)(ws + off); off += 524288;

  const ushort* Wlka1h = W5h + 65536,  *Wlka1l = W5l + 65536;
  const ushort* Wprojh = W5h + 196608, *Wprojl = W5l + 196608;

  dim3 blk(256);

  // K1: weight prep + mean
  prep_mean_kernel<<<756, blk, 0, stream>>>(w_cb, dw1_w, lka1_w, c1a_w, proj_w,
                                            c211_w, b_cb, wT, W5h, W5l, bth, btl,
                                            x, meanb);
  // K2: sca + x^T split
  sca_xsplit_kernel<<<258, blk, 0, stream>>>(x, XTxh, XTxl, meanb, sca_w, sca_b,
                                             scab);
  // K3: dw1/c1a/c211 GEMMs + lka depthwise chain + c2a gate
  main1_kernel<<<2304, blk, 0, stream>>>(XTxh, XTxl, W5h, W5l, c211_b,
                                         B1, B3, att0, x, lka0_w, lkas_w, B6,
                                         c2a_w, c2a_b, sb);
  // K4: dw2 (B1->B2) + c1b (B3->B5) + xsplit(B6)
  dwsplit_kernel<<<1280, blk, 0, stream>>>(B1, dw2_w, B2, B3, c1b_w, B5,
                                           B6, XT2h, XT2l);
  // K5: lka1 GEMM -> B1 (lka)  +  c2b_t -> attT
  gemm_c2b_kernel<<<dim3(64, 6, 2), blk, 0, stream>>>(
      Wlka1h, Wlka1l, XT2h, XT2l, lka1_b, B1,
      sb, c2b_w, c2b_b, attg, att0, attTh, attTl);
  // K6: IKBA vertical
  dim3 gik(64, 16, 2);
  ikba_mfma_kernel<<<gik, blk, 0, stream>>>(B5, attTh, wT, 0, 0, nullptr, nullptr,
                                            nullptr, nullptr, nullptr, nullptr,
                                            nullptr, nullptr, nullptr, B4);
  // K7: IKBA horizontal + bias_t MFMA + product + transposed split
  ikba_mfma_kernel<<<gik, blk, 0, stream>>>(B4, attTh, wT, 1, 3072, bth, btl,
                                            B5, ga1, B2, B1, scab, XT3h, XT3l,
                                            nullptr);
  // K8: proj GEMM -> out
  gemm_bf16s_kernel<<<dim3(64, 4, 2), blk, 0, stream>>>(Wprojh, Wprojl, XT3h,
                                                        XT3l, nullptr, out, 256, 256);
}

// Round 7
// 266.600 us; speedup vs baseline: 2.9609x; 1.0219x over previous
//
#include <hip/hip_runtime.h>
#include <cstddef>

#define P_ 4096   // H*W
#define HW_ 64

typedef __bf16 bf16x8 __attribute__((ext_vector_type(8)));
typedef float f32x4 __attribute__((ext_vector_type(4)));

__device__ inline ushort f2bf(float f) {
  unsigned u = __float_as_uint(f);
  unsigned r = (u + 0x7FFFu + ((u >> 16) & 1u)) >> 16;
  return (ushort)r;
}
__device__ inline float bf2f(ushort h) {
  return __uint_as_float(((unsigned)h) << 16);
}
__device__ inline unsigned pack2(ushort a, ushort b) {
  return (unsigned)a | ((unsigned)b << 16);
}

// ---------------- device helpers ----------------

// transpose+split one 128k x 64p tile: src [K][P] fp32 -> dst [P][K] bf16 hi/lo
__device__ inline void xsplit_body(const float* sb, ushort* dhb, ushort* dlb,
                                   int p0, int K, char* smem) {
  float (*T)[65] = (float(*)[65])smem;
  int t = threadIdx.x;
#pragma unroll
  for (int i = 0; i < 32; ++i) {
    int l = i * 256 + t;
    int n = l >> 6, c = l & 63;
    T[n][c] = sb[(size_t)n * P_ + p0 + c];
  }
  __syncthreads();
#pragma unroll
  for (int i = 0; i < 4; ++i) {
    int l = i * 256 + t;
    int c = l >> 4, n8 = (l & 15) << 3;
    ushort vh[8], vl[8];
#pragma unroll
    for (int u = 0; u < 8; ++u) {
      float f = T[n8 + u][c];
      ushort h = f2bf(f);
      vh[u] = h;
      vl[u] = f2bf(f - bf2f(h));
    }
    *(uint4*)&dhb[(size_t)(p0 + c) * K + n8] = *(uint4*)vh;
    *(uint4*)&dlb[(size_t)(p0 + c) * K + n8] = *(uint4*)vl;
  }
}

// split-bf16 GEMM 64x64 tile body
__device__ inline void gemm_body(const ushort* Whb, const ushort* Wlb,
                                 const ushort* Xhb, const ushort* Xlb,
                                 const float* bias, float* out, int M, int m0,
                                 int p0, int b, int K, char* smem) {
  ushort* Wsh = (ushort*)smem;
  ushort* Wsl = (ushort*)(smem + 9216);
  ushort* Xsh = (ushort*)(smem + 18432);
  ushort* Xsl = (ushort*)(smem + 27648);
  int t = threadIdx.x;
  int w = t >> 6, lane = t & 63, lm = lane & 15, lq = lane >> 4;
  f32x4 C[4];
#pragma unroll
  for (int pt = 0; pt < 4; ++pt) C[pt] = (f32x4)(0.f);
  for (int k0 = 0; k0 < K; k0 += 64) {
#pragma unroll
    for (int i = 0; i < 2; ++i) {
      int u = i * 256 + t;
      int row = u >> 3, k8 = (u & 7) * 8;
      *(uint4*)&Wsh[row * 72 + k8] = *(const uint4*)&Whb[(size_t)row * K + k0 + k8];
      *(uint4*)&Wsl[row * 72 + k8] = *(const uint4*)&Wlb[(size_t)row * K + k0 + k8];
      *(uint4*)&Xsh[row * 72 + k8] = *(const uint4*)&Xhb[(size_t)row * K + k0 + k8];
      *(uint4*)&Xsl[row * 72 + k8] = *(const uint4*)&Xlb[(size_t)row * K + k0 + k8];
    }
    __syncthreads();
#pragma unroll
    for (int kt = 0; kt < 2; ++kt) {
      bf16x8 Ah = *(const bf16x8*)&Wsh[(w * 16 + lm) * 72 + kt * 32 + lq * 8];
      bf16x8 Al = *(const bf16x8*)&Wsl[(w * 16 + lm) * 72 + kt * 32 + lq * 8];
#pragma unroll
      for (int pt = 0; pt < 4; ++pt) {
        bf16x8 Bh = *(const bf16x8*)&Xsh[(pt * 16 + lm) * 72 + kt * 32 + lq * 8];
        bf16x8 Bl = *(const bf16x8*)&Xsl[(pt * 16 + lm) * 72 + kt * 32 + lq * 8];
        C[pt] = __builtin_amdgcn_mfma_f32_16x16x32_bf16(Ah, Bh, C[pt], 0, 0, 0);
        C[pt] = __builtin_amdgcn_mfma_f32_16x16x32_bf16(Al, Bh, C[pt], 0, 0, 0);
        C[pt] = __builtin_amdgcn_mfma_f32_16x16x32_bf16(Ah, Bl, C[pt], 0, 0, 0);
      }
    }
    __syncthreads();
  }
#pragma unroll
  for (int pt = 0; pt < 4; ++pt) {
    int p = p0 + pt * 16 + lm;
#pragma unroll
    for (int r = 0; r < 4; ++r) {
      int m = m0 + w * 16 + lq * 4 + r;
      float v = C[pt][r];
      if (bias) v += bias[m];
      out[((size_t)b * M + m) * P_ + p] = v;
    }
  }
}

// ---------------- K1: prep (w_cb^T, weight splits, b_cb^T) + mean + xsplit(x) --
// grid 1012: [0,96) wT; [96,240) splits; [240,244) b_cb^T; [244,756) mean;
//            [756,1012) xsplit of x
__global__ __launch_bounds__(256) void prep_kernel(
    const float* __restrict__ w_cb, const float* __restrict__ dw1_w,
    const float* __restrict__ lka1_w, const float* __restrict__ c1a_w,
    const float* __restrict__ proj_w, const float* __restrict__ c211_w,
    const float* __restrict__ b_cb, ushort* __restrict__ wT,
    ushort* __restrict__ W5h, ushort* __restrict__ W5l,
    ushort* __restrict__ bth, ushort* __restrict__ btl,
    const float* __restrict__ x, float* __restrict__ mean,
    ushort* __restrict__ XTxh, ushort* __restrict__ XTxl) {
  __shared__ __align__(16) char smem[33280];
  float (*T)[65] = (float(*)[65])smem;
  int blk = blockIdx.x;
  int t = threadIdx.x;
  if (blk < 96) {
    int c0 = blk * 64;
#pragma unroll
    for (int i = 0; i < 32; ++i) {
      int l = i * 256 + t;
      int n = l >> 6, c = l & 63;
      T[n][c] = w_cb[(size_t)n * 6144 + c0 + c];
    }
    __syncthreads();
#pragma unroll
    for (int i = 0; i < 4; ++i) {
      int l = i * 256 + t;
      int c = l >> 4, n8 = (l & 15) << 3;
      ushort v[8];
#pragma unroll
      for (int u = 0; u < 8; ++u) v[u] = f2bf(T[n8 + u][c]);
      *(uint4*)&wT[(size_t)(c0 + c) * 128 + n8] = *(uint4*)v;
    }
  } else if (blk < 240) {
    int f = (blk - 96) * 2048 + t * 8;
    const float* srcs[5] = {dw1_w, lka1_w, c1a_w, proj_w, c211_w};
    const int base[6] = {0, 65536, 131072, 196608, 262144, 294912};
    int r = 0;
    while (f >= base[r + 1]) ++r;
    const float* s = srcs[r] + (f - base[r]);
    float4 a = *(const float4*)s;
    float4 b4 = *(const float4*)(s + 4);
    float vv[8] = {a.x, a.y, a.z, a.w, b4.x, b4.y, b4.z, b4.w};
    ushort vh[8], vl[8];
#pragma unroll
    for (int u = 0; u < 8; ++u) {
      ushort h = f2bf(vv[u]);
      vh[u] = h;
      vl[u] = f2bf(vv[u] - bf2f(h));
    }
    *(uint4*)&W5h[f] = *(uint4*)vh;
    *(uint4*)&W5l[f] = *(uint4*)vl;
  } else if (blk < 244) {
    int c0 = (blk - 240) * 64;
#pragma unroll
    for (int i = 0; i < 32; ++i) {
      int l = i * 256 + t;
      int n = l >> 6, c = l & 63;
      T[n][c] = b_cb[(size_t)n * 256 + c0 + c];
    }
    __syncthreads();
#pragma unroll
    for (int i = 0; i < 4; ++i) {
      int l = i * 256 + t;
      int c = l >> 4, n8 = (l & 15) << 3;
      ushort vh[8], vl[8];
#pragma unroll
      for (int u = 0; u < 8; ++u) {
        float fv = T[n8 + u][c];
        ushort h = f2bf(fv);
        vh[u] = h;
        vl[u] = f2bf(fv - bf2f(h));
      }
      *(uint4*)&bth[(size_t)(c0 + c) * 128 + n8] = *(uint4*)vh;
      *(uint4*)&btl[(size_t)(c0 + c) * 128 + n8] = *(uint4*)vl;
    }
  } else if (blk < 756) {
    int bc = blk - 244;
    const float* xp = x + (size_t)bc * P_;
    float s = 0.f;
    for (int i = t; i < P_; i += 256) s += xp[i];
    float* red = (float*)smem;
    red[t] = s;
    __syncthreads();
    for (int off2 = 128; off2 > 0; off2 >>= 1) {
      if (t < off2) red[t] += red[t + off2];
      __syncthreads();
    }
    if (t == 0) mean[bc] = red[0] * (1.f / P_);
  } else {
    const int K = 256;
    int l = blk - 756;
    int p0 = (l & 63) * 64;
    int kb = (l >> 6) & 1;
    int b = l >> 7;
    xsplit_body(x + ((size_t)b * K + kb * 128) * P_,
                XTxh + (size_t)b * P_ * K + (size_t)kb * 128,
                XTxl + (size_t)b * P_ * K + (size_t)kb * 128, p0, K, smem);
  }
}

// ---------------- K2: main1 v2 -------------------------------------------------
// grid 2306: [0,512) lka chain (vectorized); [512,1024) c2a gate; [1024,1026) sca;
//            [1026,2306) gemm tiles dw1/c1a/c211
__global__ __launch_bounds__(256) void main1_kernel(
    const ushort* __restrict__ Xh, const ushort* __restrict__ Xl,
    const ushort* __restrict__ W5h, const ushort* __restrict__ W5l,
    const float* __restrict__ c211_b, float* __restrict__ B1,
    float* __restrict__ B3, float* __restrict__ att0,
    const float* __restrict__ x, const float* __restrict__ w0,
    const float* __restrict__ w1, float* __restrict__ outlka,
    const float* __restrict__ c2aw, const float* __restrict__ c2ab,
    float* __restrict__ sgate, const float* __restrict__ mean,
    const float* __restrict__ sca_w, const float* __restrict__ sca_b,
    float* __restrict__ sca) {
  __shared__ __align__(16) char smem[48448];
  int blk = blockIdx.x;
  int t = threadIdx.x;
  if (blk < 512) {
    // lka chain: 5x5 p2 -> 7x7 d3 p9, 4x4 register-blocked float4 LDS reads.
    // p0a: 68 rows x 72 cols, interior (y,x) at [(y+2)*72 + 4 + x]
    // p1a: 82 rows x 88 cols, interior (y,x) at [(y+9)*88 + 12 + x]
    float* p0a = (float*)smem;
    float* p1a = (float*)(smem + 19584);
    int bc = blk;
    const float* ib = x + (size_t)bc * P_;
    const float* wp0 = w0 + (size_t)(bc & 255) * 25;
    const float* wp1 = w1 + (size_t)(bc & 255) * 49;
    for (int i = t; i < 4896; i += 256) p0a[i] = 0.f;
    for (int i = t; i < 7216; i += 256) p1a[i] = 0.f;
    __syncthreads();
#pragma unroll
    for (int i = 0; i < 4; ++i) {
      int l = i * 1024 + t * 4;
      int y = l >> 6, xx = l & 63;
      *(float4*)&p0a[(y + 2) * 72 + 4 + xx] = *(const float4*)(ib + l);
    }
    __syncthreads();
    int x0 = (t & 15) * 4, y0 = (t >> 4) * 4;
    // pass 1: 5x5
    {
      float acc[4][4] = {};
#pragma unroll
      for (int ry = 0; ry < 8; ++ry) {
        const float* row = &p0a[(y0 + ry) * 72 + x0];
        float4 v0 = *(const float4*)row;
        float4 v1 = *(const float4*)(row + 4);
        float4 v2 = *(const float4*)(row + 8);
        float rv[12] = {v0.x, v0.y, v0.z, v0.w, v1.x, v1.y, v1.z, v1.w,
                        v2.x, v2.y, v2.z, v2.w};
#pragma unroll
        for (int oy = 0; oy < 4; ++oy) {
          int dy = ry - oy;
          if (dy >= 0 && dy <= 4) {
#pragma unroll
            for (int dx = 0; dx < 5; ++dx) {
              float wv = wp0[dy * 5 + dx];
#pragma unroll
              for (int ox = 0; ox < 4; ++ox)
                acc[oy][ox] += wv * rv[2 + ox + dx];
            }
          }
        }
      }
#pragma unroll
      for (int oy = 0; oy < 4; ++oy) {
        float4 v = {acc[oy][0], acc[oy][1], acc[oy][2], acc[oy][3]};
        *(float4*)&p1a[(y0 + oy + 9) * 88 + 12 + x0] = v;
      }
    }
    __syncthreads();
    // pass 2: 7x7 dilation 3
    {
      float acc[4][4] = {};
#pragma unroll
      for (int ry = 0; ry < 22; ++ry) {
        const float* row = &p1a[(y0 + ry) * 88 + x0];
        float rv[28];
#pragma unroll
        for (int q = 0; q < 7; ++q)
          *(float4*)&rv[q * 4] = *(const float4*)(row + q * 4);
#pragma unroll
        for (int oy = 0; oy < 4; ++oy) {
          int d = ry - oy;
          if (d >= 0 && d <= 18 && (d % 3) == 0) {
            int dy = d / 3;
#pragma unroll
            for (int dx = 0; dx < 7; ++dx) {
              float wv = wp1[dy * 7 + dx];
#pragma unroll
              for (int ox = 0; ox < 4; ++ox)
                acc[oy][ox] += wv * rv[3 + ox + 3 * dx];
            }
          }
        }
      }
      float* ob = outlka + (size_t)bc * P_;
#pragma unroll
      for (int oy = 0; oy < 4; ++oy) {
        float4 v = {acc[oy][0], acc[oy][1], acc[oy][2], acc[oy][3]};
        *(float4*)&ob[(y0 + oy) * 64 + x0] = v;
      }
    }
  } else if (blk < 1024) {
    int idx = (blk - 512) * 256 + t;
    int xq = idx & 63, y = (idx >> 6) & 63, go = (idx >> 12) & 15, b = idx >> 16;
    float acc[2];
#pragma unroll
    for (int h = 0; h < 2; ++h) {
      int gc = go + h * 16;
      const float* wr = c2aw + gc * 72;
      const float* xb = x + ((size_t)b * 256 + gc * 8) * P_;
      float ss = c2ab[gc];
      for (int ci = 0; ci < 8; ++ci)
        for (int dy = 0; dy < 3; ++dy) {
          int yy = y + dy - 1;
          if (yy < 0 || yy >= 64) continue;
          for (int dx = 0; dx < 3; ++dx) {
            int xx = xq + dx - 1;
            if (xx < 0 || xx >= 64) continue;
            ss += wr[ci * 9 + dy * 3 + dx] * xb[(size_t)ci * P_ + yy * 64 + xx];
          }
        }
      acc[h] = ss;
    }
    sgate[idx] = acc[0] * acc[1];
  } else if (blk < 1026) {
    int b = blk - 1024, c = t;
    const float* mb = mean + b * 256;
    const float* wr = sca_w + c * 256;
    float s = sca_b[c];
    for (int k = 0; k < 256; ++k) s += wr[k] * mb[k];
    sca[b * 256 + c] = s;
  } else {
    const int K = 256;
    int g = blk - 1026;
    int p = g & 63;
    int my = (g >> 6) % 10;
    int b = g / 640;
    const ushort *Wh, *Wl;
    float* out;
    const float* bias = nullptr;
    int M, m0;
    if (my < 4) {
      Wh = W5h; Wl = W5l; out = B1; M = 256; m0 = my * 64;
    } else if (my < 8) {
      Wh = W5h + 131072; Wl = W5l + 131072; out = B3; M = 256; m0 = (my - 4) * 64;
    } else {
      Wh = W5h + 262144; Wl = W5l + 262144; out = att0; M = 128;
      m0 = (my - 8) * 64; bias = c211_b;
    }
    int p0 = p * 64;
    gemm_body(Wh + (size_t)m0 * K, Wl + (size_t)m0 * K,
              Xh + ((size_t)b * P_ + p0) * K, Xl + ((size_t)b * P_ + p0) * K,
              bias, out, M, m0, p0, b, K, smem);
  }
}

// ---------------- K3: dw2 + c1b 3x3 planes (vectorized) + xsplit(lkas) --------
// grid 1280: [0,1024) dw planes; [1024,1280) xsplit of B6
__global__ __launch_bounds__(256) void dwsplit_kernel(
    const float* __restrict__ in1, const float* __restrict__ w1,
    float* __restrict__ out1, const float* __restrict__ in2,
    const float* __restrict__ w2, float* __restrict__ out2,
    const float* __restrict__ B6, ushort* __restrict__ XT2h,
    ushort* __restrict__ XT2l) {
  __shared__ __align__(16) char smem[33280];
  int blk = blockIdx.x;
  int t = threadIdx.x;
  if (blk < 1024) {
    // plane: 66 rows x 72 cols, interior (y,x) at [(y+1)*72 + 4 + x]
    float* pl = (float*)smem;
    int which = blk >> 9;
    int bc = blk & 511;
    const float* in = which ? in2 : in1;
    const float* w = which ? w2 : w1;
    float* out = which ? out2 : out1;
    const float* ib = in + (size_t)bc * P_;
    const float* wp = w + (size_t)(bc & 255) * 9;
    for (int i = t; i < 4752; i += 256) pl[i] = 0.f;
    __syncthreads();
#pragma unroll
    for (int i = 0; i < 4; ++i) {
      int l = i * 1024 + t * 4;
      int y = l >> 6, xx = l & 63;
      *(float4*)&pl[(y + 1) * 72 + 4 + xx] = *(const float4*)(ib + l);
    }
    __syncthreads();
    int x0 = (t & 15) * 4, y0 = (t >> 4) * 4;
    float acc[4][4] = {};
#pragma unroll
    for (int ry = 0; ry < 6; ++ry) {
      const float* row = &pl[(y0 + ry) * 72 + x0];
      float4 v0 = *(const float4*)row;
      float4 v1 = *(const float4*)(row + 4);
      float4 v2 = *(const float4*)(row + 8);
      float rv[12] = {v0.x, v0.y, v0.z, v0.w, v1.x, v1.y, v1.z, v1.w,
                      v2.x, v2.y, v2.z, v2.w};
#pragma unroll
      for (int oy = 0; oy < 4; ++oy) {
        int dy = ry - oy;
        if (dy >= 0 && dy <= 2) {
#pragma unroll
          for (int dx = 0; dx < 3; ++dx) {
            float wv = wp[dy * 3 + dx];
#pragma unroll
            for (int ox = 0; ox < 4; ++ox)
              acc[oy][ox] += wv * rv[3 + ox + dx];
          }
        }
      }
    }
    float* ob = out + (size_t)bc * P_;
#pragma unroll
    for (int oy = 0; oy < 4; ++oy) {
      float4 v = {acc[oy][0], acc[oy][1], acc[oy][2], acc[oy][3]};
      *(float4*)&ob[(y0 + oy) * 64 + x0] = v;
    }
  } else {
    const int K = 256;
    int l = blk - 1024;
    int p0 = (l & 63) * 64;
    int kb = (l >> 6) & 1;
    int b = l >> 7;
    xsplit_body(B6 + ((size_t)b * K + kb * 128) * P_,
                XT2h + (size_t)b * P_ * K + (size_t)kb * 128,
                XT2l + (size_t)b * P_ * K + (size_t)kb * 128, p0, K, smem);
  }
}

// ---------------- K4: lka1 GEMM + c2b_t ----------------
// grid (64, 6, 2): y<4 lka1 gemm -> B1; y in {4,5} c2b_t -> attT
__global__ __launch_bounds__(256) void gemm_c2b_kernel(
    const ushort* __restrict__ Wh, const ushort* __restrict__ Wl,
    const ushort* __restrict__ XT2h, const ushort* __restrict__ XT2l,
    const float* __restrict__ lka1_b, float* __restrict__ B1,
    const float* __restrict__ sb, const float* __restrict__ c2bw,
    const float* __restrict__ c2bb, const float* __restrict__ gamma,
    const float* __restrict__ res, ushort* __restrict__ outh,
    ushort* __restrict__ outl) {
  __shared__ __align__(16) char smem[36864];
  int my = blockIdx.y;
  int b = blockIdx.z;
  int t = threadIdx.x;
  if (my < 4) {
    const int K = 256;
    int p0 = blockIdx.x * 64, m0 = my * 64;
    gemm_body(Wh + (size_t)m0 * K, Wl + (size_t)m0 * K,
              XT2h + ((size_t)b * P_ + p0) * K, XT2l + ((size_t)b * P_ + p0) * K,
              lka1_b, B1, 256, m0, p0, b, K, smem);
  } else {
    const int K = 16, M = 128;
    int p0 = blockIdx.x * 64;
    int m0 = (my - 4) * 64;
    float (*Ws)[68] = (float(*)[68])smem;
    float (*Xs)[68] = (float(*)[68])(smem + 4352 * 4);
    int tm = t >> 4, tp = t & 15;
    float acc[4][4] = {};
    const float* inb = sb + (size_t)b * K * P_;
    {
      int kk = t >> 4, pq = (t & 15) << 2;
      float4 v = *(const float4*)(inb + (size_t)kk * P_ + p0 + pq);
      *(float4*)&Xs[kk][pq] = v;
    }
    {
      int mm = t >> 2, kq = (t & 3) << 2;
      float4 v = *(const float4*)(c2bw + (size_t)(m0 + mm) * K + kq);
      Ws[kq + 0][mm] = v.x; Ws[kq + 1][mm] = v.y;
      Ws[kq + 2][mm] = v.z; Ws[kq + 3][mm] = v.w;
    }
    __syncthreads();
#pragma unroll
    for (int kk = 0; kk < 16; ++kk) {
      const float4 wv = *(const float4*)&Ws[kk][tm << 2];
      const float4 xv = *(const float4*)&Xs[kk][tp << 2];
      const float wa[4] = {wv.x, wv.y, wv.z, wv.w};
      const float xa[4] = {xv.x, xv.y, xv.z, xv.w};
#pragma unroll
      for (int i = 0; i < 4; ++i)
#pragma unroll
        for (int j = 0; j < 4; ++j) acc[i][j] += wa[i] * xa[j];
    }
    float val[4][4];
#pragma unroll
    for (int i = 0; i < 4; ++i) {
      int m = m0 + (tm << 2) + i;
      float bv = c2bb[m], gm = gamma[m];
      float4 rv = *(const float4*)(res + ((size_t)b * M + m) * P_ + p0 + (tp << 2));
      val[i][0] = (acc[i][0] + bv) * gm + rv.x;
      val[i][1] = (acc[i][1] + bv) * gm + rv.y;
      val[i][2] = (acc[i][2] + bv) * gm + rv.z;
      val[i][3] = (acc[i][3] + bv) * gm + rv.w;
    }
#pragma unroll
    for (int j = 0; j < 4; ++j) {
      int p = p0 + (tp << 2) + j;
      ushort vh[4], vl[4];
#pragma unroll
      for (int i = 0; i < 4; ++i) {
        float f = val[i][j];
        ushort h = f2bf(f);
        vh[i] = h;
        vl[i] = f2bf(f - bf2f(h));
      }
      size_t a = ((size_t)b * P_ + p) * 128 + m0 + (tm << 2);
      uint2 hv, lv;
      hv.x = pack2(vh[0], vh[1]); hv.y = pack2(vh[2], vh[3]);
      lv.x = pack2(vl[0], vl[1]); lv.y = pack2(vl[2], vl[3]);
      *(uint2*)&outh[a] = hv;
      *(uint2*)&outl[a] = lv;
    }
  }
}

// ---------------- IKBA v2: all-per-wave, direct global fragments ----------------
__global__ __launch_bounds__(256) void ikba_mfma_kernel(
    const float* __restrict__ in, const ushort* __restrict__ attT,
    const ushort* __restrict__ Wt, int dirH, int wofs,
    const ushort* __restrict__ bth, const ushort* __restrict__ btl,
    const float* __restrict__ uf_ep, const float* __restrict__ ga1,
    const float* __restrict__ x1, const float* __restrict__ lka,
    const float* __restrict__ sca, ushort* __restrict__ pXh,
    ushort* __restrict__ pXl, float* __restrict__ outV) {
  __shared__ float Ts[2][4][16][66];
  __shared__ float bls[64 * 17];

  int t = threadIdx.x;
  int b = blockIdx.z;
  int quad = blockIdx.y;
  int y = blockIdx.x;
  int p0 = y * 64;
  int gg = t >> 6;
  int lane = t & 63;
  int lm = lane & 15, lq = lane >> 4;
  int gi = quad * 4 + gg;
  int x = lane;

  const ushort* Wbase = Wt + ((size_t)wofs + (size_t)gi * 48) * 128;
  bf16x8 Af[3][4];
#pragma unroll
  for (int ct = 0; ct < 3; ++ct)
#pragma unroll
    for (int K = 0; K < 4; ++K)
      Af[ct][K] = *(const bf16x8*)&Wbase[(ct * 16 + lm) * 128 + K * 32 + lq * 8];

  const ushort* Ab = attT + ((size_t)b * P_ + p0) * 128;
  f32x4 Cf[3][4];
#pragma unroll
  for (int ct = 0; ct < 3; ++ct)
#pragma unroll
    for (int pt = 0; pt < 4; ++pt) Cf[ct][pt] = (f32x4)(0.f);

#pragma unroll
  for (int pt = 0; pt < 4; ++pt) {
    bf16x8 Bf[4];
#pragma unroll
    for (int K = 0; K < 4; ++K)
      Bf[K] = *(const bf16x8*)&Ab[(pt * 16 + lm) * 128 + K * 32 + lq * 8];
#pragma unroll
    for (int ct = 0; ct < 3; ++ct)
#pragma unroll
      for (int K = 0; K < 4; ++K)
        Cf[ct][pt] = __builtin_amdgcn_mfma_f32_16x16x32_bf16(
            Af[ct][K], Bf[K], Cf[ct][pt], 0, 0, 0);
  }

  if (dirH) {
    f32x4 Cb = (f32x4)(0.f);
#pragma unroll
    for (int K = 0; K < 4; ++K) {
      bf16x8 Bb = *(const bf16x8*)&Ab[(gg * 16 + lm) * 128 + K * 32 + lq * 8];
      bf16x8 Abh = *(const bf16x8*)&bth[(size_t)(quad * 16 + lm) * 128 + K * 32 + lq * 8];
      bf16x8 Abl = *(const bf16x8*)&btl[(size_t)(quad * 16 + lm) * 128 + K * 32 + lq * 8];
      Cb = __builtin_amdgcn_mfma_f32_16x16x32_bf16(Abh, Bb, Cb, 0, 0, 0);
      Cb = __builtin_amdgcn_mfma_f32_16x16x32_bf16(Abl, Bb, Cb, 0, 0, 0);
    }
#pragma unroll
    for (int r = 0; r < 4; ++r)
      bls[(gg * 16 + lm) * 17 + lq * 4 + r] = Cb[r];
  }

  float u[12];
  const float* inb = in + ((size_t)b * 256 + gi * 4) * P_;
  if (dirH) {
#pragma unroll
    for (int j = 0; j < 12; ++j) {
      int ci = j / 3, tap = j % 3;
      int xx = x + tap - 1;
      u[j] = (xx >= 0 && xx < 64) ? inb[(size_t)ci * P_ + p0 + xx] : 0.f;
    }
  } else {
#pragma unroll
    for (int j = 0; j < 12; ++j) {
      int ci = j / 3, tap = j % 3;
      int yy = y + tap - 1;
      u[j] = (yy >= 0 && yy < 64) ? inb[(size_t)ci * P_ + yy * 64 + x] : 0.f;
    }
  }

  float s4[4] = {0.f, 0.f, 0.f, 0.f};
#pragma unroll
  for (int ct = 0; ct < 3; ++ct) {
    int bi = ct & 1;
#pragma unroll
    for (int pt = 0; pt < 4; ++pt)
#pragma unroll
      for (int r = 0; r < 4; ++r)
        Ts[bi][gg][lq * 4 + r][pt * 16 + lm] = Cf[ct][pt][r];
    __syncthreads();
#pragma unroll
    for (int cl = 0; cl < 16; ++cl) {
      int col = ct * 16 + cl;
      int i = col / 12, j = col % 12;
      s4[i] += Ts[bi][gg][cl][x] * u[j];
    }
  }

#pragma unroll
  for (int i = 0; i < 4; ++i) {
    int ch = gi * 4 + i;
    size_t oidx = ((size_t)b * 256 + ch) * P_ + p0 + x;
    if (dirH) {
      float biasv = bls[x * 17 + gg * 4 + i];
      float x2v = (s4[i] + biasv) * ga1[ch] + uf_ep[oidx];
      float pr = x1[oidx] * x2v * sca[b * 256 + ch] * lka[oidx];
      ushort h = f2bf(pr);
      ushort lo = f2bf(pr - bf2f(h));
      s4[i] = __uint_as_float(pack2(h, lo));
    } else {
      outV[oidx] = s4[i];
    }
  }
  if (dirH) {
    size_t xa = ((size_t)b * P_ + p0 + x) * 256 + quad * 16 + gg * 4;
    uint2 hv, lv;
    unsigned w0 = __float_as_uint(s4[0]), w1 = __float_as_uint(s4[1]);
    unsigned w2 = __float_as_uint(s4[2]), w3 = __float_as_uint(s4[3]);
    hv.x = (w0 & 0xFFFFu) | ((w1 & 0xFFFFu) << 16);
    hv.y = (w2 & 0xFFFFu) | ((w3 & 0xFFFFu) << 16);
    lv.x = (w0 >> 16) | (w1 & 0xFFFF0000u);
    lv.y = (w2 >> 16) | (w3 & 0xFFFF0000u);
    *(uint2*)&pXh[xa] = hv;
    *(uint2*)&pXl[xa] = lv;
  }
}

// ---------------- standalone split-bf16 GEMM (proj) ----------------
__global__ __launch_bounds__(256) void gemm_bf16s_kernel(
    const ushort* __restrict__ Wh, const ushort* __restrict__ Wl,
    const ushort* __restrict__ Xh, const ushort* __restrict__ Xl,
    const float* __restrict__ bias, float* __restrict__ out, int M, int K) {
  __shared__ __align__(16) char smem[36864];
  int p0 = blockIdx.x * 64, m0 = blockIdx.y * 64, b = blockIdx.z;
  gemm_body(Wh + (size_t)m0 * K, Wl + (size_t)m0 * K,
            Xh + ((size_t)b * P_ + p0) * K, Xl + ((size_t)b * P_ + p0) * K,
            bias, out, M, m0, p0, b, K, smem);
}

extern "C" void kernel_launch(void* const* d_in, const int* in_sizes, int n_in,
                              void* d_out, int out_size, void* d_ws, size_t ws_size,
                              hipStream_t stream) {
  const float* x      = (const float*)d_in[0];
  const float* dw1_w  = (const float*)d_in[1];
  const float* dw2_w  = (const float*)d_in[2];
  const float* proj_w = (const float*)d_in[3];
  const float* lka0_w = (const float*)d_in[4];
  const float* lkas_w = (const float*)d_in[5];
  const float* lka1_w = (const float*)d_in[6];
  const float* lka1_b = (const float*)d_in[7];
  const float* sca_w  = (const float*)d_in[8];
  const float* sca_b  = (const float*)d_in[9];
  const float* c1a_w  = (const float*)d_in[10];
  const float* c1b_w  = (const float*)d_in[11];
  const float* c2a_w  = (const float*)d_in[12];
  const float* c2a_b  = (const float*)d_in[13];
  const float* c2b_w  = (const float*)d_in[14];
  const float* c2b_b  = (const float*)d_in[15];
  const float* c211_w = (const float*)d_in[16];
  const float* c211_b = (const float*)d_in[17];
  const float* w_cb   = (const float*)d_in[18];
  const float* b_cb   = (const float*)d_in[19];
  const float* attg   = (const float*)d_in[20];
  const float* ga1    = (const float*)d_in[21];
  float* out = (float*)d_out;

  const size_t NCHW = 2u * 256u * P_;
  float* ws = (float*)d_ws;
  size_t off = 0;
  float* meanb = ws + off; off += 512;
  float* scab  = ws + off; off += 512;
  float* B1 = ws + off; off += NCHW;   // dw1-out -> lka1-out (lka)
  float* B2 = ws + off; off += NCHW;   // x1
  float* B3 = ws + off; off += NCHW;   // c1a-out
  float* B4 = ws + off; off += NCHW;   // xh
  float* B5 = ws + off; off += NCHW;   // uf
  float* B6 = ws + off; off += NCHW;   // lkas-out
  float* sb   = ws + off; off += 2u * 16u * P_;   // gated
  float* att0 = ws + off; off += 2u * 128u * P_;  // c211 out (fp32)
  ushort* wT    = (ushort*)(ws + off); off += 393216;   // [6144][128] bf16
  ushort* W5h   = (ushort*)(ws + off); off += 147456;
  ushort* W5l   = (ushort*)(ws + off); off += 147456;
  ushort* bth   = (ushort*)(ws + off); off += 16384;    // b_cb^T hi [256][128]
  ushort* btl   = (ushort*)(ws + off); off += 16384;
  ushort* XTxh  = (ushort*)(ws + off); off += 1048576;  // x^T [2][P][256]
  ushort* XTxl  = (ushort*)(ws + off); off += 1048576;
  ushort* XT2h  = (ushort*)(ws + off); off += 1048576;  // lkas^T
  ushort* XT2l  = (ushort*)(ws + off); off += 1048576;
  ushort* XT3h  = (ushort*)(ws + off); off += 1048576;  // product^T
  ushort* XT3l  = (ushort*)(ws + off); off += 1048576;
  ushort* attTh = (ushort*)(ws + off); off += 524288;   // att^T [2][P][128]
  ushort* attTl = (ushort*)(ws + off); off += 524288;

  const ushort* Wlka1h = W5h + 65536,  *Wlka1l = W5l + 65536;
  const ushort* Wprojh = W5h + 196608, *Wprojl = W5l + 196608;

  dim3 blk(256);

  // K1: weight prep + mean + xsplit(x)
  prep_kernel<<<1012, blk, 0, stream>>>(w_cb, dw1_w, lka1_w, c1a_w, proj_w,
                                        c211_w, b_cb, wT, W5h, W5l, bth, btl,
                                        x, meanb, XTxh, XTxl);
  // K2: lka chain + c2a gate + sca + dw1/c1a/c211 GEMMs
  main1_kernel<<<2306, blk, 0, stream>>>(XTxh, XTxl, W5h, W5l, c211_b,
                                         B1, B3, att0, x, lka0_w, lkas_w, B6,
                                         c2a_w, c2a_b, sb, meanb, sca_w, sca_b,
                                         scab);
  // K3: dw2 (B1->B2) + c1b (B3->B5) + xsplit(B6)
  dwsplit_kernel<<<1280, blk, 0, stream>>>(B1, dw2_w, B2, B3, c1b_w, B5,
                                           B6, XT2h, XT2l);
  // K4: lka1 GEMM -> B1 (lka)  +  c2b_t -> attT
  gemm_c2b_kernel<<<dim3(64, 6, 2), blk, 0, stream>>>(
      Wlka1h, Wlka1l, XT2h, XT2l, lka1_b, B1,
      sb, c2b_w, c2b_b, attg, att0, attTh, attTl);
  // K5: IKBA vertical
  dim3 gik(64, 16, 2);
  ikba_mfma_kernel<<<gik, blk, 0, stream>>>(B5, attTh, wT, 0, 0, nullptr, nullptr,
                                            nullptr, nullptr, nullptr, nullptr,
                                            nullptr, nullptr, nullptr, B4);
  // K6: IKBA horizontal + bias_t MFMA + product + transposed split
  ikba_mfma_kernel<<<gik, blk, 0, stream>>>(B4, attTh, wT, 1, 3072, bth, btl,
                                            B5, ga1, B2, B1, scab, XT3h, XT3l,
                                            nullptr);
  // K7: proj GEMM -> out
  gemm_bf16s_kernel<<<dim3(64, 4, 2), blk, 0, stream>>>(Wprojh, Wprojl, XT3h,
                                                        XT3l, nullptr, out, 256, 256);
}